// Round 21
// baseline (2310.530 us; speedup 1.0000x reference)
//
#include <hip/hip_runtime.h>
#include <math.h>

#define BB 16
#define DD 512
#define HHN 8
#define LEN_E 720
#define LEN_D 1080
#define NV 321
#define DFF2 2048

typedef __attribute__((ext_vector_type(8))) short short8;
typedef __attribute__((ext_vector_type(4))) float floatx4;
typedef unsigned short u16;

__device__ __forceinline__ u16 f2bf(float v) {
  unsigned u = __builtin_bit_cast(unsigned, v);
  u += 0x7FFFu + ((u >> 16) & 1u);
  return (u16)(u >> 16);
}
__device__ __forceinline__ float bf2f(u16 h) {
  unsigned u = ((unsigned)h) << 16;
  return __builtin_bit_cast(float, u);
}

// element offset (u16) of (r,k) in tiled pair buffer; lo at +4096.
// tile = 128 rows x 32 cols, 8192 u16 (hi 4096 + lo 4096), XOR-swizzled slots.
__device__ __forceinline__ size_t toff(int r, int k, int ktn) {
  int rt = r >> 7, rr = r & 127;
  int kt = k >> 5, kk = k & 31;
  int sw = (kk >> 3) ^ (rr & 3) ^ ((rr >> 2) & 3);
  return (((size_t)(rt * ktn + kt)) << 13) + (rr << 5) + (sw << 3) + (kk & 7);
}

__device__ __forceinline__ void gload_lds(const void* g, void* l) {
  __builtin_amdgcn_global_load_lds(
      (const __attribute__((address_space(1))) unsigned int*)g,
      (__attribute__((address_space(3))) unsigned int*)l, 16, 0, 0);
}

// ---------------- prep kernels ----------------
__global__ void k_extract_x(const float* __restrict__ hist, float* __restrict__ xe) {
  int idx = blockIdx.x * 256 + threadIdx.x;
  if (idx >= BB*LEN_E*NV) return;
  xe[idx] = hist[(size_t)idx * 5];
}

__global__ void k_marks_enc(const float* __restrict__ hist, float* __restrict__ xme) {
  int idx = blockIdx.x * 256 + threadIdx.x;
  if (idx >= BB*LEN_E*4) return;
  int f = idx & 3;
  int r = idx >> 2;
  xme[idx] = hist[((size_t)r * NV) * 5 + 1 + f];
}

__global__ void k_marks_dec(const float* __restrict__ fut, const float* __restrict__ xme,
                            float* __restrict__ xmd) {
  int idx = blockIdx.x * 256 + threadIdx.x;
  if (idx >= BB*LEN_D*4) return;
  int f = idx & 3;
  int r = idx >> 2;
  int t = r % LEN_D, b = r / LEN_D;
  float v;
  if (t < 360) v = xme[((b*LEN_E) + 360 + t)*4 + f];
  else v = fut[(((size_t)(b*LEN_E + (t-360))) * NV) * 5 + 1 + f];
  xmd[idx] = v;
}

__global__ void k_ms_part(const float* __restrict__ xe, float* __restrict__ part,
                          int chl, int nch) {
  int n = threadIdx.x;
  if (n >= NV) return;
  int b = blockIdx.x, c = blockIdx.y;
  int l0 = c*chl, l1 = l0 + chl; if (l1 > LEN_E) l1 = LEN_E;
  float s = 0.f;
  for (int l = l0; l < l1; ++l) s += xe[((size_t)b*LEN_E + l)*NV + n];
  part[((size_t)b*nch + c)*NV + n] = s;
}
__global__ void k_ms_fin(const float* __restrict__ part, float* __restrict__ mb, int nch) {
  int i = blockIdx.x*256 + threadIdx.x;
  if (i >= BB*NV) return;
  int b = i / NV, n = i % NV;
  float s = 0.f;
  for (int c = 0; c < nch; ++c) s += part[((size_t)b*nch + c)*NV + n];
  mb[i] = s * (1.f/(float)LEN_E);
}

// seas full (B,1080,NV); trend ONLY remapped rows (b, t>=360) -> (b*720+(t-360), n)
__global__ void k_init_decomp(const float* __restrict__ xe, const float* __restrict__ mb,
                              float* __restrict__ seas, float* __restrict__ trend) {
  int idx = blockIdx.x * 256 + threadIdx.x;
  if (idx >= BB*LEN_D*NV) return;
  int n = idx % NV; int r = idx / NV; int t = r % LEN_D; int b = r / LEN_D;
  if (t < 360) {
    int l = 360 + t;
    float s = 0.f;
    for (int j = -12; j <= 12; ++j) {
      int lc = l + j; if (lc > LEN_E-1) lc = LEN_E-1; if (lc < 0) lc = 0;
      s += xe[((size_t)b*LEN_E + lc)*NV + n];
    }
    float ma = s * (1.f/25.f);
    seas[idx]  = xe[((size_t)b*LEN_E + l)*NV + n] - ma;
  } else {
    trend[((size_t)(b*LEN_E + (t - 360)))*NV + n] = mb[b*NV + n];
    seas[idx]  = 0.f;
  }
}

// marks embedding, dual output: X += marks@Wt.T (fp32) and tiled bf16 pair
__global__ void k_marks_add(float* __restrict__ X, const float* __restrict__ xm,
                            const float* __restrict__ Wt, u16* __restrict__ pair, int M) {
  int idx = blockIdx.x*256 + threadIdx.x;
  if (idx >= M*DD) return;
  int d = idx & 511, r = idx >> 9;
  const float* m4 = xm + (size_t)r*4;
  const float* w4 = Wt + (size_t)d*4;
  float v = X[idx] + m4[0]*w4[0] + m4[1]*w4[1] + m4[2]*w4[2] + m4[3]*w4[3];
  X[idx] = v;
  u16 hh = f2bf(v);
  size_t o = toff(r, d, 16);
  pair[o] = hh; pair[o + 4096] = f2bf(v - bf2f(hh));
}

// ---------------- split builders (tiled pair output) ----------------
__global__ void k_split_plain(const float* __restrict__ src, u16* __restrict__ dst,
                              int K, int Kp) {
  int col = blockIdx.x*256 + threadIdx.x;
  if (col >= Kp) return;
  int r = blockIdx.y;
  float v = (col < K) ? src[(size_t)r*K + col] : 0.f;
  u16 hh = f2bf(v);
  size_t o = toff(r, col, Kp >> 5);
  dst[o] = hh; dst[o + 4096] = f2bf(v - bf2f(hh));
}

// circular conv3 gather with row remap: out row r (r0+rr) -> b = r/Lout,
// t = (r%Lout) + tbase; sources wrap in [0,Lsrc).
__global__ void k_split_conv(const float* __restrict__ src, u16* __restrict__ dst,
                             int r0, int Lsrc, int Lout, int tbase,
                             int Din, int K, int Kp) {
  int col = blockIdx.x*256 + threadIdx.x;
  if (col >= Kp) return;
  int rr = blockIdx.y;
  int r = r0 + rr;
  int b = r / Lout, t = (r - b*Lout) + tbase;
  float v = 0.f;
  if (col < K) {
    int c = (col >= 2*Din) ? 2 : ((col >= Din) ? 1 : 0);
    int n = col - c*Din;
    int tt = t + c - 1;
    if (tt < 0) tt = Lsrc - 1; else if (tt >= Lsrc) tt -= Lsrc;
    v = src[((size_t)(b*Lsrc + tt))*Din + n];
  }
  u16 hh = f2bf(v);
  size_t o = toff(rr, col, Kp >> 5);
  dst[o] = hh; dst[o + 4096] = f2bf(v - bf2f(hh));
}

__global__ void k_split_tr(const float* __restrict__ src, u16* __restrict__ dst,
                           int Lc, int Kp) {
  __shared__ float t[32][33];
  int b = blockIdx.z;
  int l0 = blockIdx.x*32, c0 = blockIdx.y*32;
  int lx = threadIdx.x, ly = threadIdx.y;   // (32,8)
  #pragma unroll
  for (int i = 0; i < 4; ++i) {
    int ll = l0 + ly + i*8;
    t[ly + i*8][lx] = (ll < Lc) ? src[((size_t)b*Lc + ll)*DD + c0 + lx] : 0.f;
  }
  __syncthreads();
  int ktn = Kp >> 5;
  #pragma unroll
  for (int i = 0; i < 4; ++i) {
    int ch = c0 + ly + i*8;
    int ll = l0 + lx;
    float v = t[lx][ly + i*8];
    u16 hh = f2bf(v);
    size_t o = toff(b*DD + ch, ll, ktn);
    dst[o] = hh; dst[o + 4096] = f2bf(v - bf2f(hh));
  }
}

// conv-embed weight: [512][1024] (cols >=963 zero)
__global__ void k_build_wconvS(const float* __restrict__ Wv, u16* __restrict__ dst) {
  int col = blockIdx.x*256 + threadIdx.x;
  if (col >= 1024) return;
  int d = blockIdx.y;
  float v = 0.f;
  if (col < 963) {
    int c = (col >= 642) ? 2 : ((col >= 321) ? 1 : 0);
    int n = col - c*321;
    v = Wv[(size_t)d*963 + n*3 + c];
  }
  u16 hh = f2bf(v);
  size_t o = toff(d, col, 32);
  dst[o] = hh; dst[o + 4096] = f2bf(v - bf2f(hh));
}

__global__ void k_build_wtrcS(const float* __restrict__ Wtr, u16* __restrict__ dst) {
  int col = blockIdx.x*256 + threadIdx.x;
  if (col >= 1536) return;
  int n = blockIdx.y;
  int c = col >> 9, d = col & 511;
  float v = Wtr[(size_t)n*1536 + d*3 + c];
  u16 hh = f2bf(v);
  size_t o = toff(n, col, 48);
  dst[o] = hh; dst[o + 4096] = f2bf(v - bf2f(hh));
}

__global__ void k_build_dftS(u16* __restrict__ dst, int L, int Kp) {
  int col = blockIdx.x*256 + threadIdx.x;
  if (col >= Kp) return;
  int mr = blockIdx.y;
  float v = 0.f;
  if (col < L) {
    int m = mr & 63;
    int ph = (m * col) % L;
    float th = 6.2831853071795864f * ((float)ph / (float)L);
    v = (mr < 64) ? cosf(th) : -sinf(th);
  }
  u16 hh = f2bf(v);
  size_t o = toff(mr, col, Kp >> 5);
  dst[o] = hh; dst[o + 4096] = f2bf(v - bf2f(hh));
}

__global__ void k_build_irS(u16* __restrict__ dst, int L) {
  int k = threadIdx.x;   // 0..127
  int ll = blockIdx.y;
  int m = k & 63;
  int ph = (m * ll) % L;
  float th = 6.2831853071795864f * ((float)ph / (float)L);
  float v;
  if (k < 64) v = (m == 0) ? (1.f/(float)L) : (2.f/(float)L) * cosf(th);
  else        v = (m == 0) ? 0.f            : -(2.f/(float)L) * sinf(th);
  u16 hh = f2bf(v);
  size_t o = toff(ll, k, 4);
  dst[o] = hh; dst[o + 4096] = f2bf(v - bf2f(hh));
}

// ---------------- MFMA GEMM: 512-thr / 8-wave, 128x64 tile, 2 K-tiles/phase ---
// EPI bits: 1=bias, 2=res(fp32), 4=gelu, 8=res from tiled pair (Nc=512 layout)
template<int EPI, int WOUT, int KS>
__global__ __launch_bounds__(512)
void k_mg(const u16* __restrict__ A, const u16* __restrict__ B,
          const float* __restrict__ bias, const float* __restrict__ res,
          const u16* __restrict__ resp,
          float* __restrict__ C, u16* __restrict__ Cout,
          int M, int Nc, int K, int Lout)
{
  __shared__ __attribute__((aligned(16))) u16 sA[16384];   // 2 tiles x 16KB
  __shared__ __attribute__((aligned(16))) u16 sB[8192];    // 2 tiles x 8KB

  const int tid  = threadIdx.x;
  const int lane = tid & 63;
  const int wave = tid >> 6;          // 0..7
  const int lr   = lane & 15;
  const int kg   = lane >> 4;
  const int wr   = wave >> 1;         // row group (32 rows)
  const int wc   = wave & 1;          // col group (32 cols)

  const int gx  = gridDim.x;
  const int nwg = gx * gridDim.y;
  const int lid = blockIdx.y * gx + blockIdx.x;
  const int q8  = nwg >> 3, r8 = nwg & 7;
  const int xcd = lid & 7, i8 = lid >> 3;
  const int swz = (xcd < r8 ? xcd*(q8+1) : r8*(q8+1) + (xcd - r8)*q8) + i8;
  const int row0 = (swz / gx) * 128;
  const int col0 = (swz % gx) * 64;

  const int ksteps = K >> 5;
  const int zz = (KS > 1) ? (int)blockIdx.z : 0;
  const int t0 = (KS > 1) ? (int)(((long long)ksteps * zz) / KS) : 0;
  const int t1 = (KS > 1) ? (int)(((long long)ksteps * (zz+1)) / KS) : ksteps;

  const char* gA = (const char*)(A + (((size_t)(row0 >> 7) * ksteps) << 13));
  const char* gB = (const char*)(B + (((size_t)(col0 >> 7) * ksteps) << 13));
  const int bhalf = (col0 & 64) << 6;

  const int wlane = (wave << 10) + (lane << 4);
  const int wbase = (wave << 10);
  const int bso = (wave < 4) ? (bhalf + (wave << 10))
                             : (8192 + bhalf + ((wave - 4) << 10));

  floatx4 acc[2][2] = {};

  auto stageA = [&](int kt, int slot) {
    const char* ta = gA + ((size_t)kt << 14);
    char* la = (char*)sA + (slot << 14);
    gload_lds(ta + wlane, la + wbase);
    gload_lds(ta + 8192 + wlane, la + 8192 + wbase);
  };
  auto stageB = [&](int kt, int slot) {
    const char* tb = gB + ((size_t)kt << 14);
    gload_lds(tb + bso + (lane << 4), (char*)sB + (slot << 13) + wbase);
  };
  auto compute = [&](int slot) {
    const u16* cA = sA + (slot << 13);   // slot * 8192 u16
    const u16* cB = sB + (slot << 12);   // slot * 4096 u16
    short8 ahf[2], alf[2], bhf[2], blf[2];
    #pragma unroll
    for (int f = 0; f < 2; ++f) {
      int row = wr*32 + f*16 + lr;
      int sw = kg ^ (row & 3) ^ ((row >> 2) & 3);
      int off = (row << 5) + (sw << 3);
      ahf[f] = *(const short8*)&cA[off];
      alf[f] = *(const short8*)&cA[4096 + off];
    }
    #pragma unroll
    for (int n = 0; n < 2; ++n) {
      int row = wc*32 + n*16 + lr;
      int sw = kg ^ (row & 3) ^ ((row >> 2) & 3);
      int off = (row << 5) + (sw << 3);
      bhf[n] = *(const short8*)&cB[off];
      blf[n] = *(const short8*)&cB[2048 + off];
    }
    #pragma unroll
    for (int f = 0; f < 2; ++f)
      #pragma unroll
      for (int n = 0; n < 2; ++n) {
        acc[f][n] = __builtin_amdgcn_mfma_f32_16x16x32_bf16(ahf[f], bhf[n], acc[f][n], 0, 0, 0);
        acc[f][n] = __builtin_amdgcn_mfma_f32_16x16x32_bf16(ahf[f], blf[n], acc[f][n], 0, 0, 0);
        acc[f][n] = __builtin_amdgcn_mfma_f32_16x16x32_bf16(alf[f], bhf[n], acc[f][n], 0, 0, 0);
      }
  };

  for (int kt = t0; kt < t1; ) {
    const bool pair = (kt + 1 < t1);
    stageA(kt, 0); stageB(kt, 0);
    if (pair) { stageA(kt + 1, 1); stageB(kt + 1, 1); }
    __syncthreads();
    compute(0);
    if (pair) compute(1);
    __syncthreads();
    kt += pair ? 2 : 1;
  }

  if (KS > 1) {
    float* Cp = C + (size_t)zz * ((size_t)M * Nc);
    #pragma unroll
    for (int n = 0; n < 2; ++n) {
      int cN = col0 + wc*32 + n*16 + lr;
      if (cN >= Nc) continue;
      #pragma unroll
      for (int f = 0; f < 2; ++f)
        #pragma unroll
        for (int i = 0; i < 4; ++i) {
          int rM = row0 + wr*32 + f*16 + kg*4 + i;
          if (rM >= M) continue;
          Cp[(size_t)rM * Nc + cN] = acc[f][n][i];
        }
    }
  } else {
    #pragma unroll
    for (int n = 0; n < 2; ++n) {
      int cN = col0 + wc*32 + n*16 + lr;
      if (cN >= Nc) continue;
      #pragma unroll
      for (int f = 0; f < 2; ++f) {
        #pragma unroll
        for (int i = 0; i < 4; ++i) {
          int rM = row0 + wr*32 + f*16 + kg*4 + i;
          if (rM >= M) continue;
          float v = acc[f][n][i];
          if (EPI & 1) v += bias[cN];
          if (EPI & 4) v = 0.5f * v * (1.f + erff(v * 0.7071067811865476f));
          if (EPI & 2) v += res[(size_t)rM * Nc + cN];
          if (EPI & 8) {
            size_t ro = toff(rM, cN, 16);
            v += bf2f(resp[ro]) + bf2f(resp[ro + 4096]);
          }
          if (WOUT == 1) {
            u16 hh = f2bf(v);
            size_t o = toff(rM, cN, Nc >> 5);
            Cout[o] = hh; Cout[o + 4096] = f2bf(v - bf2f(hh));
          } else if (WOUT == 2) {
            int b = rM >> 9, ch = rM & 511;
            int fl = ch * Lout + cN;
            int r2 = b * Lout + (fl >> 9);
            int c2 = fl & 511;
            u16 hh = f2bf(v);
            size_t o = toff(r2, c2, 16);
            Cout[o] = hh; Cout[o + 4096] = f2bf(v - bf2f(hh));
          } else {
            C[(size_t)rM * Nc + cN] = v;
          }
        }
      }
    }
  }
}

// ---------------- split-K reduce (fixed order, deterministic) ----------------
__global__ void k_red(const float* __restrict__ p, int parts, size_t stride,
                      const float* __restrict__ res, float* __restrict__ out, size_t n) {
  size_t i = (size_t)blockIdx.x*256 + threadIdx.x;
  if (i >= n) return;
  float s = res ? res[i] : 0.f;
  for (int z = 0; z < parts; ++z) s += p[(size_t)z*stride + i];
  out[i] = s;
}

// ---------------- mode mix: m-coalesced, emits tiled bf16 pair ----------------
__global__ __launch_bounds__(256)
void k_modemix(const float* __restrict__ ftbuf, const float* __restrict__ fr,
               const float* __restrict__ fi, u16* __restrict__ sel, float scale)
{
  int tid = threadIdx.x;
  int m = tid & 63, ol = tid >> 6;
  int h = blockIdx.y, o = blockIdx.x*4 + ol;
  int b0 = blockIdx.z * 8;
  float accr[8] = {}, acci[8] = {};
  const float* fb = ftbuf + (((size_t)b0*DD + h*64)*128) + m;
  size_t wof = ((((size_t)h*64)*64 + o) << 6) + m;
  for (int e = 0; e < 64; ++e) {
    float wr = fr[wof];
    float wi = fi[wof];
    const float* fe = fb + e*128;
    #pragma unroll
    for (int b = 0; b < 8; ++b) {
      float xr = fe[(size_t)b*65536];
      float xi = fe[(size_t)b*65536 + 64];
      accr[b] += xr*wr - xi*wi;
      acci[b] += xr*wi + xi*wr;
    }
    wof += 4096;
  }
  #pragma unroll
  for (int b = 0; b < 8; ++b) {
    int row = (b0 + b)*DD + h*64 + o;
    float vr = accr[b]*scale, vi2 = acci[b]*scale;
    u16 hr = f2bf(vr);
    size_t o1 = toff(row, m, 4);
    sel[o1] = hr; sel[o1 + 4096] = f2bf(vr - bf2f(hr));
    u16 hi2 = f2bf(vi2);
    size_t o2 = toff(row, m + 64, 4);
    sel[o2] = hi2; sel[o2 + 4096] = f2bf(vi2 - bf2f(hi2));
  }
}

// ---------------- cross attention ----------------
__global__ __launch_bounds__(256)
void k_cross_qk(const float* __restrict__ qf, const float* __restrict__ kf,
                float* __restrict__ ab)
{
  int bh = blockIdx.x; int b = bh >> 3, h = bh & 7;
  __shared__ float qr[32][64], qi[32][64], kr[32][64], ki[32][64];
  int tid = threadIdx.x;
  int tx = tid & 15, ty = tid >> 4;
  float ar[4][4] = {}, ai[4][4] = {};
  for (int e0 = 0; e0 < 64; e0 += 32) {
    for (int it = 0; it < 8; ++it) {
      int idx = tid + it*256;
      int e = idx >> 6, x = idx & 63;
      size_t rof = ((size_t)b*DD + h*64 + e0 + e)*128;
      qr[e][x] = qf[rof + x]; qi[e][x] = qf[rof + 64 + x];
      kr[e][x] = kf[rof + x]; ki[e][x] = kf[rof + 64 + x];
    }
    __syncthreads();
    for (int e = 0; e < 32; ++e) {
      float xr[4], xi2[4], yr[4], yi[4];
      #pragma unroll
      for (int i = 0; i < 4; ++i) { xr[i] = qr[e][ty*4+i]; xi2[i] = qi[e][ty*4+i]; }
      #pragma unroll
      for (int j = 0; j < 4; ++j) { yr[j] = kr[e][tx*4+j]; yi[j] = ki[e][tx*4+j]; }
      #pragma unroll
      for (int i = 0; i < 4; ++i)
        #pragma unroll
        for (int j = 0; j < 4; ++j) {
          ar[i][j] += xr[i]*yr[j] - xi2[i]*yi[j];
          ai[i][j] += xr[i]*yi[j] + xi2[i]*yr[j];
        }
    }
    __syncthreads();
  }
  #pragma unroll
  for (int i = 0; i < 4; ++i)
    #pragma unroll
    for (int j = 0; j < 4; ++j) {
      float txv = tanhf(ar[i][j]);
      float tyv = tanf(ai[i][j]);
      float den = 1.f + txv*txv*tyv*tyv;
      float re = txv*(1.f + tyv*tyv) / den;
      float im = tyv*(1.f - txv*txv) / den;
      size_t of = ((size_t)bh*64 + (ty*4+i))*128 + tx*4 + j;
      ab[of] = re; ab[of + 64] = im;
    }
}

__global__ __launch_bounds__(256)
void k_cross_v(const float* __restrict__ ab, const float* __restrict__ kf,
               float* __restrict__ v)
{
  int bh = blockIdx.x; int b = bh >> 3, h = bh & 7;
  __shared__ float ar[64][32], ai[64][32], kr[64][32], ki[64][32];
  int tid = threadIdx.x;
  int tx = tid & 15, ty = tid >> 4;
  float vr[4][4] = {}, vi[4][4] = {};
  for (int y0 = 0; y0 < 64; y0 += 32) {
    for (int it = 0; it < 8; ++it) {
      int idx = tid + it*256;
      int r = idx >> 5, y = idx & 31;
      ar[r][y] = ab[((size_t)bh*64 + r)*128 + y0 + y];
      ai[r][y] = ab[((size_t)bh*64 + r)*128 + 64 + y0 + y];
      kr[r][y] = kf[((size_t)b*DD + h*64 + r)*128 + y0 + y];
      ki[r][y] = kf[((size_t)b*DD + h*64 + r)*128 + 64 + y0 + y];
    }
    __syncthreads();
    for (int y = 0; y < 32; ++y) {
      float er[4], ei[4], xr[4], xi2[4];
      #pragma unroll
      for (int i = 0; i < 4; ++i) { er[i] = kr[ty*4+i][y]; ei[i] = ki[ty*4+i][y]; }
      #pragma unroll
      for (int j = 0; j < 4; ++j) { xr[j] = ar[tx*4+j][y]; xi2[j] = ai[tx*4+j][y]; }
      #pragma unroll
      for (int i = 0; i < 4; ++i)
        #pragma unroll
        for (int j = 0; j < 4; ++j) {
          vr[i][j] += xr[j]*er[i] - xi2[j]*ei[i];
          vi[i][j] += xr[j]*ei[i] + xi2[j]*er[i];
        }
    }
    __syncthreads();
  }
  #pragma unroll
  for (int i = 0; i < 4; ++i)
    #pragma unroll
    for (int j = 0; j < 4; ++j) {
      size_t of = ((size_t)b*DD + h*64 + ty*4 + i)*128 + tx*4 + j;
      v[of] = vr[i][j]; v[of + 64] = vi[i][j];
    }
}

// ---------------- LN + column-mean subtract ----------------
__global__ __launch_bounds__(256)
void k_ln(const float* __restrict__ x, const float* __restrict__ g,
          const float* __restrict__ be, float* __restrict__ out)
{
  int r = blockIdx.x; int tid = threadIdx.x;
  float v1 = x[(size_t)r*DD + tid], v2 = x[(size_t)r*DD + 256 + tid];
  float s = v1 + v2, s2 = v1*v1 + v2*v2;
  #pragma unroll
  for (int off = 32; off; off >>= 1) { s += __shfl_down(s, off, 64); s2 += __shfl_down(s2, off, 64); }
  __shared__ float red[8];
  int wid = tid >> 6, lane = tid & 63;
  if (lane == 0) { red[wid] = s; red[4 + wid] = s2; }
  __syncthreads();
  if (tid == 0) {
    float a = red[0]+red[1]+red[2]+red[3];
    float b2 = red[4]+red[5]+red[6]+red[7];
    float mu = a / 512.f;
    float var = b2 / 512.f - mu*mu;
    red[0] = mu; red[1] = rsqrtf(var + 1e-5f);
  }
  __syncthreads();
  float mu = red[0], inv = red[1];
  out[(size_t)r*DD + tid]       = (v1 - mu)*inv*g[tid]       + be[tid];
  out[(size_t)r*DD + 256 + tid] = (v2 - mu)*inv*g[256 + tid] + be[256 + tid];
}

__global__ void k_colsum_part(const float* __restrict__ x, float* __restrict__ part,
                              int L, int chl, int nch) {
  int d = threadIdx.x;
  int b = blockIdx.x, c = blockIdx.y;
  int l0 = c*chl, l1 = l0 + chl; if (l1 > L) l1 = L;
  float s = 0.f;
  for (int l = l0; l < l1; ++l) s += x[(((size_t)b*L + l) << 9) + d];
  part[((size_t)(b*nch + c) << 9) + d] = s;
}
__global__ void k_colsum_fin(const float* __restrict__ part, float* __restrict__ cm,
                             int nch, float inv) {
  int i = blockIdx.x*256 + threadIdx.x;
  int b = i >> 9, d = i & 511;
  float s = 0.f;
  for (int c = 0; c < nch; ++c) s += part[((size_t)(b*nch + c) << 9) + d];
  cm[i] = s * inv;
}
// encoder: full rows
__global__ void k_csub_pair(const float* __restrict__ x, const float* __restrict__ cm,
                            u16* __restrict__ dst, int L) {
  size_t idx = (size_t)blockIdx.x*256 + threadIdx.x;
  if (idx >= (size_t)BB*L*DD) return;
  int d = (int)(idx & 511);
  int r = (int)(idx >> 9);
  int b = r / L;
  float v = x[idx] - cm[(b << 9) | d];
  u16 hh = f2bf(v);
  size_t o = toff(r, d, 16);
  dst[o] = hh; dst[o + 4096] = f2bf(v - bf2f(hh));
}
// decoder: remapped rows (b, 360+tt) -> r' = b*720+tt, pair of 11520 rows
__global__ void k_csub_pairR(const float* __restrict__ x, const float* __restrict__ cm,
                             u16* __restrict__ dst) {
  size_t idx = (size_t)blockIdx.x*256 + threadIdx.x;
  if (idx >= (size_t)BB*LEN_E*DD) return;
  int d = (int)(idx & 511);
  int rp = (int)(idx >> 9);
  int b = rp / LEN_E, tt = rp - b*LEN_E;
  float v = x[(((size_t)(b*LEN_D + 360 + tt)) << 9) + d] - cm[(b << 9) | d];
  u16 hh = f2bf(v);
  size_t o = toff(rp, d, 16);
  dst[o] = hh; dst[o + 4096] = f2bf(v - bf2f(hh));
}

// ---------------- series decomp: sliding-window running sum ----------------
// OUTP=0: fp32 only; OUTP=1: pair only; OUTP=2: both.
template<int ACC, int OUTP>
__global__ __launch_bounds__(512)
void k_decomp(const float* __restrict__ x, float* __restrict__ out,
              u16* __restrict__ outp, float* __restrict__ tsum, int L, int chl)
{
  int d = threadIdx.x;            // 512
  int b = blockIdx.x;
  int l0 = blockIdx.y * chl;
  int l1 = l0 + chl; if (l1 > L) l1 = L;
  const float* xb = x + (((size_t)b*L) << 9) + d;
  float s = 0.f;
  #pragma unroll
  for (int j = -12; j <= 12; ++j) {
    int lc = l0 + j; lc = lc < 0 ? 0 : (lc >= L ? L-1 : lc);
    s += xb[(size_t)lc << 9];
  }
  for (int l = l0; l < l1; ++l) {
    int r = b*L + l;
    size_t o = ((size_t)r << 9) + d;
    float ma = s * (1.f/25.f);
    float v = xb[(size_t)l << 9] - ma;
    if (OUTP == 0 || OUTP == 2) out[o] = v;
    if (OUTP == 1 || OUTP == 2) {
      size_t op = toff(r, d, 16);
      u16 hh = f2bf(v);
      outp[op] = hh; outp[op + 4096] = f2bf(v - bf2f(hh));
    }
    if (ACC == 1) tsum[o] += ma;
    if (ACC == 2) tsum[o] = ma;
    int la = l + 13; if (la >= L) la = L - 1;
    int lr = l - 12; if (lr < 0) lr = 0;
    s += xb[(size_t)la << 9] - xb[(size_t)lr << 9];
  }
}

// =====================================================================
extern "C" void kernel_launch(void* const* d_in, const int* in_sizes, int n_in,
                              void* d_out, int out_size, void* d_ws, size_t ws_size,
                              hipStream_t stream)
{
  (void)in_sizes; (void)n_in; (void)out_size; (void)ws_size;
  const float* history = (const float*)d_in[0];
  const float* future  = (const float*)d_in[1];
  const float* Wv_enc  = (const float*)d_in[2];
  const float* Wt_enc  = (const float*)d_in[3];
  const float* Wv_dec  = (const float*)d_in[4];
  const float* Wt_dec  = (const float*)d_in[5];
  const float* eWq = (const float*)d_in[6];
  const float* ebq = (const float*)d_in[7];
  const float* efr = (const float*)d_in[8];
  const float* efi = (const float*)d_in[9];
  const float* eWo = (const float*)d_in[10];
  const float* ebo = (const float*)d_in[11];
  const float* eW1 = (const float*)d_in[12];
  const float* eW2 = (const float*)d_in[13];
  const float* g_enc = (const float*)d_in[14];
  const float* b_enc = (const float*)d_in[15];
  const float* dWq = (const float*)d_in[16];
  const float* dbq = (const float*)d_in[17];
  const float* dfr = (const float*)d_in[18];
  const float* dfi = (const float*)d_in[19];
  const float* dWo = (const float*)d_in[20];
  const float* dbo = (const float*)d_in[21];
  const float* cWq = (const float*)d_in[22];
  const float* cbq = (const float*)d_in[23];
  const float* cWk = (const float*)d_in[24];
  const float* cbk = (const float*)d_in[25];
  const float* cfr = (const float*)d_in[26];
  const float* cfi = (const float*)d_in[27];
  const float* cWo = (const float*)d_in[28];
  const float* cbo = (const float*)d_in[29];
  const float* dW1 = (const float*)d_in[30];
  const float* dW2 = (const float*)d_in[31];
  const float* Wtr = (const float*)d_in[32];
  const float* g_dec = (const float*)d_in[33];
  const float* b_dec = (const float*)d_in[34];
  const float* Wp  = (const float*)d_in[35];
  const float* bp  = (const float*)d_in[36];

  float* ws = (float*)d_ws;
  size_t off = 0;
  auto alloc = [&](size_t n) { float* p = ws + off; off += (n + 63) & ~(size_t)63; return p; };

  const size_t SL = 1048576;
  const int MP = BB * LEN_E;   // remapped output rows = 11520

  float* btrend = alloc((size_t)BB*LEN_D*NV);   // uses first MP*NV
  float* bTsum  = alloc((size_t)BB*LEN_D*DD);
  float* bX     = alloc((size_t)BB*LEN_D*DD);
  float* bT     = alloc((size_t)BB*LEN_D*DD);
  float* bencout= alloc((size_t)BB*LEN_E*DD);
  float* bseas  = alloc((size_t)BB*LEN_D*NV);
  float* R      = alloc((size_t)11600000);
  float* SB     = alloc((size_t)2*SL + 128);
  float* WceS   = alloc((size_t)512*1024);
  float* WcdS   = alloc((size_t)512*1024);
  float* WtrcS  = alloc((size_t)384*1536);
  float* D720S  = alloc((size_t)128*768);
  float* D1080S = alloc((size_t)128*1088);
  float* I720S  = alloc((size_t)768*128);
  float* I1080S = alloc((size_t)1152*128);
  float* bxme   = alloc((size_t)BB*LEN_E*4);
  float* bxmd   = alloc((size_t)BB*LEN_D*4);
  float* bmean  = alloc((size_t)BB*NV);
  float* bpart  = alloc((size_t)BB*9*DD);
  float* bcm    = alloc((size_t)BB*DD);
  float* bmsp   = alloc((size_t)BB*10*NV);

  float* bxe = bT;   // prep alias (dead before T written)

  auto U = [](float* p) { return (u16*)p; };

  auto splitP = [&](const float* src, float* dst, int M, int K) {
    dim3 g((K + 255)/256, M);
    k_split_plain<<<g,256,0,stream>>>(src, U(dst), K, K);
  };
  auto splitC = [&](const float* src, float* dst, int r0, int Mc, int Lsrc, int Lout,
                    int tbase, int Din, int K, int Kp) {
    dim3 g((Kp + 255)/256, Mc);
    k_split_conv<<<g,256,0,stream>>>(src, U(dst), r0, Lsrc, Lout, tbase, Din, K, Kp);
  };
  auto splitT = [&](const float* src, float* dst, int Lc, int Kp) {
    dim3 g(Kp/32, 16, BB), b(32, 8);
    k_split_tr<<<g,b,0,stream>>>(src, U(dst), Lc, Kp);
  };
  auto red = [&](const float* p, int parts, size_t stride, const float* res,
                 float* out, size_t n) {
    k_red<<<(int)((n + 255)/256),256,0,stream>>>(p, parts, stride, res, out, n);
  };

  auto decomp = [&](const float* in, float* out, int L, int acc) {
    int chl = 45;
    int nch = (L + chl - 1) / chl;
    dim3 g(BB, nch);
    if (acc == 1)      k_decomp<1,0><<<g,512,0,stream>>>(in, out, nullptr, bTsum, L, chl);
    else if (acc == 2) k_decomp<2,0><<<g,512,0,stream>>>(in, out, nullptr, bTsum, L, chl);
    else               k_decomp<0,0><<<g,512,0,stream>>>(in, out, nullptr, nullptr, L, chl);
  };
  auto decompP = [&](const float* in, u16* outp, int L, int acc) {
    int chl = 45;
    int nch = (L + chl - 1) / chl;
    dim3 g(BB, nch);
    if (acc == 1) k_decomp<1,1><<<g,512,0,stream>>>(in, nullptr, outp, bTsum, L, chl);
    else          k_decomp<0,1><<<g,512,0,stream>>>(in, nullptr, outp, nullptr, L, chl);
  };
  auto decompD = [&](const float* in, float* out, u16* outp, int L, int acc) {
    int chl = 45;
    int nch = (L + chl - 1) / chl;
    dim3 g(BB, nch);
    if (acc == 2)      k_decomp<2,2><<<g,512,0,stream>>>(in, out, outp, bTsum, L, chl);
    else               k_decomp<0,2><<<g,512,0,stream>>>(in, out, outp, nullptr, L, chl);
  };

  // FFN: out = reconstruct(inPair) + gelu(inPair@W1.T)@W2.T
  // GEMM2 is single-K with residual-from-pair epilogue (EPI&8) -> no scratch/reduce.
  const int CHP = 4352;
  float* SA2 = R;   // hidden tiled pair
  auto ffn = [&](const u16* inPair, float* out, const float* W1, const float* W2,
                 int M) {
    splitP(W1, SB, DFF2, DD);
    splitP(W2, SB + SL, DD, DFF2);
    for (int r0 = 0; r0 < M; r0 += CHP) {
      int mc = M - r0; if (mc > CHP) mc = CHP;
      const u16* Ap = inPair + ((size_t)(r0 >> 7) << 17);   // 128 rows = 1<<17 u16
      k_mg<4,1,1><<<dim3(32,(mc+127)/128,1),512,0,stream>>>(
          Ap, U(SB), nullptr, nullptr, nullptr, nullptr, U(SA2), mc, DFF2, DD, 0);
      k_mg<8,0,1><<<dim3(8,(mc+127)/128,1),512,0,stream>>>(
          U(SA2), U(SB+SL), nullptr, nullptr, Ap, out + (size_t)r0*DD, nullptr,
          mc, DD, DFF2, 0);
    }
  };

  // X += fourier_self(X); X pair must be pre-staged in R (K=512 layout).
  auto fourier_self = [&](float* X, float* T, int L, int KpL, float* DLS, float* ILS,
                          const float* Wq, const float* bq, const float* fr, const float* fi,
                          const float* Wo, const float* bo) {
    int M = BB * L;
    size_t MN8 = (size_t)8192*128;
    float* bqf   = R + 9*SL;
    float* bselp = R + 10*SL;
    splitP(Wq, SB, DD, DD);
    k_mg<1,0,1><<<dim3(8,(M+127)/128,1),512,0,stream>>>(
        U(R), U(SB), bq, nullptr, nullptr, T, nullptr, M, DD, DD, 0);
    splitT(T, R, L, KpL);
    k_mg<0,0,4><<<dim3(2,64,4),512,0,stream>>>(
        U(R), U(DLS), nullptr, nullptr, nullptr, T, nullptr, BB*DD, 128, KpL, 0);
    red(T, 4, MN8, nullptr, bqf, MN8);
    k_modemix<<<dim3(16,8,2),256,0,stream>>>(bqf, fr, fi, U(bselp), 1.0f);
    k_mg<0,2,1><<<dim3((L+63)/64,64,1),512,0,stream>>>(   // irfft -> pair @R
        U(bselp), U(ILS), nullptr, nullptr, nullptr, nullptr, U(R), BB*DD, L, 128, L);
    splitP(Wo, SB, DD, DD);
    k_mg<3,0,1><<<dim3(8,(M+127)/128,1),512,0,stream>>>(
        U(R), U(SB), bo, X, nullptr, X, nullptr, M, DD, DD, 0);
  };

  auto myln_pair = [&](const float* in, float* tmp, float* pairdst,
                       const float* g, const float* b, int L) {
    k_ln<<<BB*L,256,0,stream>>>(in, g, b, tmp);
    int chl = L / 9;
    k_colsum_part<<<dim3(BB,9),512,0,stream>>>(tmp, bpart, L, chl, 9);
    k_colsum_fin<<<32,256,0,stream>>>(bpart, bcm, 9, 1.f/(float)L);
    size_t n = (size_t)BB*L*DD;
    k_csub_pair<<<(int)((n+255)/256),256,0,stream>>>(tmp, bcm, U(pairdst), L);
  };

  // ---------------- prep ----------------
  k_extract_x<<<(BB*LEN_E*NV + 255)/256,256,0,stream>>>(history, bxe);
  k_marks_enc<<<(BB*LEN_E*4 + 255)/256,256,0,stream>>>(history, bxme);
  k_marks_dec<<<(BB*LEN_D*4 + 255)/256,256,0,stream>>>(future, bxme, bxmd);
  k_ms_part<<<dim3(BB,10),384,0,stream>>>(bxe, bmsp, 72, 10);
  k_ms_fin<<<(BB*NV + 255)/256,256,0,stream>>>(bmsp, bmean, 10);
  k_init_decomp<<<(BB*LEN_D*NV + 255)/256,256,0,stream>>>(bxe, bmean, bseas, btrend);
  k_build_wconvS<<<dim3(4,512),256,0,stream>>>(Wv_enc, U(WceS));
  k_build_wconvS<<<dim3(4,512),256,0,stream>>>(Wv_dec, U(WcdS));
  k_build_wtrcS<<<dim3(6,321),256,0,stream>>>(Wtr, U(WtrcS));
  k_build_dftS<<<dim3(3,128),256,0,stream>>>(U(D720S), LEN_E, 768);
  k_build_dftS<<<dim3(5,128),256,0,stream>>>(U(D1080S), LEN_D, 1088);
  k_build_irS<<<dim3(1,LEN_E),128,0,stream>>>(U(I720S), LEN_E);
  k_build_irS<<<dim3(1,LEN_D),128,0,stream>>>(U(I1080S), LEN_D);

  // ---------------- encoder ----------------
  int ME = BB * LEN_E;
  for (int r0 = 0; r0 < ME; r0 += 5760) {
    splitC(bxe, R, r0, 5760, LEN_E, LEN_E, 0, NV, 963, 1024);
    k_mg<0,0,1><<<dim3(8,45,1),512,0,stream>>>(
        U(R), U(WceS), nullptr, nullptr, nullptr, bX + (size_t)r0*DD, nullptr,
        5760, DD, 1024, 0);
  }
  k_marks_add<<<(ME*DD + 255)/256,256,0,stream>>>(bX, bxme, Wt_enc, U(R), ME);

  float *X = bX, *T = bT;
  for (int i = 0; i < 2; ++i) {
    fourier_self(X, T, LEN_E, 768, D720S, I720S,
                 eWq + (size_t)i*DD*DD, ebq + (size_t)i*DD,
                 efr + (size_t)i*HHN*64*64*64, efi + (size_t)i*HHN*64*64*64,
                 eWo + (size_t)i*DD*DD, ebo + (size_t)i*DD);
    decompP(X, U(T), LEN_E, 0);                         // T = seasonal PAIR
    ffn(U(T), X, eW1 + (size_t)i*DFF2*DD, eW2 + (size_t)i*DD*DFF2, ME);
    if (i == 0) decompD(X, T, U(R), LEN_E, 0);          // T fp32 + R pair (next fourier)
    else        decomp(X, T, LEN_E, 0);                 // T fp32 only
    { float* tmp = X; X = T; T = tmp; }
  }
  myln_pair(X, T, bencout, g_enc, b_enc, LEN_E);   // bencout = tiled pair (ME,512)

  // ---------------- decoder ----------------
  int MD = BB * LEN_D;
  for (int r0 = 0; r0 < MD; r0 += 8640) {
    splitC(bseas, R, r0, 8640, LEN_D, LEN_D, 0, NV, 963, 1024);
    k_mg<0,0,1><<<dim3(8,68,1),512,0,stream>>>(
        U(R), U(WcdS), nullptr, nullptr, nullptr, X + (size_t)r0*DD, nullptr,
        8640, DD, 1024, 0);
  }
  k_marks_add<<<(MD*DD + 255)/256,256,0,stream>>>(X, bxmd, Wt_dec, U(R), MD);

  fourier_self(X, T, LEN_D, 1088, D1080S, I1080S, dWq, dbq, dfr, dfi, dWo, dbo);

  decompD(X, T, U(R), LEN_D, 2);      // T fp32 + R pair, tsum = t1

  // cross attention (q-projection first: consumes R pair before splitT clobbers R)
  {
    size_t MN8 = (size_t)8192*128;
    float* bkf = R + 9*SL;
    float* bqf = R + 10*SL;
    splitP(cWq, SB, DD, DD);
    k_mg<1,0,1><<<dim3(8,135,1),512,0,stream>>>(         // q proj from R pair
        U(R), U(SB), cbq, nullptr, nullptr, X, nullptr, MD, DD, DD, 0);
    splitT(X, R, LEN_D, 1088);
    k_mg<0,0,4><<<dim3(2,64,4),512,0,stream>>>(
        U(R), U(D1080S), nullptr, nullptr, nullptr, X, nullptr, BB*DD, 128, 1088, 0);
    red(X, 4, MN8, nullptr, bqf, MN8);
    splitP(cWk, SB, DD, DD);
    k_mg<1,0,1><<<dim3(8,90,1),512,0,stream>>>(          // k proj from bencout pair
        U(bencout), U(SB), cbk, nullptr, nullptr, X, nullptr, ME, DD, DD, 0);
    splitT(X, R, LEN_E, 768);
    k_mg<0,0,4><<<dim3(2,64,4),512,0,stream>>>(
        U(R), U(D720S), nullptr, nullptr, nullptr, X, nullptr, BB*DD, 128, 768, 0);
    red(X, 4, MN8, nullptr, bkf, MN8);
    float* ba = R;
    float* bv = R + SL;
    float* bselp = R + 2*SL;
    k_cross_qk<<<BB*HHN,256,0,stream>>>(bqf, bkf, ba);
    k_cross_v<<<BB*HHN,256,0,stream>>>(ba, bkf, bv);
    k_modemix<<<dim3(16,8,2),256,0,stream>>>(bv, cfr, cfi, U(bselp), 1.0f/262144.0f);
    k_mg<0,2,1><<<dim3(17,64,1),512,0,stream>>>(        // irfft -> pair @X
        U(bselp), U(I1080S), nullptr, nullptr, nullptr, nullptr, U(X), BB*DD, LEN_D, 128, LEN_D);
    splitP(cWo, SB, DD, DD);
    k_mg<3,0,1><<<dim3(8,135,1),512,0,stream>>>(
        U(X), U(SB), cbo, T, nullptr, T, nullptr, MD, DD, DD, 0);
  }

  decompP(T, U(X), LEN_D, 1);         // X = seasonal PAIR, tsum += t2
  ffn(U(X), T, dW1, dW2, MD);         // T = x + FFN(x)
  decomp(T, X, LEN_D, 1);             // X fp32, tsum += t3

  // decoder LN + col-mean; emit REMAPPED pair (rows t>=360 only) into bencout
  {
    k_ln<<<BB*LEN_D,256,0,stream>>>(X, g_dec, b_dec, T);
    k_colsum_part<<<dim3(BB,9),512,0,stream>>>(T, bpart, LEN_D, LEN_D/9, 9);
    k_colsum_fin<<<32,256,0,stream>>>(bpart, bcm, 9, 1.f/(float)LEN_D);
    k_csub_pairR<<<(int)(((size_t)MP*DD + 255)/256),256,0,stream>>>(T, bcm, U(bencout));
  }

  // trend conv first (in-place accumulate into btrend), then seasonal -> d_out
  for (int r0 = 0; r0 < MP; r0 += 5760) {
    splitC(bTsum, R, r0, 5760, LEN_D, LEN_E, 360, DD, 1536, 1536);
    k_mg<2,0,1><<<dim3(6,45,1),512,0,stream>>>(
        U(R), U(WtrcS), nullptr, btrend + (size_t)r0*NV, nullptr,
        btrend + (size_t)r0*NV, nullptr, 5760, NV, 1536, 0);
  }
  splitP(Wp, SB, NV, DD);
  k_mg<3,0,1><<<dim3(6,90,1),512,0,stream>>>(            // seasonal + trend -> out
      U(bencout), U(SB), bp, btrend, nullptr, (float*)d_out, nullptr, MP, NV, DD, 0);
}

// Round 22
// 2121.941 us; speedup vs baseline: 1.0889x; 1.0889x over previous
//
#include <hip/hip_runtime.h>
#include <math.h>

#define BB 16
#define DD 512
#define HHN 8
#define LEN_E 720
#define LEN_D 1080
#define NV 321
#define DFF2 2048

typedef __attribute__((ext_vector_type(8))) short short8;
typedef __attribute__((ext_vector_type(4))) float floatx4;
typedef unsigned short u16;

__device__ __forceinline__ u16 f2bf(float v) {
  unsigned u = __builtin_bit_cast(unsigned, v);
  u += 0x7FFFu + ((u >> 16) & 1u);
  return (u16)(u >> 16);
}
__device__ __forceinline__ float bf2f(u16 h) {
  unsigned u = ((unsigned)h) << 16;
  return __builtin_bit_cast(float, u);
}

// element offset (u16) of (r,k) in tiled pair buffer; lo at +4096.
// tile = 128 rows x 32 cols, 8192 u16 (hi 4096 + lo 4096), XOR-swizzled slots.
__device__ __forceinline__ size_t toff(int r, int k, int ktn) {
  int rt = r >> 7, rr = r & 127;
  int kt = k >> 5, kk = k & 31;
  int sw = (kk >> 3) ^ (rr & 3) ^ ((rr >> 2) & 3);
  return (((size_t)(rt * ktn + kt)) << 13) + (rr << 5) + (sw << 3) + (kk & 7);
}

__device__ __forceinline__ void gload_lds(const void* g, void* l) {
  __builtin_amdgcn_global_load_lds(
      (const __attribute__((address_space(1))) unsigned int*)g,
      (__attribute__((address_space(3))) unsigned int*)l, 16, 0, 0);
}

// ---------------- prep kernels ----------------
__global__ void k_extract_x(const float* __restrict__ hist, float* __restrict__ xe) {
  int idx = blockIdx.x * 256 + threadIdx.x;
  if (idx >= BB*LEN_E*NV) return;
  xe[idx] = hist[(size_t)idx * 5];
}

__global__ void k_marks_enc(const float* __restrict__ hist, float* __restrict__ xme) {
  int idx = blockIdx.x * 256 + threadIdx.x;
  if (idx >= BB*LEN_E*4) return;
  int f = idx & 3;
  int r = idx >> 2;
  xme[idx] = hist[((size_t)r * NV) * 5 + 1 + f];
}

__global__ void k_marks_dec(const float* __restrict__ fut, const float* __restrict__ xme,
                            float* __restrict__ xmd) {
  int idx = blockIdx.x * 256 + threadIdx.x;
  if (idx >= BB*LEN_D*4) return;
  int f = idx & 3;
  int r = idx >> 2;
  int t = r % LEN_D, b = r / LEN_D;
  float v;
  if (t < 360) v = xme[((b*LEN_E) + 360 + t)*4 + f];
  else v = fut[(((size_t)(b*LEN_E + (t-360))) * NV) * 5 + 1 + f];
  xmd[idx] = v;
}

__global__ void k_ms_part(const float* __restrict__ xe, float* __restrict__ part,
                          int chl, int nch) {
  int n = threadIdx.x;
  if (n >= NV) return;
  int b = blockIdx.x, c = blockIdx.y;
  int l0 = c*chl, l1 = l0 + chl; if (l1 > LEN_E) l1 = LEN_E;
  float s = 0.f;
  for (int l = l0; l < l1; ++l) s += xe[((size_t)b*LEN_E + l)*NV + n];
  part[((size_t)b*nch + c)*NV + n] = s;
}
__global__ void k_ms_fin(const float* __restrict__ part, float* __restrict__ mb, int nch) {
  int i = blockIdx.x*256 + threadIdx.x;
  if (i >= BB*NV) return;
  int b = i / NV, n = i % NV;
  float s = 0.f;
  for (int c = 0; c < nch; ++c) s += part[((size_t)b*nch + c)*NV + n];
  mb[i] = s * (1.f/(float)LEN_E);
}

// seas full (B,1080,NV); trend ONLY remapped rows (b, t>=360) -> (b*720+(t-360), n)
__global__ void k_init_decomp(const float* __restrict__ xe, const float* __restrict__ mb,
                              float* __restrict__ seas, float* __restrict__ trend) {
  int idx = blockIdx.x * 256 + threadIdx.x;
  if (idx >= BB*LEN_D*NV) return;
  int n = idx % NV; int r = idx / NV; int t = r % LEN_D; int b = r / LEN_D;
  if (t < 360) {
    int l = 360 + t;
    float s = 0.f;
    for (int j = -12; j <= 12; ++j) {
      int lc = l + j; if (lc > LEN_E-1) lc = LEN_E-1; if (lc < 0) lc = 0;
      s += xe[((size_t)b*LEN_E + lc)*NV + n];
    }
    float ma = s * (1.f/25.f);
    seas[idx]  = xe[((size_t)b*LEN_E + l)*NV + n] - ma;
  } else {
    trend[((size_t)(b*LEN_E + (t - 360)))*NV + n] = mb[b*NV + n];
    seas[idx]  = 0.f;
  }
}

// marks embedding, dual output: X += marks@Wt.T (fp32) and tiled bf16 pair
__global__ void k_marks_add(float* __restrict__ X, const float* __restrict__ xm,
                            const float* __restrict__ Wt, u16* __restrict__ pair, int M) {
  int idx = blockIdx.x*256 + threadIdx.x;
  if (idx >= M*DD) return;
  int d = idx & 511, r = idx >> 9;
  const float* m4 = xm + (size_t)r*4;
  const float* w4 = Wt + (size_t)d*4;
  float v = X[idx] + m4[0]*w4[0] + m4[1]*w4[1] + m4[2]*w4[2] + m4[3]*w4[3];
  X[idx] = v;
  u16 hh = f2bf(v);
  size_t o = toff(r, d, 16);
  pair[o] = hh; pair[o + 4096] = f2bf(v - bf2f(hh));
}

// ---------------- split builders (tiled pair output) ----------------
__global__ void k_split_plain(const float* __restrict__ src, u16* __restrict__ dst,
                              int K, int Kp) {
  int col = blockIdx.x*256 + threadIdx.x;
  if (col >= Kp) return;
  int r = blockIdx.y;
  float v = (col < K) ? src[(size_t)r*K + col] : 0.f;
  u16 hh = f2bf(v);
  size_t o = toff(r, col, Kp >> 5);
  dst[o] = hh; dst[o + 4096] = f2bf(v - bf2f(hh));
}

// circular conv3 gather with row remap: out row r (r0+rr) -> b = r/Lout,
// t = (r%Lout) + tbase; sources wrap in [0,Lsrc).
__global__ void k_split_conv(const float* __restrict__ src, u16* __restrict__ dst,
                             int r0, int Lsrc, int Lout, int tbase,
                             int Din, int K, int Kp) {
  int col = blockIdx.x*256 + threadIdx.x;
  if (col >= Kp) return;
  int rr = blockIdx.y;
  int r = r0 + rr;
  int b = r / Lout, t = (r - b*Lout) + tbase;
  float v = 0.f;
  if (col < K) {
    int c = (col >= 2*Din) ? 2 : ((col >= Din) ? 1 : 0);
    int n = col - c*Din;
    int tt = t + c - 1;
    if (tt < 0) tt = Lsrc - 1; else if (tt >= Lsrc) tt -= Lsrc;
    v = src[((size_t)(b*Lsrc + tt))*Din + n];
  }
  u16 hh = f2bf(v);
  size_t o = toff(rr, col, Kp >> 5);
  dst[o] = hh; dst[o + 4096] = f2bf(v - bf2f(hh));
}

__global__ void k_split_tr(const float* __restrict__ src, u16* __restrict__ dst,
                           int Lc, int Kp) {
  __shared__ float t[32][33];
  int b = blockIdx.z;
  int l0 = blockIdx.x*32, c0 = blockIdx.y*32;
  int lx = threadIdx.x, ly = threadIdx.y;   // (32,8)
  #pragma unroll
  for (int i = 0; i < 4; ++i) {
    int ll = l0 + ly + i*8;
    t[ly + i*8][lx] = (ll < Lc) ? src[((size_t)b*Lc + ll)*DD + c0 + lx] : 0.f;
  }
  __syncthreads();
  int ktn = Kp >> 5;
  #pragma unroll
  for (int i = 0; i < 4; ++i) {
    int ch = c0 + ly + i*8;
    int ll = l0 + lx;
    float v = t[lx][ly + i*8];
    u16 hh = f2bf(v);
    size_t o = toff(b*DD + ch, ll, ktn);
    dst[o] = hh; dst[o + 4096] = f2bf(v - bf2f(hh));
  }
}

// conv-embed weight: [512][1024] (cols >=963 zero)
__global__ void k_build_wconvS(const float* __restrict__ Wv, u16* __restrict__ dst) {
  int col = blockIdx.x*256 + threadIdx.x;
  if (col >= 1024) return;
  int d = blockIdx.y;
  float v = 0.f;
  if (col < 963) {
    int c = (col >= 642) ? 2 : ((col >= 321) ? 1 : 0);
    int n = col - c*321;
    v = Wv[(size_t)d*963 + n*3 + c];
  }
  u16 hh = f2bf(v);
  size_t o = toff(d, col, 32);
  dst[o] = hh; dst[o + 4096] = f2bf(v - bf2f(hh));
}

__global__ void k_build_wtrcS(const float* __restrict__ Wtr, u16* __restrict__ dst) {
  int col = blockIdx.x*256 + threadIdx.x;
  if (col >= 1536) return;
  int n = blockIdx.y;
  int c = col >> 9, d = col & 511;
  float v = Wtr[(size_t)n*1536 + d*3 + c];
  u16 hh = f2bf(v);
  size_t o = toff(n, col, 48);
  dst[o] = hh; dst[o + 4096] = f2bf(v - bf2f(hh));
}

__global__ void k_build_dftS(u16* __restrict__ dst, int L, int Kp) {
  int col = blockIdx.x*256 + threadIdx.x;
  if (col >= Kp) return;
  int mr = blockIdx.y;
  float v = 0.f;
  if (col < L) {
    int m = mr & 63;
    int ph = (m * col) % L;
    float th = 6.2831853071795864f * ((float)ph / (float)L);
    v = (mr < 64) ? cosf(th) : -sinf(th);
  }
  u16 hh = f2bf(v);
  size_t o = toff(mr, col, Kp >> 5);
  dst[o] = hh; dst[o + 4096] = f2bf(v - bf2f(hh));
}

__global__ void k_build_irS(u16* __restrict__ dst, int L) {
  int k = threadIdx.x;   // 0..127
  int ll = blockIdx.y;
  int m = k & 63;
  int ph = (m * ll) % L;
  float th = 6.2831853071795864f * ((float)ph / (float)L);
  float v;
  if (k < 64) v = (m == 0) ? (1.f/(float)L) : (2.f/(float)L) * cosf(th);
  else        v = (m == 0) ? 0.f            : -(2.f/(float)L) * sinf(th);
  u16 hh = f2bf(v);
  size_t o = toff(ll, k, 4);
  dst[o] = hh; dst[o + 4096] = f2bf(v - bf2f(hh));
}

// ---------------- MFMA GEMM: 512-thr / 8-wave, 128x64 tile, 2 K-tiles/phase ---
// EPI bits: 1=bias, 2=res(fp32), 4=gelu, 8=res from tiled pair (Nc=512 layout)
template<int EPI, int WOUT, int KS>
__global__ __launch_bounds__(512)
void k_mg(const u16* __restrict__ A, const u16* __restrict__ B,
          const float* __restrict__ bias, const float* __restrict__ res,
          const u16* __restrict__ resp,
          float* __restrict__ C, u16* __restrict__ Cout,
          int M, int Nc, int K, int Lout)
{
  __shared__ __attribute__((aligned(16))) u16 sA[16384];   // 2 tiles x 16KB
  __shared__ __attribute__((aligned(16))) u16 sB[8192];    // 2 tiles x 8KB

  const int tid  = threadIdx.x;
  const int lane = tid & 63;
  const int wave = tid >> 6;          // 0..7
  const int lr   = lane & 15;
  const int kg   = lane >> 4;
  const int wr   = wave >> 1;         // row group (32 rows)
  const int wc   = wave & 1;          // col group (32 cols)

  const int gx  = gridDim.x;
  const int nwg = gx * gridDim.y;
  const int lid = blockIdx.y * gx + blockIdx.x;
  const int q8  = nwg >> 3, r8 = nwg & 7;
  const int xcd = lid & 7, i8 = lid >> 3;
  const int swz = (xcd < r8 ? xcd*(q8+1) : r8*(q8+1) + (xcd - r8)*q8) + i8;
  const int row0 = (swz / gx) * 128;
  const int col0 = (swz % gx) * 64;

  const int ksteps = K >> 5;
  const int zz = (KS > 1) ? (int)blockIdx.z : 0;
  const int t0 = (KS > 1) ? (int)(((long long)ksteps * zz) / KS) : 0;
  const int t1 = (KS > 1) ? (int)(((long long)ksteps * (zz+1)) / KS) : ksteps;

  const char* gA = (const char*)(A + (((size_t)(row0 >> 7) * ksteps) << 13));
  const char* gB = (const char*)(B + (((size_t)(col0 >> 7) * ksteps) << 13));
  const int bhalf = (col0 & 64) << 6;

  const int wlane = (wave << 10) + (lane << 4);
  const int wbase = (wave << 10);
  const int bso = (wave < 4) ? (bhalf + (wave << 10))
                             : (8192 + bhalf + ((wave - 4) << 10));

  floatx4 acc[2][2] = {};

  auto stageA = [&](int kt, int slot) {
    const char* ta = gA + ((size_t)kt << 14);
    char* la = (char*)sA + (slot << 14);
    gload_lds(ta + wlane, la + wbase);
    gload_lds(ta + 8192 + wlane, la + 8192 + wbase);
  };
  auto stageB = [&](int kt, int slot) {
    const char* tb = gB + ((size_t)kt << 14);
    gload_lds(tb + bso + (lane << 4), (char*)sB + (slot << 13) + wbase);
  };
  auto compute = [&](int slot) {
    const u16* cA = sA + (slot << 13);   // slot * 8192 u16
    const u16* cB = sB + (slot << 12);   // slot * 4096 u16
    short8 ahf[2], alf[2], bhf[2], blf[2];
    #pragma unroll
    for (int f = 0; f < 2; ++f) {
      int row = wr*32 + f*16 + lr;
      int sw = kg ^ (row & 3) ^ ((row >> 2) & 3);
      int off = (row << 5) + (sw << 3);
      ahf[f] = *(const short8*)&cA[off];
      alf[f] = *(const short8*)&cA[4096 + off];
    }
    #pragma unroll
    for (int n = 0; n < 2; ++n) {
      int row = wc*32 + n*16 + lr;
      int sw = kg ^ (row & 3) ^ ((row >> 2) & 3);
      int off = (row << 5) + (sw << 3);
      bhf[n] = *(const short8*)&cB[off];
      blf[n] = *(const short8*)&cB[2048 + off];
    }
    #pragma unroll
    for (int f = 0; f < 2; ++f)
      #pragma unroll
      for (int n = 0; n < 2; ++n) {
        acc[f][n] = __builtin_amdgcn_mfma_f32_16x16x32_bf16(ahf[f], bhf[n], acc[f][n], 0, 0, 0);
        acc[f][n] = __builtin_amdgcn_mfma_f32_16x16x32_bf16(ahf[f], blf[n], acc[f][n], 0, 0, 0);
        acc[f][n] = __builtin_amdgcn_mfma_f32_16x16x32_bf16(alf[f], bhf[n], acc[f][n], 0, 0, 0);
      }
  };

  for (int kt = t0; kt < t1; ) {
    const bool pair = (kt + 1 < t1);
    stageA(kt, 0); stageB(kt, 0);
    if (pair) { stageA(kt + 1, 1); stageB(kt + 1, 1); }
    __syncthreads();
    compute(0);
    if (pair) compute(1);
    __syncthreads();
    kt += pair ? 2 : 1;
  }

  if (KS > 1) {
    float* Cp = C + (size_t)zz * ((size_t)M * Nc);
    #pragma unroll
    for (int n = 0; n < 2; ++n) {
      int cN = col0 + wc*32 + n*16 + lr;
      if (cN >= Nc) continue;
      #pragma unroll
      for (int f = 0; f < 2; ++f)
        #pragma unroll
        for (int i = 0; i < 4; ++i) {
          int rM = row0 + wr*32 + f*16 + kg*4 + i;
          if (rM >= M) continue;
          Cp[(size_t)rM * Nc + cN] = acc[f][n][i];
        }
    }
  } else {
    #pragma unroll
    for (int n = 0; n < 2; ++n) {
      int cN = col0 + wc*32 + n*16 + lr;
      if (cN >= Nc) continue;
      #pragma unroll
      for (int f = 0; f < 2; ++f) {
        #pragma unroll
        for (int i = 0; i < 4; ++i) {
          int rM = row0 + wr*32 + f*16 + kg*4 + i;
          if (rM >= M) continue;
          float v = acc[f][n][i];
          if (EPI & 1) v += bias[cN];
          if (EPI & 4) v = 0.5f * v * (1.f + erff(v * 0.7071067811865476f));
          if (EPI & 2) v += res[(size_t)rM * Nc + cN];
          if (EPI & 8) {
            size_t ro = toff(rM, cN, 16);
            v += bf2f(resp[ro]) + bf2f(resp[ro + 4096]);
          }
          if (WOUT == 1) {
            u16 hh = f2bf(v);
            size_t o = toff(rM, cN, Nc >> 5);
            Cout[o] = hh; Cout[o + 4096] = f2bf(v - bf2f(hh));
          } else if (WOUT == 2) {
            int b = rM >> 9, ch = rM & 511;
            int fl = ch * Lout + cN;
            int r2 = b * Lout + (fl >> 9);
            int c2 = fl & 511;
            u16 hh = f2bf(v);
            size_t o = toff(r2, c2, 16);
            Cout[o] = hh; Cout[o + 4096] = f2bf(v - bf2f(hh));
          } else {
            C[(size_t)rM * Nc + cN] = v;
          }
        }
      }
    }
  }
}

// ---------------- split-K reduce (fixed order, deterministic) ----------------
__global__ void k_red(const float* __restrict__ p, int parts, size_t stride,
                      const float* __restrict__ res, float* __restrict__ out, size_t n) {
  size_t i = (size_t)blockIdx.x*256 + threadIdx.x;
  if (i >= n) return;
  float s = res ? res[i] : 0.f;
  for (int z = 0; z < parts; ++z) s += p[(size_t)z*stride + i];
  out[i] = s;
}

// split-K reduce with residual reconstructed from tiled bf16 pair (K=512 layout)
__global__ void k_redp(const float* __restrict__ p, int parts, size_t stride,
                       const u16* __restrict__ resp, float* __restrict__ out, size_t n) {
  size_t i = (size_t)blockIdx.x*256 + threadIdx.x;
  if (i >= n) return;
  int row = (int)(i >> 9), d = (int)(i & 511);
  size_t o = toff(row, d, 16);
  float s = bf2f(resp[o]) + bf2f(resp[o + 4096]);
  for (int z = 0; z < parts; ++z) s += p[(size_t)z*stride + i];
  out[i] = s;
}

// ---------------- mode mix: m-coalesced, emits tiled bf16 pair ----------------
__global__ __launch_bounds__(256)
void k_modemix(const float* __restrict__ ftbuf, const float* __restrict__ fr,
               const float* __restrict__ fi, u16* __restrict__ sel, float scale)
{
  int tid = threadIdx.x;
  int m = tid & 63, ol = tid >> 6;
  int h = blockIdx.y, o = blockIdx.x*4 + ol;
  int b0 = blockIdx.z * 8;
  float accr[8] = {}, acci[8] = {};
  const float* fb = ftbuf + (((size_t)b0*DD + h*64)*128) + m;
  size_t wof = ((((size_t)h*64)*64 + o) << 6) + m;
  for (int e = 0; e < 64; ++e) {
    float wr = fr[wof];
    float wi = fi[wof];
    const float* fe = fb + e*128;
    #pragma unroll
    for (int b = 0; b < 8; ++b) {
      float xr = fe[(size_t)b*65536];
      float xi = fe[(size_t)b*65536 + 64];
      accr[b] += xr*wr - xi*wi;
      acci[b] += xr*wi + xi*wr;
    }
    wof += 4096;
  }
  #pragma unroll
  for (int b = 0; b < 8; ++b) {
    int row = (b0 + b)*DD + h*64 + o;
    float vr = accr[b]*scale, vi2 = acci[b]*scale;
    u16 hr = f2bf(vr);
    size_t o1 = toff(row, m, 4);
    sel[o1] = hr; sel[o1 + 4096] = f2bf(vr - bf2f(hr));
    u16 hi2 = f2bf(vi2);
    size_t o2 = toff(row, m + 64, 4);
    sel[o2] = hi2; sel[o2 + 4096] = f2bf(vi2 - bf2f(hi2));
  }
}

// ---------------- cross attention ----------------
__global__ __launch_bounds__(256)
void k_cross_qk(const float* __restrict__ qf, const float* __restrict__ kf,
                float* __restrict__ ab)
{
  int bh = blockIdx.x; int b = bh >> 3, h = bh & 7;
  __shared__ float qr[32][64], qi[32][64], kr[32][64], ki[32][64];
  int tid = threadIdx.x;
  int tx = tid & 15, ty = tid >> 4;
  float ar[4][4] = {}, ai[4][4] = {};
  for (int e0 = 0; e0 < 64; e0 += 32) {
    for (int it = 0; it < 8; ++it) {
      int idx = tid + it*256;
      int e = idx >> 6, x = idx & 63;
      size_t rof = ((size_t)b*DD + h*64 + e0 + e)*128;
      qr[e][x] = qf[rof + x]; qi[e][x] = qf[rof + 64 + x];
      kr[e][x] = kf[rof + x]; ki[e][x] = kf[rof + 64 + x];
    }
    __syncthreads();
    for (int e = 0; e < 32; ++e) {
      float xr[4], xi2[4], yr[4], yi[4];
      #pragma unroll
      for (int i = 0; i < 4; ++i) { xr[i] = qr[e][ty*4+i]; xi2[i] = qi[e][ty*4+i]; }
      #pragma unroll
      for (int j = 0; j < 4; ++j) { yr[j] = kr[e][tx*4+j]; yi[j] = ki[e][tx*4+j]; }
      #pragma unroll
      for (int i = 0; i < 4; ++i)
        #pragma unroll
        for (int j = 0; j < 4; ++j) {
          ar[i][j] += xr[i]*yr[j] - xi2[i]*yi[j];
          ai[i][j] += xr[i]*yi[j] + xi2[i]*yr[j];
        }
    }
    __syncthreads();
  }
  #pragma unroll
  for (int i = 0; i < 4; ++i)
    #pragma unroll
    for (int j = 0; j < 4; ++j) {
      float txv = tanhf(ar[i][j]);
      float tyv = tanf(ai[i][j]);
      float den = 1.f + txv*txv*tyv*tyv;
      float re = txv*(1.f + tyv*tyv) / den;
      float im = tyv*(1.f - txv*txv) / den;
      size_t of = ((size_t)bh*64 + (ty*4+i))*128 + tx*4 + j;
      ab[of] = re; ab[of + 64] = im;
    }
}

__global__ __launch_bounds__(256)
void k_cross_v(const float* __restrict__ ab, const float* __restrict__ kf,
               float* __restrict__ v)
{
  int bh = blockIdx.x; int b = bh >> 3, h = bh & 7;
  __shared__ float ar[64][32], ai[64][32], kr[64][32], ki[64][32];
  int tid = threadIdx.x;
  int tx = tid & 15, ty = tid >> 4;
  float vr[4][4] = {}, vi[4][4] = {};
  for (int y0 = 0; y0 < 64; y0 += 32) {
    for (int it = 0; it < 8; ++it) {
      int idx = tid + it*256;
      int r = idx >> 5, y = idx & 31;
      ar[r][y] = ab[((size_t)bh*64 + r)*128 + y0 + y];
      ai[r][y] = ab[((size_t)bh*64 + r)*128 + 64 + y0 + y];
      kr[r][y] = kf[((size_t)b*DD + h*64 + r)*128 + y0 + y];
      ki[r][y] = kf[((size_t)b*DD + h*64 + r)*128 + 64 + y0 + y];
    }
    __syncthreads();
    for (int y = 0; y < 32; ++y) {
      float er[4], ei[4], xr[4], xi2[4];
      #pragma unroll
      for (int i = 0; i < 4; ++i) { er[i] = kr[ty*4+i][y]; ei[i] = ki[ty*4+i][y]; }
      #pragma unroll
      for (int j = 0; j < 4; ++j) { xr[j] = ar[tx*4+j][y]; xi2[j] = ai[tx*4+j][y]; }
      #pragma unroll
      for (int i = 0; i < 4; ++i)
        #pragma unroll
        for (int j = 0; j < 4; ++j) {
          vr[i][j] += xr[j]*er[i] - xi2[j]*ei[i];
          vi[i][j] += xr[j]*ei[i] + xi2[j]*er[i];
        }
    }
    __syncthreads();
  }
  #pragma unroll
  for (int i = 0; i < 4; ++i)
    #pragma unroll
    for (int j = 0; j < 4; ++j) {
      size_t of = ((size_t)b*DD + h*64 + ty*4 + i)*128 + tx*4 + j;
      v[of] = vr[i][j]; v[of + 64] = vi[i][j];
    }
}

// ---------------- LN + column-mean subtract ----------------
__global__ __launch_bounds__(256)
void k_ln(const float* __restrict__ x, const float* __restrict__ g,
          const float* __restrict__ be, float* __restrict__ out)
{
  int r = blockIdx.x; int tid = threadIdx.x;
  float v1 = x[(size_t)r*DD + tid], v2 = x[(size_t)r*DD + 256 + tid];
  float s = v1 + v2, s2 = v1*v1 + v2*v2;
  #pragma unroll
  for (int off = 32; off; off >>= 1) { s += __shfl_down(s, off, 64); s2 += __shfl_down(s2, off, 64); }
  __shared__ float red[8];
  int wid = tid >> 6, lane = tid & 63;
  if (lane == 0) { red[wid] = s; red[4 + wid] = s2; }
  __syncthreads();
  if (tid == 0) {
    float a = red[0]+red[1]+red[2]+red[3];
    float b2 = red[4]+red[5]+red[6]+red[7];
    float mu = a / 512.f;
    float var = b2 / 512.f - mu*mu;
    red[0] = mu; red[1] = rsqrtf(var + 1e-5f);
  }
  __syncthreads();
  float mu = red[0], inv = red[1];
  out[(size_t)r*DD + tid]       = (v1 - mu)*inv*g[tid]       + be[tid];
  out[(size_t)r*DD + 256 + tid] = (v2 - mu)*inv*g[256 + tid] + be[256 + tid];
}

__global__ void k_colsum_part(const float* __restrict__ x, float* __restrict__ part,
                              int L, int chl, int nch) {
  int d = threadIdx.x;
  int b = blockIdx.x, c = blockIdx.y;
  int l0 = c*chl, l1 = l0 + chl; if (l1 > L) l1 = L;
  float s = 0.f;
  for (int l = l0; l < l1; ++l) s += x[(((size_t)b*L + l) << 9) + d];
  part[((size_t)(b*nch + c) << 9) + d] = s;
}
__global__ void k_colsum_fin(const float* __restrict__ part, float* __restrict__ cm,
                             int nch, float inv) {
  int i = blockIdx.x*256 + threadIdx.x;
  int b = i >> 9, d = i & 511;
  float s = 0.f;
  for (int c = 0; c < nch; ++c) s += part[((size_t)(b*nch + c) << 9) + d];
  cm[i] = s * inv;
}
// encoder: full rows
__global__ void k_csub_pair(const float* __restrict__ x, const float* __restrict__ cm,
                            u16* __restrict__ dst, int L) {
  size_t idx = (size_t)blockIdx.x*256 + threadIdx.x;
  if (idx >= (size_t)BB*L*DD) return;
  int d = (int)(idx & 511);
  int r = (int)(idx >> 9);
  int b = r / L;
  float v = x[idx] - cm[(b << 9) | d];
  u16 hh = f2bf(v);
  size_t o = toff(r, d, 16);
  dst[o] = hh; dst[o + 4096] = f2bf(v - bf2f(hh));
}
// decoder: remapped rows (b, 360+tt) -> r' = b*720+tt, pair of 11520 rows
__global__ void k_csub_pairR(const float* __restrict__ x, const float* __restrict__ cm,
                             u16* __restrict__ dst) {
  size_t idx = (size_t)blockIdx.x*256 + threadIdx.x;
  if (idx >= (size_t)BB*LEN_E*DD) return;
  int d = (int)(idx & 511);
  int rp = (int)(idx >> 9);
  int b = rp / LEN_E, tt = rp - b*LEN_E;
  float v = x[(((size_t)(b*LEN_D + 360 + tt)) << 9) + d] - cm[(b << 9) | d];
  u16 hh = f2bf(v);
  size_t o = toff(rp, d, 16);
  dst[o] = hh; dst[o + 4096] = f2bf(v - bf2f(hh));
}

// ---------------- series decomp: sliding-window running sum ----------------
// OUTP=0: fp32 only; OUTP=1: pair only; OUTP=2: both.
template<int ACC, int OUTP>
__global__ __launch_bounds__(512)
void k_decomp(const float* __restrict__ x, float* __restrict__ out,
              u16* __restrict__ outp, float* __restrict__ tsum, int L, int chl)
{
  int d = threadIdx.x;            // 512
  int b = blockIdx.x;
  int l0 = blockIdx.y * chl;
  int l1 = l0 + chl; if (l1 > L) l1 = L;
  const float* xb = x + (((size_t)b*L) << 9) + d;
  float s = 0.f;
  #pragma unroll
  for (int j = -12; j <= 12; ++j) {
    int lc = l0 + j; lc = lc < 0 ? 0 : (lc >= L ? L-1 : lc);
    s += xb[(size_t)lc << 9];
  }
  for (int l = l0; l < l1; ++l) {
    int r = b*L + l;
    size_t o = ((size_t)r << 9) + d;
    float ma = s * (1.f/25.f);
    float v = xb[(size_t)l << 9] - ma;
    if (OUTP == 0 || OUTP == 2) out[o] = v;
    if (OUTP == 1 || OUTP == 2) {
      size_t op = toff(r, d, 16);
      u16 hh = f2bf(v);
      outp[op] = hh; outp[op + 4096] = f2bf(v - bf2f(hh));
    }
    if (ACC == 1) tsum[o] += ma;
    if (ACC == 2) tsum[o] = ma;
    int la = l + 13; if (la >= L) la = L - 1;
    int lr = l - 12; if (lr < 0) lr = 0;
    s += xb[(size_t)la << 9] - xb[(size_t)lr << 9];
  }
}

// =====================================================================
extern "C" void kernel_launch(void* const* d_in, const int* in_sizes, int n_in,
                              void* d_out, int out_size, void* d_ws, size_t ws_size,
                              hipStream_t stream)
{
  (void)in_sizes; (void)n_in; (void)out_size; (void)ws_size;
  const float* history = (const float*)d_in[0];
  const float* future  = (const float*)d_in[1];
  const float* Wv_enc  = (const float*)d_in[2];
  const float* Wt_enc  = (const float*)d_in[3];
  const float* Wv_dec  = (const float*)d_in[4];
  const float* Wt_dec  = (const float*)d_in[5];
  const float* eWq = (const float*)d_in[6];
  const float* ebq = (const float*)d_in[7];
  const float* efr = (const float*)d_in[8];
  const float* efi = (const float*)d_in[9];
  const float* eWo = (const float*)d_in[10];
  const float* ebo = (const float*)d_in[11];
  const float* eW1 = (const float*)d_in[12];
  const float* eW2 = (const float*)d_in[13];
  const float* g_enc = (const float*)d_in[14];
  const float* b_enc = (const float*)d_in[15];
  const float* dWq = (const float*)d_in[16];
  const float* dbq = (const float*)d_in[17];
  const float* dfr = (const float*)d_in[18];
  const float* dfi = (const float*)d_in[19];
  const float* dWo = (const float*)d_in[20];
  const float* dbo = (const float*)d_in[21];
  const float* cWq = (const float*)d_in[22];
  const float* cbq = (const float*)d_in[23];
  const float* cWk = (const float*)d_in[24];
  const float* cbk = (const float*)d_in[25];
  const float* cfr = (const float*)d_in[26];
  const float* cfi = (const float*)d_in[27];
  const float* cWo = (const float*)d_in[28];
  const float* cbo = (const float*)d_in[29];
  const float* dW1 = (const float*)d_in[30];
  const float* dW2 = (const float*)d_in[31];
  const float* Wtr = (const float*)d_in[32];
  const float* g_dec = (const float*)d_in[33];
  const float* b_dec = (const float*)d_in[34];
  const float* Wp  = (const float*)d_in[35];
  const float* bp  = (const float*)d_in[36];

  float* ws = (float*)d_ws;
  size_t off = 0;
  auto alloc = [&](size_t n) { float* p = ws + off; off += (n + 63) & ~(size_t)63; return p; };

  const size_t SL = 1048576;
  const int MP = BB * LEN_E;   // remapped output rows = 11520

  float* btrend = alloc((size_t)BB*LEN_D*NV);   // uses first MP*NV
  float* bTsum  = alloc((size_t)BB*LEN_D*DD);
  float* bX     = alloc((size_t)BB*LEN_D*DD);
  float* bT     = alloc((size_t)BB*LEN_D*DD);
  float* bencout= alloc((size_t)BB*LEN_E*DD);
  float* bseas  = alloc((size_t)BB*LEN_D*NV);
  float* R      = alloc((size_t)11900000);
  float* SB     = alloc((size_t)2*SL + 128);
  float* WceS   = alloc((size_t)512*1024);
  float* WcdS   = alloc((size_t)512*1024);
  float* WtrcS  = alloc((size_t)384*1536);
  float* D720S  = alloc((size_t)128*768);
  float* D1080S = alloc((size_t)128*1088);
  float* I720S  = alloc((size_t)768*128);
  float* I1080S = alloc((size_t)1152*128);
  float* bxme   = alloc((size_t)BB*LEN_E*4);
  float* bxmd   = alloc((size_t)BB*LEN_D*4);
  float* bmean  = alloc((size_t)BB*NV);
  float* bpart  = alloc((size_t)BB*9*DD);
  float* bcm    = alloc((size_t)BB*DD);
  float* bmsp   = alloc((size_t)BB*10*NV);

  float* bxe = bT;   // prep alias (dead before T written)

  auto U = [](float* p) { return (u16*)p; };

  auto splitP = [&](const float* src, float* dst, int M, int K) {
    dim3 g((K + 255)/256, M);
    k_split_plain<<<g,256,0,stream>>>(src, U(dst), K, K);
  };
  auto splitC = [&](const float* src, float* dst, int r0, int Mc, int Lsrc, int Lout,
                    int tbase, int Din, int K, int Kp) {
    dim3 g((Kp + 255)/256, Mc);
    k_split_conv<<<g,256,0,stream>>>(src, U(dst), r0, Lsrc, Lout, tbase, Din, K, Kp);
  };
  auto splitT = [&](const float* src, float* dst, int Lc, int Kp) {
    dim3 g(Kp/32, 16, BB), b(32, 8);
    k_split_tr<<<g,b,0,stream>>>(src, U(dst), Lc, Kp);
  };
  auto red = [&](const float* p, int parts, size_t stride, const float* res,
                 float* out, size_t n) {
    k_red<<<(int)((n + 255)/256),256,0,stream>>>(p, parts, stride, res, out, n);
  };

  auto decomp = [&](const float* in, float* out, int L, int acc) {
    int chl = 45;
    int nch = (L + chl - 1) / chl;
    dim3 g(BB, nch);
    if (acc == 1)      k_decomp<1,0><<<g,512,0,stream>>>(in, out, nullptr, bTsum, L, chl);
    else if (acc == 2) k_decomp<2,0><<<g,512,0,stream>>>(in, out, nullptr, bTsum, L, chl);
    else               k_decomp<0,0><<<g,512,0,stream>>>(in, out, nullptr, nullptr, L, chl);
  };
  auto decompP = [&](const float* in, u16* outp, int L, int acc) {
    int chl = 45;
    int nch = (L + chl - 1) / chl;
    dim3 g(BB, nch);
    if (acc == 1) k_decomp<1,1><<<g,512,0,stream>>>(in, nullptr, outp, bTsum, L, chl);
    else          k_decomp<0,1><<<g,512,0,stream>>>(in, nullptr, outp, nullptr, L, chl);
  };
  auto decompD = [&](const float* in, float* out, u16* outp, int L, int acc) {
    int chl = 45;
    int nch = (L + chl - 1) / chl;
    dim3 g(BB, nch);
    if (acc == 2)      k_decomp<2,2><<<g,512,0,stream>>>(in, out, outp, bTsum, L, chl);
    else               k_decomp<0,2><<<g,512,0,stream>>>(in, out, outp, nullptr, L, chl);
  };

  // FFN: out = reconstruct(inPair) + gelu(inPair@W1.T)@W2.T
  // GEMM1 KS=1 (big grid); GEMM2 split-K=2 (720 blocks) + k_redp.
  const int CHP = 5760;   // ME = 2 chunks, MD = 3 chunks exactly
  float* SA2 = R;         // hidden tiled pair (5760x2048 pair = 11.8M floats)
  auto ffn = [&](const u16* inPair, float* out, const float* W1, const float* W2,
                 int M, float* scratch) {
    splitP(W1, SB, DFF2, DD);
    splitP(W2, SB + SL, DD, DFF2);
    for (int r0 = 0; r0 < M; r0 += CHP) {
      int mc = M - r0; if (mc > CHP) mc = CHP;
      const u16* Ap = inPair + ((size_t)(r0 >> 7) << 17);   // 128 rows = 1<<17 u16
      k_mg<4,1,1><<<dim3(32,(mc+127)/128,1),512,0,stream>>>(
          Ap, U(SB), nullptr, nullptr, nullptr, nullptr, U(SA2), mc, DFF2, DD, 0);
      k_mg<0,0,2><<<dim3(8,(mc+127)/128,2),512,0,stream>>>(
          U(SA2), U(SB+SL), nullptr, nullptr, nullptr, scratch, nullptr, mc, DD, DFF2, 0);
      k_redp<<<(int)(((size_t)mc*DD + 255)/256),256,0,stream>>>(
          scratch, 2, (size_t)mc*DD, Ap, out + (size_t)r0*DD, (size_t)mc*DD);
    }
  };

  // X += fourier_self(X); X pair must be pre-staged in R (K=512 layout).
  auto fourier_self = [&](float* X, float* T, int L, int KpL, float* DLS, float* ILS,
                          const float* Wq, const float* bq, const float* fr, const float* fi,
                          const float* Wo, const float* bo) {
    int M = BB * L;
    size_t MN8 = (size_t)8192*128;
    float* bqf   = R + 9*SL;
    float* bselp = R + 10*SL;
    splitP(Wq, SB, DD, DD);
    k_mg<1,0,1><<<dim3(8,(M+127)/128,1),512,0,stream>>>(
        U(R), U(SB), bq, nullptr, nullptr, T, nullptr, M, DD, DD, 0);
    splitT(T, R, L, KpL);
    k_mg<0,0,4><<<dim3(2,64,4),512,0,stream>>>(
        U(R), U(DLS), nullptr, nullptr, nullptr, T, nullptr, BB*DD, 128, KpL, 0);
    red(T, 4, MN8, nullptr, bqf, MN8);
    k_modemix<<<dim3(16,8,2),256,0,stream>>>(bqf, fr, fi, U(bselp), 1.0f);
    k_mg<0,2,1><<<dim3((L+63)/64,64,1),512,0,stream>>>(   // irfft -> pair @R
        U(bselp), U(ILS), nullptr, nullptr, nullptr, nullptr, U(R), BB*DD, L, 128, L);
    splitP(Wo, SB, DD, DD);
    k_mg<3,0,1><<<dim3(8,(M+127)/128,1),512,0,stream>>>(
        U(R), U(SB), bo, X, nullptr, X, nullptr, M, DD, DD, 0);
  };

  auto myln_pair = [&](const float* in, float* tmp, float* pairdst,
                       const float* g, const float* b, int L) {
    k_ln<<<BB*L,256,0,stream>>>(in, g, b, tmp);
    int chl = L / 9;
    k_colsum_part<<<dim3(BB,9),512,0,stream>>>(tmp, bpart, L, chl, 9);
    k_colsum_fin<<<32,256,0,stream>>>(bpart, bcm, 9, 1.f/(float)L);
    size_t n = (size_t)BB*L*DD;
    k_csub_pair<<<(int)((n+255)/256),256,0,stream>>>(tmp, bcm, U(pairdst), L);
  };

  // ---------------- prep ----------------
  k_extract_x<<<(BB*LEN_E*NV + 255)/256,256,0,stream>>>(history, bxe);
  k_marks_enc<<<(BB*LEN_E*4 + 255)/256,256,0,stream>>>(history, bxme);
  k_marks_dec<<<(BB*LEN_D*4 + 255)/256,256,0,stream>>>(future, bxme, bxmd);
  k_ms_part<<<dim3(BB,10),384,0,stream>>>(bxe, bmsp, 72, 10);
  k_ms_fin<<<(BB*NV + 255)/256,256,0,stream>>>(bmsp, bmean, 10);
  k_init_decomp<<<(BB*LEN_D*NV + 255)/256,256,0,stream>>>(bxe, bmean, bseas, btrend);
  k_build_wconvS<<<dim3(4,512),256,0,stream>>>(Wv_enc, U(WceS));
  k_build_wconvS<<<dim3(4,512),256,0,stream>>>(Wv_dec, U(WcdS));
  k_build_wtrcS<<<dim3(6,321),256,0,stream>>>(Wtr, U(WtrcS));
  k_build_dftS<<<dim3(3,128),256,0,stream>>>(U(D720S), LEN_E, 768);
  k_build_dftS<<<dim3(5,128),256,0,stream>>>(U(D1080S), LEN_D, 1088);
  k_build_irS<<<dim3(1,LEN_E),128,0,stream>>>(U(I720S), LEN_E);
  k_build_irS<<<dim3(1,LEN_D),128,0,stream>>>(U(I1080S), LEN_D);

  // ---------------- encoder ----------------
  int ME = BB * LEN_E;
  // conv-embed in ONE dispatch: 720 blocks, KS=1, no reduce
  splitC(bxe, R, 0, ME, LEN_E, LEN_E, 0, NV, 963, 1024);
  k_mg<0,0,1><<<dim3(8,90,1),512,0,stream>>>(
      U(R), U(WceS), nullptr, nullptr, nullptr, bX, nullptr, ME, DD, 1024, 0);
  k_marks_add<<<(ME*DD + 255)/256,256,0,stream>>>(bX, bxme, Wt_enc, U(R), ME);

  float *X = bX, *T = bT;
  for (int i = 0; i < 2; ++i) {
    fourier_self(X, T, LEN_E, 768, D720S, I720S,
                 eWq + (size_t)i*DD*DD, ebq + (size_t)i*DD,
                 efr + (size_t)i*HHN*64*64*64, efi + (size_t)i*HHN*64*64*64,
                 eWo + (size_t)i*DD*DD, ebo + (size_t)i*DD);
    decompP(X, U(T), LEN_E, 0);                         // T = seasonal PAIR
    ffn(U(T), X, eW1 + (size_t)i*DFF2*DD, eW2 + (size_t)i*DD*DFF2, ME, bencout);
    if (i == 0) decompD(X, T, U(R), LEN_E, 0);          // T fp32 + R pair (next fourier)
    else        decomp(X, T, LEN_E, 0);                 // T fp32 only
    { float* tmp = X; X = T; T = tmp; }
  }
  myln_pair(X, T, bencout, g_enc, b_enc, LEN_E);   // bencout = tiled pair (ME,512)

  // ---------------- decoder ----------------
  int MD = BB * LEN_D;
  for (int r0 = 0; r0 < MD; r0 += 8640) {               // 2 chunks, KS=1 (544 blocks)
    splitC(bseas, R, r0, 8640, LEN_D, LEN_D, 0, NV, 963, 1024);
    k_mg<0,0,1><<<dim3(8,68,1),512,0,stream>>>(
        U(R), U(WcdS), nullptr, nullptr, nullptr, X + (size_t)r0*DD, nullptr,
        8640, DD, 1024, 0);
  }
  k_marks_add<<<(MD*DD + 255)/256,256,0,stream>>>(X, bxmd, Wt_dec, U(R), MD);

  fourier_self(X, T, LEN_D, 1088, D1080S, I1080S, dWq, dbq, dfr, dfi, dWo, dbo);

  decompD(X, T, U(R), LEN_D, 2);      // T fp32 + R pair, tsum = t1

  // cross attention (q-projection first: consumes R pair before splitT clobbers R)
  {
    size_t MN8 = (size_t)8192*128;
    float* bkf = R + 9*SL;
    float* bqf = R + 10*SL;
    splitP(cWq, SB, DD, DD);
    k_mg<1,0,1><<<dim3(8,135,1),512,0,stream>>>(         // q proj from R pair
        U(R), U(SB), cbq, nullptr, nullptr, X, nullptr, MD, DD, DD, 0);
    splitT(X, R, LEN_D, 1088);
    k_mg<0,0,4><<<dim3(2,64,4),512,0,stream>>>(
        U(R), U(D1080S), nullptr, nullptr, nullptr, X, nullptr, BB*DD, 128, 1088, 0);
    red(X, 4, MN8, nullptr, bqf, MN8);
    splitP(cWk, SB, DD, DD);
    k_mg<1,0,1><<<dim3(8,90,1),512,0,stream>>>(          // k proj from bencout pair
        U(bencout), U(SB), cbk, nullptr, nullptr, X, nullptr, ME, DD, DD, 0);
    splitT(X, R, LEN_E, 768);
    k_mg<0,0,4><<<dim3(2,64,4),512,0,stream>>>(
        U(R), U(D720S), nullptr, nullptr, nullptr, X, nullptr, BB*DD, 128, 768, 0);
    red(X, 4, MN8, nullptr, bkf, MN8);
    float* ba = R;
    float* bv = R + SL;
    float* bselp = R + 2*SL;
    k_cross_qk<<<BB*HHN,256,0,stream>>>(bqf, bkf, ba);
    k_cross_v<<<BB*HHN,256,0,stream>>>(ba, bkf, bv);
    k_modemix<<<dim3(16,8,2),256,0,stream>>>(bv, cfr, cfi, U(bselp), 1.0f/262144.0f);
    k_mg<0,2,1><<<dim3(17,64,1),512,0,stream>>>(        // irfft -> pair @X
        U(bselp), U(I1080S), nullptr, nullptr, nullptr, nullptr, U(X), BB*DD, LEN_D, 128, LEN_D);
    splitP(cWo, SB, DD, DD);
    k_mg<3,0,1><<<dim3(8,135,1),512,0,stream>>>(
        U(X), U(SB), cbo, T, nullptr, T, nullptr, MD, DD, DD, 0);
  }

  decompP(T, U(X), LEN_D, 1);         // X = seasonal PAIR, tsum += t2
  ffn(U(X), T, dW1, dW2, MD, bencout);// T = x + FFN(x)
  decomp(T, X, LEN_D, 1);             // X fp32, tsum += t3

  // decoder LN + col-mean; emit REMAPPED pair (rows t>=360 only) into bencout
  {
    k_ln<<<BB*LEN_D,256,0,stream>>>(X, g_dec, b_dec, T);
    k_colsum_part<<<dim3(BB,9),512,0,stream>>>(T, bpart, LEN_D, LEN_D/9, 9);
    k_colsum_fin<<<32,256,0,stream>>>(bpart, bcm, 9, 1.f/(float)LEN_D);
    k_csub_pairR<<<(int)(((size_t)MP*DD + 255)/256),256,0,stream>>>(T, bcm, U(bencout));
  }

  // trend conv: split-K=2 (540 blocks) + reduce accumulating into btrend
  for (int r0 = 0; r0 < MP; r0 += 5760) {
    splitC(bTsum, R, r0, 5760, LEN_D, LEN_E, 360, DD, 1536, 1536);
    k_mg<0,0,2><<<dim3(6,45,2),512,0,stream>>>(
        U(R), U(WtrcS), nullptr, nullptr, nullptr, bX, nullptr, 5760, NV, 1536, 0);
    red(bX, 2, (size_t)5760*NV, btrend + (size_t)r0*NV, btrend + (size_t)r0*NV,
        (size_t)5760*NV);
  }

  // seasonal + trend -> d_out (fused, no k_final)
  splitP(Wp, SB, NV, DD);
  k_mg<3,0,1><<<dim3(6,90,1),512,0,stream>>>(
      U(bencout), U(SB), bp, btrend, nullptr, (float*)d_out, nullptr, MP, NV, DD, 0);
}

// Round 23
// 2017.247 us; speedup vs baseline: 1.1454x; 1.0519x over previous
//
#include <hip/hip_runtime.h>
#include <math.h>

#define BB 16
#define DD 512
#define HHN 8
#define LEN_E 720
#define LEN_D 1080
#define NV 321
#define DFF2 2048

typedef __attribute__((ext_vector_type(8))) short short8;
typedef __attribute__((ext_vector_type(4))) float floatx4;
typedef unsigned short u16;

__device__ __forceinline__ u16 f2bf(float v) {
  unsigned u = __builtin_bit_cast(unsigned, v);
  u += 0x7FFFu + ((u >> 16) & 1u);
  return (u16)(u >> 16);
}
__device__ __forceinline__ float bf2f(u16 h) {
  unsigned u = ((unsigned)h) << 16;
  return __builtin_bit_cast(float, u);
}

// element offset (u16) of (r,k) in tiled pair buffer; lo at +4096.
// tile = 128 rows x 32 cols, 8192 u16 (hi 4096 + lo 4096), XOR-swizzled slots.
__device__ __forceinline__ size_t toff(int r, int k, int ktn) {
  int rt = r >> 7, rr = r & 127;
  int kt = k >> 5, kk = k & 31;
  int sw = (kk >> 3) ^ (rr & 3) ^ ((rr >> 2) & 3);
  return (((size_t)(rt * ktn + kt)) << 13) + (rr << 5) + (sw << 3) + (kk & 7);
}
// single-bf16 tiled layout: tile = 128x32 = 4096 u16, same intra-tile swizzle.
__device__ __forceinline__ size_t toffS(int r, int k, int ktn) {
  int rt = r >> 7, rr = r & 127;
  int kt = k >> 5, kk = k & 31;
  int sw = (kk >> 3) ^ (rr & 3) ^ ((rr >> 2) & 3);
  return (((size_t)(rt * ktn + kt)) << 12) + (rr << 5) + (sw << 3) + (kk & 7);
}

__device__ __forceinline__ void gload_lds(const void* g, void* l) {
  __builtin_amdgcn_global_load_lds(
      (const __attribute__((address_space(1))) unsigned int*)g,
      (__attribute__((address_space(3))) unsigned int*)l, 16, 0, 0);
}

// ---------------- prep kernels ----------------
__global__ void k_extract_x(const float* __restrict__ hist, float* __restrict__ xe) {
  int idx = blockIdx.x * 256 + threadIdx.x;
  if (idx >= BB*LEN_E*NV) return;
  xe[idx] = hist[(size_t)idx * 5];
}

__global__ void k_marks_enc(const float* __restrict__ hist, float* __restrict__ xme) {
  int idx = blockIdx.x * 256 + threadIdx.x;
  if (idx >= BB*LEN_E*4) return;
  int f = idx & 3;
  int r = idx >> 2;
  xme[idx] = hist[((size_t)r * NV) * 5 + 1 + f];
}

__global__ void k_marks_dec(const float* __restrict__ fut, const float* __restrict__ xme,
                            float* __restrict__ xmd) {
  int idx = blockIdx.x * 256 + threadIdx.x;
  if (idx >= BB*LEN_D*4) return;
  int f = idx & 3;
  int r = idx >> 2;
  int t = r % LEN_D, b = r / LEN_D;
  float v;
  if (t < 360) v = xme[((b*LEN_E) + 360 + t)*4 + f];
  else v = fut[(((size_t)(b*LEN_E + (t-360))) * NV) * 5 + 1 + f];
  xmd[idx] = v;
}

__global__ void k_ms_part(const float* __restrict__ xe, float* __restrict__ part,
                          int chl, int nch) {
  int n = threadIdx.x;
  if (n >= NV) return;
  int b = blockIdx.x, c = blockIdx.y;
  int l0 = c*chl, l1 = l0 + chl; if (l1 > LEN_E) l1 = LEN_E;
  float s = 0.f;
  for (int l = l0; l < l1; ++l) s += xe[((size_t)b*LEN_E + l)*NV + n];
  part[((size_t)b*nch + c)*NV + n] = s;
}
__global__ void k_ms_fin(const float* __restrict__ part, float* __restrict__ mb, int nch) {
  int i = blockIdx.x*256 + threadIdx.x;
  if (i >= BB*NV) return;
  int b = i / NV, n = i % NV;
  float s = 0.f;
  for (int c = 0; c < nch; ++c) s += part[((size_t)b*nch + c)*NV + n];
  mb[i] = s * (1.f/(float)LEN_E);
}

// seas full (B,1080,NV); trend ONLY remapped rows (b, t>=360) -> (b*720+(t-360), n)
__global__ void k_init_decomp(const float* __restrict__ xe, const float* __restrict__ mb,
                              float* __restrict__ seas, float* __restrict__ trend) {
  int idx = blockIdx.x * 256 + threadIdx.x;
  if (idx >= BB*LEN_D*NV) return;
  int n = idx % NV; int r = idx / NV; int t = r % LEN_D; int b = r / LEN_D;
  if (t < 360) {
    int l = 360 + t;
    float s = 0.f;
    for (int j = -12; j <= 12; ++j) {
      int lc = l + j; if (lc > LEN_E-1) lc = LEN_E-1; if (lc < 0) lc = 0;
      s += xe[((size_t)b*LEN_E + lc)*NV + n];
    }
    float ma = s * (1.f/25.f);
    seas[idx]  = xe[((size_t)b*LEN_E + l)*NV + n] - ma;
  } else {
    trend[((size_t)(b*LEN_E + (t - 360)))*NV + n] = mb[b*NV + n];
    seas[idx]  = 0.f;
  }
}

// marks embedding, dual output: X += marks@Wt.T (fp32) and tiled bf16 pair
__global__ void k_marks_add(float* __restrict__ X, const float* __restrict__ xm,
                            const float* __restrict__ Wt, u16* __restrict__ pair, int M) {
  int idx = blockIdx.x*256 + threadIdx.x;
  if (idx >= M*DD) return;
  int d = idx & 511, r = idx >> 9;
  const float* m4 = xm + (size_t)r*4;
  const float* w4 = Wt + (size_t)d*4;
  float v = X[idx] + m4[0]*w4[0] + m4[1]*w4[1] + m4[2]*w4[2] + m4[3]*w4[3];
  X[idx] = v;
  u16 hh = f2bf(v);
  size_t o = toff(r, d, 16);
  pair[o] = hh; pair[o + 4096] = f2bf(v - bf2f(hh));
}

// ---------------- split builders (tiled pair output) ----------------
__global__ void k_split_plain(const float* __restrict__ src, u16* __restrict__ dst,
                              int K, int Kp) {
  int col = blockIdx.x*256 + threadIdx.x;
  if (col >= Kp) return;
  int r = blockIdx.y;
  float v = (col < K) ? src[(size_t)r*K + col] : 0.f;
  u16 hh = f2bf(v);
  size_t o = toff(r, col, Kp >> 5);
  dst[o] = hh; dst[o + 4096] = f2bf(v - bf2f(hh));
}

// circular conv3 gather with row remap: out row r (r0+rr) -> b = r/Lout,
// t = (r%Lout) + tbase; sources wrap in [0,Lsrc).
__global__ void k_split_conv(const float* __restrict__ src, u16* __restrict__ dst,
                             int r0, int Lsrc, int Lout, int tbase,
                             int Din, int K, int Kp) {
  int col = blockIdx.x*256 + threadIdx.x;
  if (col >= Kp) return;
  int rr = blockIdx.y;
  int r = r0 + rr;
  int b = r / Lout, t = (r - b*Lout) + tbase;
  float v = 0.f;
  if (col < K) {
    int c = (col >= 2*Din) ? 2 : ((col >= Din) ? 1 : 0);
    int n = col - c*Din;
    int tt = t + c - 1;
    if (tt < 0) tt = Lsrc - 1; else if (tt >= Lsrc) tt -= Lsrc;
    v = src[((size_t)(b*Lsrc + tt))*Din + n];
  }
  u16 hh = f2bf(v);
  size_t o = toff(rr, col, Kp >> 5);
  dst[o] = hh; dst[o + 4096] = f2bf(v - bf2f(hh));
}

__global__ void k_split_tr(const float* __restrict__ src, u16* __restrict__ dst,
                           int Lc, int Kp) {
  __shared__ float t[32][33];
  int b = blockIdx.z;
  int l0 = blockIdx.x*32, c0 = blockIdx.y*32;
  int lx = threadIdx.x, ly = threadIdx.y;   // (32,8)
  #pragma unroll
  for (int i = 0; i < 4; ++i) {
    int ll = l0 + ly + i*8;
    t[ly + i*8][lx] = (ll < Lc) ? src[((size_t)b*Lc + ll)*DD + c0 + lx] : 0.f;
  }
  __syncthreads();
  int ktn = Kp >> 5;
  #pragma unroll
  for (int i = 0; i < 4; ++i) {
    int ch = c0 + ly + i*8;
    int ll = l0 + lx;
    float v = t[lx][ly + i*8];
    u16 hh = f2bf(v);
    size_t o = toff(b*DD + ch, ll, ktn);
    dst[o] = hh; dst[o + 4096] = f2bf(v - bf2f(hh));
  }
}

// conv-embed weight: [512][1024] (cols >=963 zero)
__global__ void k_build_wconvS(const float* __restrict__ Wv, u16* __restrict__ dst) {
  int col = blockIdx.x*256 + threadIdx.x;
  if (col >= 1024) return;
  int d = blockIdx.y;
  float v = 0.f;
  if (col < 963) {
    int c = (col >= 642) ? 2 : ((col >= 321) ? 1 : 0);
    int n = col - c*321;
    v = Wv[(size_t)d*963 + n*3 + c];
  }
  u16 hh = f2bf(v);
  size_t o = toff(d, col, 32);
  dst[o] = hh; dst[o + 4096] = f2bf(v - bf2f(hh));
}

__global__ void k_build_wtrcS(const float* __restrict__ Wtr, u16* __restrict__ dst) {
  int col = blockIdx.x*256 + threadIdx.x;
  if (col >= 1536) return;
  int n = blockIdx.y;
  int c = col >> 9, d = col & 511;
  float v = Wtr[(size_t)n*1536 + d*3 + c];
  u16 hh = f2bf(v);
  size_t o = toff(n, col, 48);
  dst[o] = hh; dst[o + 4096] = f2bf(v - bf2f(hh));
}

__global__ void k_build_dftS(u16* __restrict__ dst, int L, int Kp) {
  int col = blockIdx.x*256 + threadIdx.x;
  if (col >= Kp) return;
  int mr = blockIdx.y;
  float v = 0.f;
  if (col < L) {
    int m = mr & 63;
    int ph = (m * col) % L;
    float th = 6.2831853071795864f * ((float)ph / (float)L);
    v = (mr < 64) ? cosf(th) : -sinf(th);
  }
  u16 hh = f2bf(v);
  size_t o = toff(mr, col, Kp >> 5);
  dst[o] = hh; dst[o + 4096] = f2bf(v - bf2f(hh));
}

__global__ void k_build_irS(u16* __restrict__ dst, int L) {
  int k = threadIdx.x;   // 0..127
  int ll = blockIdx.y;
  int m = k & 63;
  int ph = (m * ll) % L;
  float th = 6.2831853071795864f * ((float)ph / (float)L);
  float v;
  if (k < 64) v = (m == 0) ? (1.f/(float)L) : (2.f/(float)L) * cosf(th);
  else        v = (m == 0) ? 0.f            : -(2.f/(float)L) * sinf(th);
  u16 hh = f2bf(v);
  size_t o = toff(ll, k, 4);
  dst[o] = hh; dst[o + 4096] = f2bf(v - bf2f(hh));
}

// ---------------- MFMA GEMM: 512-thr / 8-wave, 128x64 tile, 2 K-tiles/phase ---
// EPI bits: 1=bias, 2=res(fp32), 4=gelu, 8=res from tiled pair (Nc=512 layout)
// WOUT: 0=fp32 C, 1=pair Cout, 2=remap pair, 3=single-bf16 Cout
// ASING: A operand is single-bf16 tiled (4096 u16/tile), 2 MFMAs per step
template<int EPI, int WOUT, int KS, int ASING>
__global__ __launch_bounds__(512)
void k_mg(const u16* __restrict__ A, const u16* __restrict__ B,
          const float* __restrict__ bias, const float* __restrict__ res,
          const u16* __restrict__ resp,
          float* __restrict__ C, u16* __restrict__ Cout,
          int M, int Nc, int K, int Lout)
{
  __shared__ __attribute__((aligned(16))) u16 sA[ASING ? 8192 : 16384];
  __shared__ __attribute__((aligned(16))) u16 sB[8192];

  const int tid  = threadIdx.x;
  const int lane = tid & 63;
  const int wave = tid >> 6;          // 0..7
  const int lr   = lane & 15;
  const int kg   = lane >> 4;
  const int wr   = wave >> 1;         // row group (32 rows)
  const int wc   = wave & 1;          // col group (32 cols)

  const int gx  = gridDim.x;
  const int nwg = gx * gridDim.y;
  const int lid = blockIdx.y * gx + blockIdx.x;
  const int q8  = nwg >> 3, r8 = nwg & 7;
  const int xcd = lid & 7, i8 = lid >> 3;
  const int swz = (xcd < r8 ? xcd*(q8+1) : r8*(q8+1) + (xcd - r8)*q8) + i8;
  const int row0 = (swz / gx) * 128;
  const int col0 = (swz % gx) * 64;

  const int ksteps = K >> 5;
  const int zz = (KS > 1) ? (int)blockIdx.z : 0;
  const int t0 = (KS > 1) ? (int)(((long long)ksteps * zz) / KS) : 0;
  const int t1 = (KS > 1) ? (int)(((long long)ksteps * (zz+1)) / KS) : ksteps;

  const char* gA = (const char*)(A + (((size_t)(row0 >> 7) * ksteps) << (ASING ? 12 : 13)));
  const char* gB = (const char*)(B + (((size_t)(col0 >> 7) * ksteps) << 13));
  const int bhalf = (col0 & 64) << 6;

  const int wlane = (wave << 10) + (lane << 4);
  const int wbase = (wave << 10);
  const int bso = (wave < 4) ? (bhalf + (wave << 10))
                             : (8192 + bhalf + ((wave - 4) << 10));

  floatx4 acc[2][2] = {};

  auto stageA = [&](int kt, int slot) {
    if (ASING) {
      const char* ta = gA + ((size_t)kt << 13);
      char* la = (char*)sA + (slot << 13);
      gload_lds(ta + wlane, la + wbase);
    } else {
      const char* ta = gA + ((size_t)kt << 14);
      char* la = (char*)sA + (slot << 14);
      gload_lds(ta + wlane, la + wbase);
      gload_lds(ta + 8192 + wlane, la + 8192 + wbase);
    }
  };
  auto stageB = [&](int kt, int slot) {
    const char* tb = gB + ((size_t)kt << 14);
    gload_lds(tb + bso + (lane << 4), (char*)sB + (slot << 13) + wbase);
  };
  auto compute = [&](int slot) {
    const u16* cA = sA + (slot << (ASING ? 12 : 13));
    const u16* cB = sB + (slot << 12);   // slot * 4096 u16
    short8 ahf[2], alf[2], bhf[2], blf[2];
    #pragma unroll
    for (int f = 0; f < 2; ++f) {
      int row = wr*32 + f*16 + lr;
      int sw = kg ^ (row & 3) ^ ((row >> 2) & 3);
      int off = (row << 5) + (sw << 3);
      ahf[f] = *(const short8*)&cA[off];
      if (!ASING) alf[f] = *(const short8*)&cA[4096 + off];
    }
    #pragma unroll
    for (int n = 0; n < 2; ++n) {
      int row = wc*32 + n*16 + lr;
      int sw = kg ^ (row & 3) ^ ((row >> 2) & 3);
      int off = (row << 5) + (sw << 3);
      bhf[n] = *(const short8*)&cB[off];
      blf[n] = *(const short8*)&cB[2048 + off];
    }
    #pragma unroll
    for (int f = 0; f < 2; ++f)
      #pragma unroll
      for (int n = 0; n < 2; ++n) {
        acc[f][n] = __builtin_amdgcn_mfma_f32_16x16x32_bf16(ahf[f], bhf[n], acc[f][n], 0, 0, 0);
        acc[f][n] = __builtin_amdgcn_mfma_f32_16x16x32_bf16(ahf[f], blf[n], acc[f][n], 0, 0, 0);
        if (!ASING)
          acc[f][n] = __builtin_amdgcn_mfma_f32_16x16x32_bf16(alf[f], bhf[n], acc[f][n], 0, 0, 0);
      }
  };

  for (int kt = t0; kt < t1; ) {
    const bool pair = (kt + 1 < t1);
    stageA(kt, 0); stageB(kt, 0);
    if (pair) { stageA(kt + 1, 1); stageB(kt + 1, 1); }
    __syncthreads();
    compute(0);
    if (pair) compute(1);
    __syncthreads();
    kt += pair ? 2 : 1;
  }

  if (KS > 1) {
    float* Cp = C + (size_t)zz * ((size_t)M * Nc);
    #pragma unroll
    for (int n = 0; n < 2; ++n) {
      int cN = col0 + wc*32 + n*16 + lr;
      if (cN >= Nc) continue;
      #pragma unroll
      for (int f = 0; f < 2; ++f)
        #pragma unroll
        for (int i = 0; i < 4; ++i) {
          int rM = row0 + wr*32 + f*16 + kg*4 + i;
          if (rM >= M) continue;
          Cp[(size_t)rM * Nc + cN] = acc[f][n][i];
        }
    }
  } else {
    #pragma unroll
    for (int n = 0; n < 2; ++n) {
      int cN = col0 + wc*32 + n*16 + lr;
      if (cN >= Nc) continue;
      #pragma unroll
      for (int f = 0; f < 2; ++f) {
        #pragma unroll
        for (int i = 0; i < 4; ++i) {
          int rM = row0 + wr*32 + f*16 + kg*4 + i;
          if (rM >= M) continue;
          float v = acc[f][n][i];
          if (EPI & 1) v += bias[cN];
          if (EPI & 4) v = 0.5f * v * (1.f + erff(v * 0.7071067811865476f));
          if (EPI & 2) v += res[(size_t)rM * Nc + cN];
          if (EPI & 8) {
            size_t ro = toff(rM, cN, 16);
            v += bf2f(resp[ro]) + bf2f(resp[ro + 4096]);
          }
          if (WOUT == 1) {
            u16 hh = f2bf(v);
            size_t o = toff(rM, cN, Nc >> 5);
            Cout[o] = hh; Cout[o + 4096] = f2bf(v - bf2f(hh));
          } else if (WOUT == 2) {
            int b = rM >> 9, ch = rM & 511;
            int fl = ch * Lout + cN;
            int r2 = b * Lout + (fl >> 9);
            int c2 = fl & 511;
            u16 hh = f2bf(v);
            size_t o = toff(r2, c2, 16);
            Cout[o] = hh; Cout[o + 4096] = f2bf(v - bf2f(hh));
          } else if (WOUT == 3) {
            size_t o = toffS(rM, cN, Nc >> 5);
            Cout[o] = f2bf(v);
          } else {
            C[(size_t)rM * Nc + cN] = v;
          }
        }
      }
    }
  }
}

// ---------------- split-K reduce (fixed order, deterministic) ----------------
__global__ void k_red(const float* __restrict__ p, int parts, size_t stride,
                      const float* __restrict__ res, float* __restrict__ out, size_t n) {
  size_t i = (size_t)blockIdx.x*256 + threadIdx.x;
  if (i >= n) return;
  float s = res ? res[i] : 0.f;
  for (int z = 0; z < parts; ++z) s += p[(size_t)z*stride + i];
  out[i] = s;
}

// split-K reduce with residual reconstructed from tiled bf16 pair (K=512 layout)
__global__ void k_redp(const float* __restrict__ p, int parts, size_t stride,
                       const u16* __restrict__ resp, float* __restrict__ out, size_t n) {
  size_t i = (size_t)blockIdx.x*256 + threadIdx.x;
  if (i >= n) return;
  int row = (int)(i >> 9), d = (int)(i & 511);
  size_t o = toff(row, d, 16);
  float s = bf2f(resp[o]) + bf2f(resp[o + 4096]);
  for (int z = 0; z < parts; ++z) s += p[(size_t)z*stride + i];
  out[i] = s;
}

// ---------------- mode mix: m-coalesced, emits tiled bf16 pair ----------------
__global__ __launch_bounds__(256)
void k_modemix(const float* __restrict__ ftbuf, const float* __restrict__ fr,
               const float* __restrict__ fi, u16* __restrict__ sel, float scale)
{
  int tid = threadIdx.x;
  int m = tid & 63, ol = tid >> 6;
  int h = blockIdx.y, o = blockIdx.x*4 + ol;
  int b0 = blockIdx.z * 8;
  float accr[8] = {}, acci[8] = {};
  const float* fb = ftbuf + (((size_t)b0*DD + h*64)*128) + m;
  size_t wof = ((((size_t)h*64)*64 + o) << 6) + m;
  for (int e = 0; e < 64; ++e) {
    float wr = fr[wof];
    float wi = fi[wof];
    const float* fe = fb + e*128;
    #pragma unroll
    for (int b = 0; b < 8; ++b) {
      float xr = fe[(size_t)b*65536];
      float xi = fe[(size_t)b*65536 + 64];
      accr[b] += xr*wr - xi*wi;
      acci[b] += xr*wi + xi*wr;
    }
    wof += 4096;
  }
  #pragma unroll
  for (int b = 0; b < 8; ++b) {
    int row = (b0 + b)*DD + h*64 + o;
    float vr = accr[b]*scale, vi2 = acci[b]*scale;
    u16 hr = f2bf(vr);
    size_t o1 = toff(row, m, 4);
    sel[o1] = hr; sel[o1 + 4096] = f2bf(vr - bf2f(hr));
    u16 hi2 = f2bf(vi2);
    size_t o2 = toff(row, m + 64, 4);
    sel[o2] = hi2; sel[o2 + 4096] = f2bf(vi2 - bf2f(hi2));
  }
}

// ---------------- cross attention ----------------
__global__ __launch_bounds__(256)
void k_cross_qk(const float* __restrict__ qf, const float* __restrict__ kf,
                float* __restrict__ ab)
{
  int bh = blockIdx.x; int b = bh >> 3, h = bh & 7;
  __shared__ float qr[32][64], qi[32][64], kr[32][64], ki[32][64];
  int tid = threadIdx.x;
  int tx = tid & 15, ty = tid >> 4;
  float ar[4][4] = {}, ai[4][4] = {};
  for (int e0 = 0; e0 < 64; e0 += 32) {
    for (int it = 0; it < 8; ++it) {
      int idx = tid + it*256;
      int e = idx >> 6, x = idx & 63;
      size_t rof = ((size_t)b*DD + h*64 + e0 + e)*128;
      qr[e][x] = qf[rof + x]; qi[e][x] = qf[rof + 64 + x];
      kr[e][x] = kf[rof + x]; ki[e][x] = kf[rof + 64 + x];
    }
    __syncthreads();
    for (int e = 0; e < 32; ++e) {
      float xr[4], xi2[4], yr[4], yi[4];
      #pragma unroll
      for (int i = 0; i < 4; ++i) { xr[i] = qr[e][ty*4+i]; xi2[i] = qi[e][ty*4+i]; }
      #pragma unroll
      for (int j = 0; j < 4; ++j) { yr[j] = kr[e][tx*4+j]; yi[j] = ki[e][tx*4+j]; }
      #pragma unroll
      for (int i = 0; i < 4; ++i)
        #pragma unroll
        for (int j = 0; j < 4; ++j) {
          ar[i][j] += xr[i]*yr[j] - xi2[i]*yi[j];
          ai[i][j] += xr[i]*yi[j] + xi2[i]*yr[j];
        }
    }
    __syncthreads();
  }
  #pragma unroll
  for (int i = 0; i < 4; ++i)
    #pragma unroll
    for (int j = 0; j < 4; ++j) {
      float txv = tanhf(ar[i][j]);
      float tyv = tanf(ai[i][j]);
      float den = 1.f + txv*txv*tyv*tyv;
      float re = txv*(1.f + tyv*tyv) / den;
      float im = tyv*(1.f - txv*txv) / den;
      size_t of = ((size_t)bh*64 + (ty*4+i))*128 + tx*4 + j;
      ab[of] = re; ab[of + 64] = im;
    }
}

__global__ __launch_bounds__(256)
void k_cross_v(const float* __restrict__ ab, const float* __restrict__ kf,
               float* __restrict__ v)
{
  int bh = blockIdx.x; int b = bh >> 3, h = bh & 7;
  __shared__ float ar[64][32], ai[64][32], kr[64][32], ki[64][32];
  int tid = threadIdx.x;
  int tx = tid & 15, ty = tid >> 4;
  float vr[4][4] = {}, vi[4][4] = {};
  for (int y0 = 0; y0 < 64; y0 += 32) {
    for (int it = 0; it < 8; ++it) {
      int idx = tid + it*256;
      int r = idx >> 5, y = idx & 31;
      ar[r][y] = ab[((size_t)bh*64 + r)*128 + y0 + y];
      ai[r][y] = ab[((size_t)bh*64 + r)*128 + 64 + y0 + y];
      kr[r][y] = kf[((size_t)b*DD + h*64 + r)*128 + y0 + y];
      ki[r][y] = kf[((size_t)b*DD + h*64 + r)*128 + 64 + y0 + y];
    }
    __syncthreads();
    for (int y = 0; y < 32; ++y) {
      float er[4], ei[4], xr[4], xi2[4];
      #pragma unroll
      for (int i = 0; i < 4; ++i) { er[i] = kr[ty*4+i][y]; ei[i] = ki[ty*4+i][y]; }
      #pragma unroll
      for (int j = 0; j < 4; ++j) { xr[j] = ar[tx*4+j][y]; xi2[j] = ai[tx*4+j][y]; }
      #pragma unroll
      for (int i = 0; i < 4; ++i)
        #pragma unroll
        for (int j = 0; j < 4; ++j) {
          vr[i][j] += xr[j]*er[i] - xi2[j]*ei[i];
          vi[i][j] += xr[j]*ei[i] + xi2[j]*er[i];
        }
    }
    __syncthreads();
  }
  #pragma unroll
  for (int i = 0; i < 4; ++i)
    #pragma unroll
    for (int j = 0; j < 4; ++j) {
      size_t of = ((size_t)b*DD + h*64 + ty*4 + i)*128 + tx*4 + j;
      v[of] = vr[i][j]; v[of + 64] = vi[i][j];
    }
}

// ---------------- LN + column-mean subtract ----------------
__global__ __launch_bounds__(256)
void k_ln(const float* __restrict__ x, const float* __restrict__ g,
          const float* __restrict__ be, float* __restrict__ out)
{
  int r = blockIdx.x; int tid = threadIdx.x;
  float v1 = x[(size_t)r*DD + tid], v2 = x[(size_t)r*DD + 256 + tid];
  float s = v1 + v2, s2 = v1*v1 + v2*v2;
  #pragma unroll
  for (int off = 32; off; off >>= 1) { s += __shfl_down(s, off, 64); s2 += __shfl_down(s2, off, 64); }
  __shared__ float red[8];
  int wid = tid >> 6, lane = tid & 63;
  if (lane == 0) { red[wid] = s; red[4 + wid] = s2; }
  __syncthreads();
  if (tid == 0) {
    float a = red[0]+red[1]+red[2]+red[3];
    float b2 = red[4]+red[5]+red[6]+red[7];
    float mu = a / 512.f;
    float var = b2 / 512.f - mu*mu;
    red[0] = mu; red[1] = rsqrtf(var + 1e-5f);
  }
  __syncthreads();
  float mu = red[0], inv = red[1];
  out[(size_t)r*DD + tid]       = (v1 - mu)*inv*g[tid]       + be[tid];
  out[(size_t)r*DD + 256 + tid] = (v2 - mu)*inv*g[256 + tid] + be[256 + tid];
}

__global__ void k_colsum_part(const float* __restrict__ x, float* __restrict__ part,
                              int L, int chl, int nch) {
  int d = threadIdx.x;
  int b = blockIdx.x, c = blockIdx.y;
  int l0 = c*chl, l1 = l0 + chl; if (l1 > L) l1 = L;
  float s = 0.f;
  for (int l = l0; l < l1; ++l) s += x[(((size_t)b*L + l) << 9) + d];
  part[((size_t)(b*nch + c) << 9) + d] = s;
}
__global__ void k_colsum_fin(const float* __restrict__ part, float* __restrict__ cm,
                             int nch, float inv) {
  int i = blockIdx.x*256 + threadIdx.x;
  int b = i >> 9, d = i & 511;
  float s = 0.f;
  for (int c = 0; c < nch; ++c) s += part[((size_t)(b*nch + c) << 9) + d];
  cm[i] = s * inv;
}
// encoder: full rows
__global__ void k_csub_pair(const float* __restrict__ x, const float* __restrict__ cm,
                            u16* __restrict__ dst, int L) {
  size_t idx = (size_t)blockIdx.x*256 + threadIdx.x;
  if (idx >= (size_t)BB*L*DD) return;
  int d = (int)(idx & 511);
  int r = (int)(idx >> 9);
  int b = r / L;
  float v = x[idx] - cm[(b << 9) | d];
  u16 hh = f2bf(v);
  size_t o = toff(r, d, 16);
  dst[o] = hh; dst[o + 4096] = f2bf(v - bf2f(hh));
}
// decoder: remapped rows (b, 360+tt) -> r' = b*720+tt, pair of 11520 rows
__global__ void k_csub_pairR(const float* __restrict__ x, const float* __restrict__ cm,
                             u16* __restrict__ dst) {
  size_t idx = (size_t)blockIdx.x*256 + threadIdx.x;
  if (idx >= (size_t)BB*LEN_E*DD) return;
  int d = (int)(idx & 511);
  int rp = (int)(idx >> 9);
  int b = rp / LEN_E, tt = rp - b*LEN_E;
  float v = x[(((size_t)(b*LEN_D + 360 + tt)) << 9) + d] - cm[(b << 9) | d];
  u16 hh = f2bf(v);
  size_t o = toff(rp, d, 16);
  dst[o] = hh; dst[o + 4096] = f2bf(v - bf2f(hh));
}

// ---------------- series decomp: sliding-window running sum ----------------
// OUTP=0: fp32 only; OUTP=1: pair only; OUTP=2: both.
template<int ACC, int OUTP>
__global__ __launch_bounds__(512)
void k_decomp(const float* __restrict__ x, float* __restrict__ out,
              u16* __restrict__ outp, float* __restrict__ tsum, int L, int chl)
{
  int d = threadIdx.x;            // 512
  int b = blockIdx.x;
  int l0 = blockIdx.y * chl;
  int l1 = l0 + chl; if (l1 > L) l1 = L;
  const float* xb = x + (((size_t)b*L) << 9) + d;
  float s = 0.f;
  #pragma unroll
  for (int j = -12; j <= 12; ++j) {
    int lc = l0 + j; lc = lc < 0 ? 0 : (lc >= L ? L-1 : lc);
    s += xb[(size_t)lc << 9];
  }
  for (int l = l0; l < l1; ++l) {
    int r = b*L + l;
    size_t o = ((size_t)r << 9) + d;
    float ma = s * (1.f/25.f);
    float v = xb[(size_t)l << 9] - ma;
    if (OUTP == 0 || OUTP == 2) out[o] = v;
    if (OUTP == 1 || OUTP == 2) {
      size_t op = toff(r, d, 16);
      u16 hh = f2bf(v);
      outp[op] = hh; outp[op + 4096] = f2bf(v - bf2f(hh));
    }
    if (ACC == 1) tsum[o] += ma;
    if (ACC == 2) tsum[o] = ma;
    int la = l + 13; if (la >= L) la = L - 1;
    int lr = l - 12; if (lr < 0) lr = 0;
    s += xb[(size_t)la << 9] - xb[(size_t)lr << 9];
  }
}

// =====================================================================
extern "C" void kernel_launch(void* const* d_in, const int* in_sizes, int n_in,
                              void* d_out, int out_size, void* d_ws, size_t ws_size,
                              hipStream_t stream)
{
  (void)in_sizes; (void)n_in; (void)out_size; (void)ws_size;
  const float* history = (const float*)d_in[0];
  const float* future  = (const float*)d_in[1];
  const float* Wv_enc  = (const float*)d_in[2];
  const float* Wt_enc  = (const float*)d_in[3];
  const float* Wv_dec  = (const float*)d_in[4];
  const float* Wt_dec  = (const float*)d_in[5];
  const float* eWq = (const float*)d_in[6];
  const float* ebq = (const float*)d_in[7];
  const float* efr = (const float*)d_in[8];
  const float* efi = (const float*)d_in[9];
  const float* eWo = (const float*)d_in[10];
  const float* ebo = (const float*)d_in[11];
  const float* eW1 = (const float*)d_in[12];
  const float* eW2 = (const float*)d_in[13];
  const float* g_enc = (const float*)d_in[14];
  const float* b_enc = (const float*)d_in[15];
  const float* dWq = (const float*)d_in[16];
  const float* dbq = (const float*)d_in[17];
  const float* dfr = (const float*)d_in[18];
  const float* dfi = (const float*)d_in[19];
  const float* dWo = (const float*)d_in[20];
  const float* dbo = (const float*)d_in[21];
  const float* cWq = (const float*)d_in[22];
  const float* cbq = (const float*)d_in[23];
  const float* cWk = (const float*)d_in[24];
  const float* cbk = (const float*)d_in[25];
  const float* cfr = (const float*)d_in[26];
  const float* cfi = (const float*)d_in[27];
  const float* cWo = (const float*)d_in[28];
  const float* cbo = (const float*)d_in[29];
  const float* dW1 = (const float*)d_in[30];
  const float* dW2 = (const float*)d_in[31];
  const float* Wtr = (const float*)d_in[32];
  const float* g_dec = (const float*)d_in[33];
  const float* b_dec = (const float*)d_in[34];
  const float* Wp  = (const float*)d_in[35];
  const float* bp  = (const float*)d_in[36];

  float* ws = (float*)d_ws;
  size_t off = 0;
  auto alloc = [&](size_t n) { float* p = ws + off; off += (n + 63) & ~(size_t)63; return p; };

  const size_t SL = 1048576;
  const int MP = BB * LEN_E;   // remapped output rows = 11520

  float* btrend = alloc((size_t)BB*LEN_D*NV);   // uses first MP*NV
  float* bTsum  = alloc((size_t)BB*LEN_D*DD);
  float* bX     = alloc((size_t)BB*LEN_D*DD);
  float* bT     = alloc((size_t)BB*LEN_D*DD);
  float* bencout= alloc((size_t)BB*LEN_E*DD);
  float* bseas  = alloc((size_t)BB*LEN_D*NV);
  float* R      = alloc((size_t)11900000);
  float* SB     = alloc((size_t)2*SL + 128);
  float* WceS   = alloc((size_t)512*1024);
  float* WcdS   = alloc((size_t)512*1024);
  float* WtrcS  = alloc((size_t)384*1536);
  float* D720S  = alloc((size_t)128*768);
  float* D1080S = alloc((size_t)128*1088);
  float* I720S  = alloc((size_t)768*128);
  float* I1080S = alloc((size_t)1152*128);
  float* bxme   = alloc((size_t)BB*LEN_E*4);
  float* bxmd   = alloc((size_t)BB*LEN_D*4);
  float* bmean  = alloc((size_t)BB*NV);
  float* bpart  = alloc((size_t)BB*9*DD);
  float* bcm    = alloc((size_t)BB*DD);
  float* bmsp   = alloc((size_t)BB*10*NV);

  float* bxe = bT;   // prep alias (dead before T written)

  auto U = [](float* p) { return (u16*)p; };

  auto splitP = [&](const float* src, float* dst, int M, int K) {
    dim3 g((K + 255)/256, M);
    k_split_plain<<<g,256,0,stream>>>(src, U(dst), K, K);
  };
  auto splitC = [&](const float* src, float* dst, int r0, int Mc, int Lsrc, int Lout,
                    int tbase, int Din, int K, int Kp) {
    dim3 g((Kp + 255)/256, Mc);
    k_split_conv<<<g,256,0,stream>>>(src, U(dst), r0, Lsrc, Lout, tbase, Din, K, Kp);
  };
  auto splitT = [&](const float* src, float* dst, int Lc, int Kp) {
    dim3 g(Kp/32, 16, BB), b(32, 8);
    k_split_tr<<<g,b,0,stream>>>(src, U(dst), Lc, Kp);
  };
  auto red = [&](const float* p, int parts, size_t stride, const float* res,
                 float* out, size_t n) {
    k_red<<<(int)((n + 255)/256),256,0,stream>>>(p, parts, stride, res, out, n);
  };

  auto decomp = [&](const float* in, float* out, int L, int acc) {
    int chl = 45;
    int nch = (L + chl - 1) / chl;
    dim3 g(BB, nch);
    if (acc == 1)      k_decomp<1,0><<<g,512,0,stream>>>(in, out, nullptr, bTsum, L, chl);
    else if (acc == 2) k_decomp<2,0><<<g,512,0,stream>>>(in, out, nullptr, bTsum, L, chl);
    else               k_decomp<0,0><<<g,512,0,stream>>>(in, out, nullptr, nullptr, L, chl);
  };
  auto decompP = [&](const float* in, u16* outp, int L, int acc) {
    int chl = 45;
    int nch = (L + chl - 1) / chl;
    dim3 g(BB, nch);
    if (acc == 1) k_decomp<1,1><<<g,512,0,stream>>>(in, nullptr, outp, bTsum, L, chl);
    else          k_decomp<0,1><<<g,512,0,stream>>>(in, nullptr, outp, nullptr, L, chl);
  };
  auto decompD = [&](const float* in, float* out, u16* outp, int L, int acc) {
    int chl = 45;
    int nch = (L + chl - 1) / chl;
    dim3 g(BB, nch);
    if (acc == 2)      k_decomp<2,2><<<g,512,0,stream>>>(in, out, outp, bTsum, L, chl);
    else               k_decomp<0,2><<<g,512,0,stream>>>(in, out, outp, nullptr, L, chl);
  };

  // FFN: out = reconstruct(inPair) + gelu(inPair@W1.T)@W2.T
  // GEMM1 KS=1 writes hidden as SINGLE bf16 (WOUT=3); GEMM2 ASING=1 split-K=2.
  const int CHP = 5760;   // ME = 2 chunks, MD = 3 chunks exactly
  float* SA2 = R;         // hidden single tiled (5760x2048 u16 = 5.9M floats)
  auto ffn = [&](const u16* inPair, float* out, const float* W1, const float* W2,
                 int M, float* scratch) {
    splitP(W1, SB, DFF2, DD);
    splitP(W2, SB + SL, DD, DFF2);
    for (int r0 = 0; r0 < M; r0 += CHP) {
      int mc = M - r0; if (mc > CHP) mc = CHP;
      const u16* Ap = inPair + ((size_t)(r0 >> 7) << 17);   // 128 rows = 1<<17 u16
      k_mg<4,3,1,0><<<dim3(32,(mc+127)/128,1),512,0,stream>>>(
          Ap, U(SB), nullptr, nullptr, nullptr, nullptr, U(SA2), mc, DFF2, DD, 0);
      k_mg<0,0,2,1><<<dim3(8,(mc+127)/128,2),512,0,stream>>>(
          U(SA2), U(SB+SL), nullptr, nullptr, nullptr, scratch, nullptr, mc, DD, DFF2, 0);
      k_redp<<<(int)(((size_t)mc*DD + 255)/256),256,0,stream>>>(
          scratch, 2, (size_t)mc*DD, Ap, out + (size_t)r0*DD, (size_t)mc*DD);
    }
  };

  // X += fourier_self(X); X pair must be pre-staged in R (K=512 layout).
  auto fourier_self = [&](float* X, float* T, int L, int KpL, float* DLS, float* ILS,
                          const float* Wq, const float* bq, const float* fr, const float* fi,
                          const float* Wo, const float* bo) {
    int M = BB * L;
    size_t MN8 = (size_t)8192*128;
    float* bqf   = R + 9*SL;
    float* bselp = R + 10*SL;
    splitP(Wq, SB, DD, DD);
    k_mg<1,0,1,0><<<dim3(8,(M+127)/128,1),512,0,stream>>>(
        U(R), U(SB), bq, nullptr, nullptr, T, nullptr, M, DD, DD, 0);
    splitT(T, R, L, KpL);
    k_mg<0,0,4,0><<<dim3(2,64,4),512,0,stream>>>(
        U(R), U(DLS), nullptr, nullptr, nullptr, T, nullptr, BB*DD, 128, KpL, 0);
    red(T, 4, MN8, nullptr, bqf, MN8);
    k_modemix<<<dim3(16,8,2),256,0,stream>>>(bqf, fr, fi, U(bselp), 1.0f);
    k_mg<0,2,1,0><<<dim3((L+63)/64,64,1),512,0,stream>>>(   // irfft -> pair @R
        U(bselp), U(ILS), nullptr, nullptr, nullptr, nullptr, U(R), BB*DD, L, 128, L);
    splitP(Wo, SB, DD, DD);
    k_mg<3,0,1,0><<<dim3(8,(M+127)/128,1),512,0,stream>>>(
        U(R), U(SB), bo, X, nullptr, X, nullptr, M, DD, DD, 0);
  };

  auto myln_pair = [&](const float* in, float* tmp, float* pairdst,
                       const float* g, const float* b, int L) {
    k_ln<<<BB*L,256,0,stream>>>(in, g, b, tmp);
    int chl = L / 9;
    k_colsum_part<<<dim3(BB,9),512,0,stream>>>(tmp, bpart, L, chl, 9);
    k_colsum_fin<<<32,256,0,stream>>>(bpart, bcm, 9, 1.f/(float)L);
    size_t n = (size_t)BB*L*DD;
    k_csub_pair<<<(int)((n+255)/256),256,0,stream>>>(tmp, bcm, U(pairdst), L);
  };

  // ---------------- prep ----------------
  k_extract_x<<<(BB*LEN_E*NV + 255)/256,256,0,stream>>>(history, bxe);
  k_marks_enc<<<(BB*LEN_E*4 + 255)/256,256,0,stream>>>(history, bxme);
  k_marks_dec<<<(BB*LEN_D*4 + 255)/256,256,0,stream>>>(future, bxme, bxmd);
  k_ms_part<<<dim3(BB,10),384,0,stream>>>(bxe, bmsp, 72, 10);
  k_ms_fin<<<(BB*NV + 255)/256,256,0,stream>>>(bmsp, bmean, 10);
  k_init_decomp<<<(BB*LEN_D*NV + 255)/256,256,0,stream>>>(bxe, bmean, bseas, btrend);
  k_build_wconvS<<<dim3(4,512),256,0,stream>>>(Wv_enc, U(WceS));
  k_build_wconvS<<<dim3(4,512),256,0,stream>>>(Wv_dec, U(WcdS));
  k_build_wtrcS<<<dim3(6,321),256,0,stream>>>(Wtr, U(WtrcS));
  k_build_dftS<<<dim3(3,128),256,0,stream>>>(U(D720S), LEN_E, 768);
  k_build_dftS<<<dim3(5,128),256,0,stream>>>(U(D1080S), LEN_D, 1088);
  k_build_irS<<<dim3(1,LEN_E),128,0,stream>>>(U(I720S), LEN_E);
  k_build_irS<<<dim3(1,LEN_D),128,0,stream>>>(U(I1080S), LEN_D);

  // ---------------- encoder ----------------
  int ME = BB * LEN_E;
  // conv-embed in ONE dispatch: 720 blocks, KS=1, no reduce
  splitC(bxe, R, 0, ME, LEN_E, LEN_E, 0, NV, 963, 1024);
  k_mg<0,0,1,0><<<dim3(8,90,1),512,0,stream>>>(
      U(R), U(WceS), nullptr, nullptr, nullptr, bX, nullptr, ME, DD, 1024, 0);
  k_marks_add<<<(ME*DD + 255)/256,256,0,stream>>>(bX, bxme, Wt_enc, U(R), ME);

  float *X = bX, *T = bT;
  for (int i = 0; i < 2; ++i) {
    fourier_self(X, T, LEN_E, 768, D720S, I720S,
                 eWq + (size_t)i*DD*DD, ebq + (size_t)i*DD,
                 efr + (size_t)i*HHN*64*64*64, efi + (size_t)i*HHN*64*64*64,
                 eWo + (size_t)i*DD*DD, ebo + (size_t)i*DD);
    decompP(X, U(T), LEN_E, 0);                         // T = seasonal PAIR
    ffn(U(T), X, eW1 + (size_t)i*DFF2*DD, eW2 + (size_t)i*DD*DFF2, ME, bencout);
    if (i == 0) decompD(X, T, U(R), LEN_E, 0);          // T fp32 + R pair (next fourier)
    else        decomp(X, T, LEN_E, 0);                 // T fp32 only
    { float* tmp = X; X = T; T = tmp; }
  }
  myln_pair(X, T, bencout, g_enc, b_enc, LEN_E);   // bencout = tiled pair (ME,512)

  // ---------------- decoder ----------------
  int MD = BB * LEN_D;
  for (int r0 = 0; r0 < MD; r0 += 8640) {               // 2 chunks, KS=1 (544 blocks)
    splitC(bseas, R, r0, 8640, LEN_D, LEN_D, 0, NV, 963, 1024);
    k_mg<0,0,1,0><<<dim3(8,68,1),512,0,stream>>>(
        U(R), U(WcdS), nullptr, nullptr, nullptr, X + (size_t)r0*DD, nullptr,
        8640, DD, 1024, 0);
  }
  k_marks_add<<<(MD*DD + 255)/256,256,0,stream>>>(X, bxmd, Wt_dec, U(R), MD);

  fourier_self(X, T, LEN_D, 1088, D1080S, I1080S, dWq, dbq, dfr, dfi, dWo, dbo);

  decompD(X, T, U(R), LEN_D, 2);      // T fp32 + R pair, tsum = t1

  // cross attention (q-projection first: consumes R pair before splitT clobbers R)
  {
    size_t MN8 = (size_t)8192*128;
    float* bkf = R + 9*SL;
    float* bqf = R + 10*SL;
    splitP(cWq, SB, DD, DD);
    k_mg<1,0,1,0><<<dim3(8,135,1),512,0,stream>>>(       // q proj from R pair
        U(R), U(SB), cbq, nullptr, nullptr, X, nullptr, MD, DD, DD, 0);
    splitT(X, R, LEN_D, 1088);
    k_mg<0,0,4,0><<<dim3(2,64,4),512,0,stream>>>(
        U(R), U(D1080S), nullptr, nullptr, nullptr, X, nullptr, BB*DD, 128, 1088, 0);
    red(X, 4, MN8, nullptr, bqf, MN8);
    splitP(cWk, SB, DD, DD);
    k_mg<1,0,1,0><<<dim3(8,90,1),512,0,stream>>>(        // k proj from bencout pair
        U(bencout), U(SB), cbk, nullptr, nullptr, X, nullptr, ME, DD, DD, 0);
    splitT(X, R, LEN_E, 768);
    k_mg<0,0,4,0><<<dim3(2,64,4),512,0,stream>>>(
        U(R), U(D720S), nullptr, nullptr, nullptr, X, nullptr, BB*DD, 128, 768, 0);
    red(X, 4, MN8, nullptr, bkf, MN8);
    float* ba = R;
    float* bv = R + SL;
    float* bselp = R + 2*SL;
    k_cross_qk<<<BB*HHN,256,0,stream>>>(bqf, bkf, ba);
    k_cross_v<<<BB*HHN,256,0,stream>>>(ba, bkf, bv);
    k_modemix<<<dim3(16,8,2),256,0,stream>>>(bv, cfr, cfi, U(bselp), 1.0f/262144.0f);
    k_mg<0,2,1,0><<<dim3(17,64,1),512,0,stream>>>(      // irfft -> pair @X
        U(bselp), U(I1080S), nullptr, nullptr, nullptr, nullptr, U(X), BB*DD, LEN_D, 128, LEN_D);
    splitP(cWo, SB, DD, DD);
    k_mg<3,0,1,0><<<dim3(8,135,1),512,0,stream>>>(
        U(X), U(SB), cbo, T, nullptr, T, nullptr, MD, DD, DD, 0);
  }

  decompP(T, U(X), LEN_D, 1);         // X = seasonal PAIR, tsum += t2
  ffn(U(X), T, dW1, dW2, MD, bencout);// T = x + FFN(x)
  decomp(T, X, LEN_D, 1);             // X fp32, tsum += t3

  // decoder LN + col-mean; emit REMAPPED pair (rows t>=360 only) into bencout
  {
    k_ln<<<BB*LEN_D,256,0,stream>>>(X, g_dec, b_dec, T);
    k_colsum_part<<<dim3(BB,9),512,0,stream>>>(T, bpart, LEN_D, LEN_D/9, 9);
    k_colsum_fin<<<32,256,0,stream>>>(bpart, bcm, 9, 1.f/(float)LEN_D);
    k_csub_pairR<<<(int)(((size_t)MP*DD + 255)/256),256,0,stream>>>(T, bcm, U(bencout));
  }

  // trend conv: split-K=2 (540 blocks) + reduce accumulating into btrend
  for (int r0 = 0; r0 < MP; r0 += 5760) {
    splitC(bTsum, R, r0, 5760, LEN_D, LEN_E, 360, DD, 1536, 1536);
    k_mg<0,0,2,0><<<dim3(6,45,2),512,0,stream>>>(
        U(R), U(WtrcS), nullptr, nullptr, nullptr, bX, nullptr, 5760, NV, 1536, 0);
    red(bX, 2, (size_t)5760*NV, btrend + (size_t)r0*NV, btrend + (size_t)r0*NV,
        (size_t)5760*NV);
  }

  // seasonal + trend -> d_out (fused, no k_final)
  splitP(Wp, SB, NV, DD);
  k_mg<3,0,1,0><<<dim3(6,90,1),512,0,stream>>>(
      U(bencout), U(SB), bp, btrend, nullptr, (float*)d_out, nullptr, MP, NV, DD, 0);
}

// Round 24
// 1941.387 us; speedup vs baseline: 1.1901x; 1.0391x over previous
//
#include <hip/hip_runtime.h>
#include <math.h>

#define BB 16
#define DD 512
#define HHN 8
#define LEN_E 720
#define LEN_D 1080
#define NV 321
#define DFF2 2048

typedef __attribute__((ext_vector_type(8))) short short8;
typedef __attribute__((ext_vector_type(4))) float floatx4;
typedef unsigned short u16;

__device__ __forceinline__ u16 f2bf(float v) {
  unsigned u = __builtin_bit_cast(unsigned, v);
  u += 0x7FFFu + ((u >> 16) & 1u);
  return (u16)(u >> 16);
}
__device__ __forceinline__ float bf2f(u16 h) {
  unsigned u = ((unsigned)h) << 16;
  return __builtin_bit_cast(float, u);
}

// element offset (u16) of (r,k) in tiled pair buffer; lo at +4096.
// tile = 128 rows x 32 cols, 8192 u16 (hi 4096 + lo 4096), XOR-swizzled slots.
__device__ __forceinline__ size_t toff(int r, int k, int ktn) {
  int rt = r >> 7, rr = r & 127;
  int kt = k >> 5, kk = k & 31;
  int sw = (kk >> 3) ^ (rr & 3) ^ ((rr >> 2) & 3);
  return (((size_t)(rt * ktn + kt)) << 13) + (rr << 5) + (sw << 3) + (kk & 7);
}
// single-bf16 tiled layout: tile = 128x32 = 4096 u16, same intra-tile swizzle.
__device__ __forceinline__ size_t toffS(int r, int k, int ktn) {
  int rt = r >> 7, rr = r & 127;
  int kt = k >> 5, kk = k & 31;
  int sw = (kk >> 3) ^ (rr & 3) ^ ((rr >> 2) & 3);
  return (((size_t)(rt * ktn + kt)) << 12) + (rr << 5) + (sw << 3) + (kk & 7);
}

__device__ __forceinline__ void gload_lds(const void* g, void* l) {
  __builtin_amdgcn_global_load_lds(
      (const __attribute__((address_space(1))) unsigned int*)g,
      (__attribute__((address_space(3))) unsigned int*)l, 16, 0, 0);
}

// ---------------- prep kernels ----------------
__global__ void k_extract_x(const float* __restrict__ hist, float* __restrict__ xe) {
  int idx = blockIdx.x * 256 + threadIdx.x;
  if (idx >= BB*LEN_E*NV) return;
  xe[idx] = hist[(size_t)idx * 5];
}

__global__ void k_marks_enc(const float* __restrict__ hist, float* __restrict__ xme) {
  int idx = blockIdx.x * 256 + threadIdx.x;
  if (idx >= BB*LEN_E*4) return;
  int f = idx & 3;
  int r = idx >> 2;
  xme[idx] = hist[((size_t)r * NV) * 5 + 1 + f];
}

__global__ void k_marks_dec(const float* __restrict__ fut, const float* __restrict__ xme,
                            float* __restrict__ xmd) {
  int idx = blockIdx.x * 256 + threadIdx.x;
  if (idx >= BB*LEN_D*4) return;
  int f = idx & 3;
  int r = idx >> 2;
  int t = r % LEN_D, b = r / LEN_D;
  float v;
  if (t < 360) v = xme[((b*LEN_E) + 360 + t)*4 + f];
  else v = fut[(((size_t)(b*LEN_E + (t-360))) * NV) * 5 + 1 + f];
  xmd[idx] = v;
}

__global__ void k_ms_part(const float* __restrict__ xe, float* __restrict__ part,
                          int chl, int nch) {
  int n = threadIdx.x;
  if (n >= NV) return;
  int b = blockIdx.x, c = blockIdx.y;
  int l0 = c*chl, l1 = l0 + chl; if (l1 > LEN_E) l1 = LEN_E;
  float s = 0.f;
  for (int l = l0; l < l1; ++l) s += xe[((size_t)b*LEN_E + l)*NV + n];
  part[((size_t)b*nch + c)*NV + n] = s;
}
__global__ void k_ms_fin(const float* __restrict__ part, float* __restrict__ mb, int nch) {
  int i = blockIdx.x*256 + threadIdx.x;
  if (i >= BB*NV) return;
  int b = i / NV, n = i % NV;
  float s = 0.f;
  for (int c = 0; c < nch; ++c) s += part[((size_t)b*nch + c)*NV + n];
  mb[i] = s * (1.f/(float)LEN_E);
}

// seas full (B,1080,NV); trend ONLY remapped rows (b, t>=360) -> (b*720+(t-360), n)
__global__ void k_init_decomp(const float* __restrict__ xe, const float* __restrict__ mb,
                              float* __restrict__ seas, float* __restrict__ trend) {
  int idx = blockIdx.x * 256 + threadIdx.x;
  if (idx >= BB*LEN_D*NV) return;
  int n = idx % NV; int r = idx / NV; int t = r % LEN_D; int b = r / LEN_D;
  if (t < 360) {
    int l = 360 + t;
    float s = 0.f;
    for (int j = -12; j <= 12; ++j) {
      int lc = l + j; if (lc > LEN_E-1) lc = LEN_E-1; if (lc < 0) lc = 0;
      s += xe[((size_t)b*LEN_E + lc)*NV + n];
    }
    float ma = s * (1.f/25.f);
    seas[idx]  = xe[((size_t)b*LEN_E + l)*NV + n] - ma;
  } else {
    trend[((size_t)(b*LEN_E + (t - 360)))*NV + n] = mb[b*NV + n];
    seas[idx]  = 0.f;
  }
}

// marks embedding, dual output: X += marks@Wt.T (fp32) and tiled bf16 pair
__global__ void k_marks_add(float* __restrict__ X, const float* __restrict__ xm,
                            const float* __restrict__ Wt, u16* __restrict__ pair, int M) {
  int idx = blockIdx.x*256 + threadIdx.x;
  if (idx >= M*DD) return;
  int d = idx & 511, r = idx >> 9;
  const float* m4 = xm + (size_t)r*4;
  const float* w4 = Wt + (size_t)d*4;
  float v = X[idx] + m4[0]*w4[0] + m4[1]*w4[1] + m4[2]*w4[2] + m4[3]*w4[3];
  X[idx] = v;
  u16 hh = f2bf(v);
  size_t o = toff(r, d, 16);
  pair[o] = hh; pair[o + 4096] = f2bf(v - bf2f(hh));
}

// ---------------- split builders (tiled pair output) ----------------
__global__ void k_split_plain(const float* __restrict__ src, u16* __restrict__ dst,
                              int K, int Kp) {
  int col = blockIdx.x*256 + threadIdx.x;
  if (col >= Kp) return;
  int r = blockIdx.y;
  float v = (col < K) ? src[(size_t)r*K + col] : 0.f;
  u16 hh = f2bf(v);
  size_t o = toff(r, col, Kp >> 5);
  dst[o] = hh; dst[o + 4096] = f2bf(v - bf2f(hh));
}

// circular conv3 gather with row remap: out row r (r0+rr) -> b = r/Lout,
// t = (r%Lout) + tbase; sources wrap in [0,Lsrc).
__global__ void k_split_conv(const float* __restrict__ src, u16* __restrict__ dst,
                             int r0, int Lsrc, int Lout, int tbase,
                             int Din, int K, int Kp) {
  int col = blockIdx.x*256 + threadIdx.x;
  if (col >= Kp) return;
  int rr = blockIdx.y;
  int r = r0 + rr;
  int b = r / Lout, t = (r - b*Lout) + tbase;
  float v = 0.f;
  if (col < K) {
    int c = (col >= 2*Din) ? 2 : ((col >= Din) ? 1 : 0);
    int n = col - c*Din;
    int tt = t + c - 1;
    if (tt < 0) tt = Lsrc - 1; else if (tt >= Lsrc) tt -= Lsrc;
    v = src[((size_t)(b*Lsrc + tt))*Din + n];
  }
  u16 hh = f2bf(v);
  size_t o = toff(rr, col, Kp >> 5);
  dst[o] = hh; dst[o + 4096] = f2bf(v - bf2f(hh));
}

__global__ void k_split_tr(const float* __restrict__ src, u16* __restrict__ dst,
                           int Lc, int Kp) {
  __shared__ float t[32][33];
  int b = blockIdx.z;
  int l0 = blockIdx.x*32, c0 = blockIdx.y*32;
  int lx = threadIdx.x, ly = threadIdx.y;   // (32,8)
  #pragma unroll
  for (int i = 0; i < 4; ++i) {
    int ll = l0 + ly + i*8;
    t[ly + i*8][lx] = (ll < Lc) ? src[((size_t)b*Lc + ll)*DD + c0 + lx] : 0.f;
  }
  __syncthreads();
  int ktn = Kp >> 5;
  #pragma unroll
  for (int i = 0; i < 4; ++i) {
    int ch = c0 + ly + i*8;
    int ll = l0 + lx;
    float v = t[lx][ly + i*8];
    u16 hh = f2bf(v);
    size_t o = toff(b*DD + ch, ll, ktn);
    dst[o] = hh; dst[o + 4096] = f2bf(v - bf2f(hh));
  }
}

// conv-embed weight: [512][1024] (cols >=963 zero)
__global__ void k_build_wconvS(const float* __restrict__ Wv, u16* __restrict__ dst) {
  int col = blockIdx.x*256 + threadIdx.x;
  if (col >= 1024) return;
  int d = blockIdx.y;
  float v = 0.f;
  if (col < 963) {
    int c = (col >= 642) ? 2 : ((col >= 321) ? 1 : 0);
    int n = col - c*321;
    v = Wv[(size_t)d*963 + n*3 + c];
  }
  u16 hh = f2bf(v);
  size_t o = toff(d, col, 32);
  dst[o] = hh; dst[o + 4096] = f2bf(v - bf2f(hh));
}

__global__ void k_build_wtrcS(const float* __restrict__ Wtr, u16* __restrict__ dst) {
  int col = blockIdx.x*256 + threadIdx.x;
  if (col >= 1536) return;
  int n = blockIdx.y;
  int c = col >> 9, d = col & 511;
  float v = Wtr[(size_t)n*1536 + d*3 + c];
  u16 hh = f2bf(v);
  size_t o = toff(n, col, 48);
  dst[o] = hh; dst[o + 4096] = f2bf(v - bf2f(hh));
}

__global__ void k_build_dftS(u16* __restrict__ dst, int L, int Kp) {
  int col = blockIdx.x*256 + threadIdx.x;
  if (col >= Kp) return;
  int mr = blockIdx.y;
  float v = 0.f;
  if (col < L) {
    int m = mr & 63;
    int ph = (m * col) % L;
    float th = 6.2831853071795864f * ((float)ph / (float)L);
    v = (mr < 64) ? cosf(th) : -sinf(th);
  }
  u16 hh = f2bf(v);
  size_t o = toff(mr, col, Kp >> 5);
  dst[o] = hh; dst[o + 4096] = f2bf(v - bf2f(hh));
}

__global__ void k_build_irS(u16* __restrict__ dst, int L) {
  int k = threadIdx.x;   // 0..127
  int ll = blockIdx.y;
  int m = k & 63;
  int ph = (m * ll) % L;
  float th = 6.2831853071795864f * ((float)ph / (float)L);
  float v;
  if (k < 64) v = (m == 0) ? (1.f/(float)L) : (2.f/(float)L) * cosf(th);
  else        v = (m == 0) ? 0.f            : -(2.f/(float)L) * sinf(th);
  u16 hh = f2bf(v);
  size_t o = toff(ll, k, 4);
  dst[o] = hh; dst[o + 4096] = f2bf(v - bf2f(hh));
}

// ---------------- MFMA GEMM: 512-thr / 8-wave, 128x64 tile, 2 K-tiles/phase ---
// EPI bits: 1=bias, 2=res(fp32), 4=gelu, 8=res from tiled pair (Nc=512 layout)
// WOUT: 0=fp32 C, 1=pair Cout, 2=remap pair, 3=single-bf16 Cout
// AMODE: 0=pair (3 MFMA), 1=single tiled (2 MFMA, 4096 u16/tile),
//        2=pair layout, hi half only (2 MFMA, 8192 u16/tile stride, 8KB staged)
template<int EPI, int WOUT, int KS, int AMODE>
__global__ __launch_bounds__(512)
void k_mg(const u16* __restrict__ A, const u16* __restrict__ B,
          const float* __restrict__ bias, const float* __restrict__ res,
          const u16* __restrict__ resp,
          float* __restrict__ C, u16* __restrict__ Cout,
          int M, int Nc, int K, int Lout)
{
  __shared__ __attribute__((aligned(16))) u16 sA[AMODE ? 8192 : 16384];
  __shared__ __attribute__((aligned(16))) u16 sB[8192];

  const int tid  = threadIdx.x;
  const int lane = tid & 63;
  const int wave = tid >> 6;          // 0..7
  const int lr   = lane & 15;
  const int kg   = lane >> 4;
  const int wr   = wave >> 1;         // row group (32 rows)
  const int wc   = wave & 1;          // col group (32 cols)

  const int gx  = gridDim.x;
  const int nwg = gx * gridDim.y;
  const int lid = blockIdx.y * gx + blockIdx.x;
  const int q8  = nwg >> 3, r8 = nwg & 7;
  const int xcd = lid & 7, i8 = lid >> 3;
  const int swz = (xcd < r8 ? xcd*(q8+1) : r8*(q8+1) + (xcd - r8)*q8) + i8;
  const int row0 = (swz / gx) * 128;
  const int col0 = (swz % gx) * 64;

  const int ksteps = K >> 5;
  const int zz = (KS > 1) ? (int)blockIdx.z : 0;
  const int t0 = (KS > 1) ? (int)(((long long)ksteps * zz) / KS) : 0;
  const int t1 = (KS > 1) ? (int)(((long long)ksteps * (zz+1)) / KS) : ksteps;

  const char* gA = (const char*)(A + (((size_t)(row0 >> 7) * ksteps) << (AMODE == 1 ? 12 : 13)));
  const char* gB = (const char*)(B + (((size_t)(col0 >> 7) * ksteps) << 13));
  const int bhalf = (col0 & 64) << 6;

  const int wlane = (wave << 10) + (lane << 4);
  const int wbase = (wave << 10);
  const int bso = (wave < 4) ? (bhalf + (wave << 10))
                             : (8192 + bhalf + ((wave - 4) << 10));

  floatx4 acc[2][2] = {};

  auto stageA = [&](int kt, int slot) {
    if (AMODE == 1) {
      const char* ta = gA + ((size_t)kt << 13);
      char* la = (char*)sA + (slot << 13);
      gload_lds(ta + wlane, la + wbase);
    } else if (AMODE == 2) {
      const char* ta = gA + ((size_t)kt << 14);   // pair tile stride, hi half only
      char* la = (char*)sA + (slot << 13);
      gload_lds(ta + wlane, la + wbase);
    } else {
      const char* ta = gA + ((size_t)kt << 14);
      char* la = (char*)sA + (slot << 14);
      gload_lds(ta + wlane, la + wbase);
      gload_lds(ta + 8192 + wlane, la + 8192 + wbase);
    }
  };
  auto stageB = [&](int kt, int slot) {
    const char* tb = gB + ((size_t)kt << 14);
    gload_lds(tb + bso + (lane << 4), (char*)sB + (slot << 13) + wbase);
  };
  auto compute = [&](int slot) {
    const u16* cA = sA + (slot << (AMODE ? 12 : 13));
    const u16* cB = sB + (slot << 12);   // slot * 4096 u16
    short8 ahf[2], alf[2], bhf[2], blf[2];
    #pragma unroll
    for (int f = 0; f < 2; ++f) {
      int row = wr*32 + f*16 + lr;
      int sw = kg ^ (row & 3) ^ ((row >> 2) & 3);
      int off = (row << 5) + (sw << 3);
      ahf[f] = *(const short8*)&cA[off];
      if (!AMODE) alf[f] = *(const short8*)&cA[4096 + off];
    }
    #pragma unroll
    for (int n = 0; n < 2; ++n) {
      int row = wc*32 + n*16 + lr;
      int sw = kg ^ (row & 3) ^ ((row >> 2) & 3);
      int off = (row << 5) + (sw << 3);
      bhf[n] = *(const short8*)&cB[off];
      blf[n] = *(const short8*)&cB[2048 + off];
    }
    #pragma unroll
    for (int f = 0; f < 2; ++f)
      #pragma unroll
      for (int n = 0; n < 2; ++n) {
        acc[f][n] = __builtin_amdgcn_mfma_f32_16x16x32_bf16(ahf[f], bhf[n], acc[f][n], 0, 0, 0);
        acc[f][n] = __builtin_amdgcn_mfma_f32_16x16x32_bf16(ahf[f], blf[n], acc[f][n], 0, 0, 0);
        if (!AMODE)
          acc[f][n] = __builtin_amdgcn_mfma_f32_16x16x32_bf16(alf[f], bhf[n], acc[f][n], 0, 0, 0);
      }
  };

  for (int kt = t0; kt < t1; ) {
    const bool pair = (kt + 1 < t1);
    stageA(kt, 0); stageB(kt, 0);
    if (pair) { stageA(kt + 1, 1); stageB(kt + 1, 1); }
    __syncthreads();
    compute(0);
    if (pair) compute(1);
    __syncthreads();
    kt += pair ? 2 : 1;
  }

  if (KS > 1) {
    float* Cp = C + (size_t)zz * ((size_t)M * Nc);
    #pragma unroll
    for (int n = 0; n < 2; ++n) {
      int cN = col0 + wc*32 + n*16 + lr;
      if (cN >= Nc) continue;
      #pragma unroll
      for (int f = 0; f < 2; ++f)
        #pragma unroll
        for (int i = 0; i < 4; ++i) {
          int rM = row0 + wr*32 + f*16 + kg*4 + i;
          if (rM >= M) continue;
          Cp[(size_t)rM * Nc + cN] = acc[f][n][i];
        }
    }
  } else {
    #pragma unroll
    for (int n = 0; n < 2; ++n) {
      int cN = col0 + wc*32 + n*16 + lr;
      if (cN >= Nc) continue;
      #pragma unroll
      for (int f = 0; f < 2; ++f) {
        #pragma unroll
        for (int i = 0; i < 4; ++i) {
          int rM = row0 + wr*32 + f*16 + kg*4 + i;
          if (rM >= M) continue;
          float v = acc[f][n][i];
          if (EPI & 1) v += bias[cN];
          if (EPI & 4) v = 0.5f * v * (1.f + erff(v * 0.7071067811865476f));
          if (EPI & 2) v += res[(size_t)rM * Nc + cN];
          if (EPI & 8) {
            size_t ro = toff(rM, cN, 16);
            v += bf2f(resp[ro]) + bf2f(resp[ro + 4096]);
          }
          if (WOUT == 1) {
            u16 hh = f2bf(v);
            size_t o = toff(rM, cN, Nc >> 5);
            Cout[o] = hh; Cout[o + 4096] = f2bf(v - bf2f(hh));
          } else if (WOUT == 2) {
            int b = rM >> 9, ch = rM & 511;
            int fl = ch * Lout + cN;
            int r2 = b * Lout + (fl >> 9);
            int c2 = fl & 511;
            u16 hh = f2bf(v);
            size_t o = toff(r2, c2, 16);
            Cout[o] = hh; Cout[o + 4096] = f2bf(v - bf2f(hh));
          } else if (WOUT == 3) {
            size_t o = toffS(rM, cN, Nc >> 5);
            Cout[o] = f2bf(v);
          } else {
            C[(size_t)rM * Nc + cN] = v;
          }
        }
      }
    }
  }
}

// ---------------- split-K reduce (fixed order, deterministic) ----------------
__global__ void k_red(const float* __restrict__ p, int parts, size_t stride,
                      const float* __restrict__ res, float* __restrict__ out, size_t n) {
  size_t i = (size_t)blockIdx.x*256 + threadIdx.x;
  if (i >= n) return;
  float s = res ? res[i] : 0.f;
  for (int z = 0; z < parts; ++z) s += p[(size_t)z*stride + i];
  out[i] = s;
}

// split-K reduce with residual reconstructed from tiled bf16 pair (K=512 layout)
__global__ void k_redp(const float* __restrict__ p, int parts, size_t stride,
                       const u16* __restrict__ resp, float* __restrict__ out, size_t n) {
  size_t i = (size_t)blockIdx.x*256 + threadIdx.x;
  if (i >= n) return;
  int row = (int)(i >> 9), d = (int)(i & 511);
  size_t o = toff(row, d, 16);
  float s = bf2f(resp[o]) + bf2f(resp[o + 4096]);
  for (int z = 0; z < parts; ++z) s += p[(size_t)z*stride + i];
  out[i] = s;
}

// ---------------- mode mix: m-coalesced, emits tiled bf16 pair ----------------
__global__ __launch_bounds__(256)
void k_modemix(const float* __restrict__ ftbuf, const float* __restrict__ fr,
               const float* __restrict__ fi, u16* __restrict__ sel, float scale)
{
  int tid = threadIdx.x;
  int m = tid & 63, ol = tid >> 6;
  int h = blockIdx.y, o = blockIdx.x*4 + ol;
  int b0 = blockIdx.z * 8;
  float accr[8] = {}, acci[8] = {};
  const float* fb = ftbuf + (((size_t)b0*DD + h*64)*128) + m;
  size_t wof = ((((size_t)h*64)*64 + o) << 6) + m;
  for (int e = 0; e < 64; ++e) {
    float wr = fr[wof];
    float wi = fi[wof];
    const float* fe = fb + e*128;
    #pragma unroll
    for (int b = 0; b < 8; ++b) {
      float xr = fe[(size_t)b*65536];
      float xi = fe[(size_t)b*65536 + 64];
      accr[b] += xr*wr - xi*wi;
      acci[b] += xr*wi + xi*wr;
    }
    wof += 4096;
  }
  #pragma unroll
  for (int b = 0; b < 8; ++b) {
    int row = (b0 + b)*DD + h*64 + o;
    float vr = accr[b]*scale, vi2 = acci[b]*scale;
    u16 hr = f2bf(vr);
    size_t o1 = toff(row, m, 4);
    sel[o1] = hr; sel[o1 + 4096] = f2bf(vr - bf2f(hr));
    u16 hi2 = f2bf(vi2);
    size_t o2 = toff(row, m + 64, 4);
    sel[o2] = hi2; sel[o2 + 4096] = f2bf(vi2 - bf2f(hi2));
  }
}

// ---------------- cross attention ----------------
__global__ __launch_bounds__(256)
void k_cross_qk(const float* __restrict__ qf, const float* __restrict__ kf,
                float* __restrict__ ab)
{
  int bh = blockIdx.x; int b = bh >> 3, h = bh & 7;
  __shared__ float qr[32][64], qi[32][64], kr[32][64], ki[32][64];
  int tid = threadIdx.x;
  int tx = tid & 15, ty = tid >> 4;
  float ar[4][4] = {}, ai[4][4] = {};
  for (int e0 = 0; e0 < 64; e0 += 32) {
    for (int it = 0; it < 8; ++it) {
      int idx = tid + it*256;
      int e = idx >> 6, x = idx & 63;
      size_t rof = ((size_t)b*DD + h*64 + e0 + e)*128;
      qr[e][x] = qf[rof + x]; qi[e][x] = qf[rof + 64 + x];
      kr[e][x] = kf[rof + x]; ki[e][x] = kf[rof + 64 + x];
    }
    __syncthreads();
    for (int e = 0; e < 32; ++e) {
      float xr[4], xi2[4], yr[4], yi[4];
      #pragma unroll
      for (int i = 0; i < 4; ++i) { xr[i] = qr[e][ty*4+i]; xi2[i] = qi[e][ty*4+i]; }
      #pragma unroll
      for (int j = 0; j < 4; ++j) { yr[j] = kr[e][tx*4+j]; yi[j] = ki[e][tx*4+j]; }
      #pragma unroll
      for (int i = 0; i < 4; ++i)
        #pragma unroll
        for (int j = 0; j < 4; ++j) {
          ar[i][j] += xr[i]*yr[j] - xi2[i]*yi[j];
          ai[i][j] += xr[i]*yi[j] + xi2[i]*yr[j];
        }
    }
    __syncthreads();
  }
  #pragma unroll
  for (int i = 0; i < 4; ++i)
    #pragma unroll
    for (int j = 0; j < 4; ++j) {
      float txv = tanhf(ar[i][j]);
      float tyv = tanf(ai[i][j]);
      float den = 1.f + txv*txv*tyv*tyv;
      float re = txv*(1.f + tyv*tyv) / den;
      float im = tyv*(1.f - txv*txv) / den;
      size_t of = ((size_t)bh*64 + (ty*4+i))*128 + tx*4 + j;
      ab[of] = re; ab[of + 64] = im;
    }
}

__global__ __launch_bounds__(256)
void k_cross_v(const float* __restrict__ ab, const float* __restrict__ kf,
               float* __restrict__ v)
{
  int bh = blockIdx.x; int b = bh >> 3, h = bh & 7;
  __shared__ float ar[64][32], ai[64][32], kr[64][32], ki[64][32];
  int tid = threadIdx.x;
  int tx = tid & 15, ty = tid >> 4;
  float vr[4][4] = {}, vi[4][4] = {};
  for (int y0 = 0; y0 < 64; y0 += 32) {
    for (int it = 0; it < 8; ++it) {
      int idx = tid + it*256;
      int r = idx >> 5, y = idx & 31;
      ar[r][y] = ab[((size_t)bh*64 + r)*128 + y0 + y];
      ai[r][y] = ab[((size_t)bh*64 + r)*128 + 64 + y0 + y];
      kr[r][y] = kf[((size_t)b*DD + h*64 + r)*128 + y0 + y];
      ki[r][y] = kf[((size_t)b*DD + h*64 + r)*128 + 64 + y0 + y];
    }
    __syncthreads();
    for (int y = 0; y < 32; ++y) {
      float er[4], ei[4], xr[4], xi2[4];
      #pragma unroll
      for (int i = 0; i < 4; ++i) { er[i] = kr[ty*4+i][y]; ei[i] = ki[ty*4+i][y]; }
      #pragma unroll
      for (int j = 0; j < 4; ++j) { xr[j] = ar[tx*4+j][y]; xi2[j] = ai[tx*4+j][y]; }
      #pragma unroll
      for (int i = 0; i < 4; ++i)
        #pragma unroll
        for (int j = 0; j < 4; ++j) {
          vr[i][j] += xr[j]*er[i] - xi2[j]*ei[i];
          vi[i][j] += xr[j]*ei[i] + xi2[j]*er[i];
        }
    }
    __syncthreads();
  }
  #pragma unroll
  for (int i = 0; i < 4; ++i)
    #pragma unroll
    for (int j = 0; j < 4; ++j) {
      size_t of = ((size_t)b*DD + h*64 + ty*4 + i)*128 + tx*4 + j;
      v[of] = vr[i][j]; v[of + 64] = vi[i][j];
    }
}

// ---------------- LN + column-mean subtract ----------------
__global__ __launch_bounds__(256)
void k_ln(const float* __restrict__ x, const float* __restrict__ g,
          const float* __restrict__ be, float* __restrict__ out)
{
  int r = blockIdx.x; int tid = threadIdx.x;
  float v1 = x[(size_t)r*DD + tid], v2 = x[(size_t)r*DD + 256 + tid];
  float s = v1 + v2, s2 = v1*v1 + v2*v2;
  #pragma unroll
  for (int off = 32; off; off >>= 1) { s += __shfl_down(s, off, 64); s2 += __shfl_down(s2, off, 64); }
  __shared__ float red[8];
  int wid = tid >> 6, lane = tid & 63;
  if (lane == 0) { red[wid] = s; red[4 + wid] = s2; }
  __syncthreads();
  if (tid == 0) {
    float a = red[0]+red[1]+red[2]+red[3];
    float b2 = red[4]+red[5]+red[6]+red[7];
    float mu = a / 512.f;
    float var = b2 / 512.f - mu*mu;
    red[0] = mu; red[1] = rsqrtf(var + 1e-5f);
  }
  __syncthreads();
  float mu = red[0], inv = red[1];
  out[(size_t)r*DD + tid]       = (v1 - mu)*inv*g[tid]       + be[tid];
  out[(size_t)r*DD + 256 + tid] = (v2 - mu)*inv*g[256 + tid] + be[256 + tid];
}

__global__ void k_colsum_part(const float* __restrict__ x, float* __restrict__ part,
                              int L, int chl, int nch) {
  int d = threadIdx.x;
  int b = blockIdx.x, c = blockIdx.y;
  int l0 = c*chl, l1 = l0 + chl; if (l1 > L) l1 = L;
  float s = 0.f;
  for (int l = l0; l < l1; ++l) s += x[(((size_t)b*L + l) << 9) + d];
  part[((size_t)(b*nch + c) << 9) + d] = s;
}
__global__ void k_colsum_fin(const float* __restrict__ part, float* __restrict__ cm,
                             int nch, float inv) {
  int i = blockIdx.x*256 + threadIdx.x;
  int b = i >> 9, d = i & 511;
  float s = 0.f;
  for (int c = 0; c < nch; ++c) s += part[((size_t)(b*nch + c) << 9) + d];
  cm[i] = s * inv;
}
// encoder: full rows
__global__ void k_csub_pair(const float* __restrict__ x, const float* __restrict__ cm,
                            u16* __restrict__ dst, int L) {
  size_t idx = (size_t)blockIdx.x*256 + threadIdx.x;
  if (idx >= (size_t)BB*L*DD) return;
  int d = (int)(idx & 511);
  int r = (int)(idx >> 9);
  int b = r / L;
  float v = x[idx] - cm[(b << 9) | d];
  u16 hh = f2bf(v);
  size_t o = toff(r, d, 16);
  dst[o] = hh; dst[o + 4096] = f2bf(v - bf2f(hh));
}
// decoder: remapped rows (b, 360+tt) -> r' = b*720+tt, pair of 11520 rows
__global__ void k_csub_pairR(const float* __restrict__ x, const float* __restrict__ cm,
                             u16* __restrict__ dst) {
  size_t idx = (size_t)blockIdx.x*256 + threadIdx.x;
  if (idx >= (size_t)BB*LEN_E*DD) return;
  int d = (int)(idx & 511);
  int rp = (int)(idx >> 9);
  int b = rp / LEN_E, tt = rp - b*LEN_E;
  float v = x[(((size_t)(b*LEN_D + 360 + tt)) << 9) + d] - cm[(b << 9) | d];
  u16 hh = f2bf(v);
  size_t o = toff(rp, d, 16);
  dst[o] = hh; dst[o + 4096] = f2bf(v - bf2f(hh));
}

// ---------------- series decomp: sliding-window running sum ----------------
// OUTP=0: fp32 only; OUTP=1: pair only; OUTP=2: both.
template<int ACC, int OUTP>
__global__ __launch_bounds__(512)
void k_decomp(const float* __restrict__ x, float* __restrict__ out,
              u16* __restrict__ outp, float* __restrict__ tsum, int L, int chl)
{
  int d = threadIdx.x;            // 512
  int b = blockIdx.x;
  int l0 = blockIdx.y * chl;
  int l1 = l0 + chl; if (l1 > L) l1 = L;
  const float* xb = x + (((size_t)b*L) << 9) + d;
  float s = 0.f;
  #pragma unroll
  for (int j = -12; j <= 12; ++j) {
    int lc = l0 + j; lc = lc < 0 ? 0 : (lc >= L ? L-1 : lc);
    s += xb[(size_t)lc << 9];
  }
  for (int l = l0; l < l1; ++l) {
    int r = b*L + l;
    size_t o = ((size_t)r << 9) + d;
    float ma = s * (1.f/25.f);
    float v = xb[(size_t)l << 9] - ma;
    if (OUTP == 0 || OUTP == 2) out[o] = v;
    if (OUTP == 1 || OUTP == 2) {
      size_t op = toff(r, d, 16);
      u16 hh = f2bf(v);
      outp[op] = hh; outp[op + 4096] = f2bf(v - bf2f(hh));
    }
    if (ACC == 1) tsum[o] += ma;
    if (ACC == 2) tsum[o] = ma;
    int la = l + 13; if (la >= L) la = L - 1;
    int lr = l - 12; if (lr < 0) lr = 0;
    s += xb[(size_t)la << 9] - xb[(size_t)lr << 9];
  }
}

// =====================================================================
extern "C" void kernel_launch(void* const* d_in, const int* in_sizes, int n_in,
                              void* d_out, int out_size, void* d_ws, size_t ws_size,
                              hipStream_t stream)
{
  (void)in_sizes; (void)n_in; (void)out_size; (void)ws_size;
  const float* history = (const float*)d_in[0];
  const float* future  = (const float*)d_in[1];
  const float* Wv_enc  = (const float*)d_in[2];
  const float* Wt_enc  = (const float*)d_in[3];
  const float* Wv_dec  = (const float*)d_in[4];
  const float* Wt_dec  = (const float*)d_in[5];
  const float* eWq = (const float*)d_in[6];
  const float* ebq = (const float*)d_in[7];
  const float* efr = (const float*)d_in[8];
  const float* efi = (const float*)d_in[9];
  const float* eWo = (const float*)d_in[10];
  const float* ebo = (const float*)d_in[11];
  const float* eW1 = (const float*)d_in[12];
  const float* eW2 = (const float*)d_in[13];
  const float* g_enc = (const float*)d_in[14];
  const float* b_enc = (const float*)d_in[15];
  const float* dWq = (const float*)d_in[16];
  const float* dbq = (const float*)d_in[17];
  const float* dfr = (const float*)d_in[18];
  const float* dfi = (const float*)d_in[19];
  const float* dWo = (const float*)d_in[20];
  const float* dbo = (const float*)d_in[21];
  const float* cWq = (const float*)d_in[22];
  const float* cbq = (const float*)d_in[23];
  const float* cWk = (const float*)d_in[24];
  const float* cbk = (const float*)d_in[25];
  const float* cfr = (const float*)d_in[26];
  const float* cfi = (const float*)d_in[27];
  const float* cWo = (const float*)d_in[28];
  const float* cbo = (const float*)d_in[29];
  const float* dW1 = (const float*)d_in[30];
  const float* dW2 = (const float*)d_in[31];
  const float* Wtr = (const float*)d_in[32];
  const float* g_dec = (const float*)d_in[33];
  const float* b_dec = (const float*)d_in[34];
  const float* Wp  = (const float*)d_in[35];
  const float* bp  = (const float*)d_in[36];

  float* ws = (float*)d_ws;
  size_t off = 0;
  auto alloc = [&](size_t n) { float* p = ws + off; off += (n + 63) & ~(size_t)63; return p; };

  const size_t SL = 1048576;
  const int MP = BB * LEN_E;   // remapped output rows = 11520

  float* btrend = alloc((size_t)BB*LEN_D*NV);   // uses first MP*NV
  float* bTsum  = alloc((size_t)BB*LEN_D*DD);
  float* bX     = alloc((size_t)BB*LEN_D*DD);
  float* bT     = alloc((size_t)BB*LEN_D*DD);
  float* bencout= alloc((size_t)BB*LEN_E*DD);
  float* bseas  = alloc((size_t)BB*LEN_D*NV);
  float* R      = alloc((size_t)11900000);
  float* SB     = alloc((size_t)2*SL + 128);
  float* WceS   = alloc((size_t)512*1024);
  float* WcdS   = alloc((size_t)512*1024);
  float* WtrcS  = alloc((size_t)384*1536);
  float* D720S  = alloc((size_t)128*768);
  float* D1080S = alloc((size_t)128*1088);
  float* I720S  = alloc((size_t)768*128);
  float* I1080S = alloc((size_t)1152*128);
  float* bxme   = alloc((size_t)BB*LEN_E*4);
  float* bxmd   = alloc((size_t)BB*LEN_D*4);
  float* bmean  = alloc((size_t)BB*NV);
  float* bpart  = alloc((size_t)BB*9*DD);
  float* bcm    = alloc((size_t)BB*DD);
  float* bmsp   = alloc((size_t)BB*10*NV);

  float* bxe = bT;   // prep alias (dead before T written)

  auto U = [](float* p) { return (u16*)p; };

  auto splitP = [&](const float* src, float* dst, int M, int K) {
    dim3 g((K + 255)/256, M);
    k_split_plain<<<g,256,0,stream>>>(src, U(dst), K, K);
  };
  auto splitC = [&](const float* src, float* dst, int r0, int Mc, int Lsrc, int Lout,
                    int tbase, int Din, int K, int Kp) {
    dim3 g((Kp + 255)/256, Mc);
    k_split_conv<<<g,256,0,stream>>>(src, U(dst), r0, Lsrc, Lout, tbase, Din, K, Kp);
  };
  auto splitT = [&](const float* src, float* dst, int Lc, int Kp) {
    dim3 g(Kp/32, 16, BB), b(32, 8);
    k_split_tr<<<g,b,0,stream>>>(src, U(dst), Lc, Kp);
  };
  auto red = [&](const float* p, int parts, size_t stride, const float* res,
                 float* out, size_t n) {
    k_red<<<(int)((n + 255)/256),256,0,stream>>>(p, parts, stride, res, out, n);
  };

  auto decomp = [&](const float* in, float* out, int L, int acc) {
    int chl = 45;
    int nch = (L + chl - 1) / chl;
    dim3 g(BB, nch);
    if (acc == 1)      k_decomp<1,0><<<g,512,0,stream>>>(in, out, nullptr, bTsum, L, chl);
    else if (acc == 2) k_decomp<2,0><<<g,512,0,stream>>>(in, out, nullptr, bTsum, L, chl);
    else               k_decomp<0,0><<<g,512,0,stream>>>(in, out, nullptr, nullptr, L, chl);
  };
  auto decompP = [&](const float* in, u16* outp, int L, int acc) {
    int chl = 45;
    int nch = (L + chl - 1) / chl;
    dim3 g(BB, nch);
    if (acc == 1) k_decomp<1,1><<<g,512,0,stream>>>(in, nullptr, outp, bTsum, L, chl);
    else          k_decomp<0,1><<<g,512,0,stream>>>(in, nullptr, outp, nullptr, L, chl);
  };
  auto decompD = [&](const float* in, float* out, u16* outp, int L, int acc) {
    int chl = 45;
    int nch = (L + chl - 1) / chl;
    dim3 g(BB, nch);
    if (acc == 2)      k_decomp<2,2><<<g,512,0,stream>>>(in, out, outp, bTsum, L, chl);
    else               k_decomp<0,2><<<g,512,0,stream>>>(in, out, outp, nullptr, L, chl);
  };

  // FFN: out = reconstruct(inPair) + gelu(hi(inPair)@W1.T)@W2.T
  // GEMM1 AMODE=2 (pair hi-only) writes hidden as SINGLE bf16 (WOUT=3);
  // GEMM2 AMODE=1 split-K=2 + k_redp (residual from full pair).
  const int CHP = 5760;   // ME = 2 chunks, MD = 3 chunks exactly
  float* SA2 = R;         // hidden single tiled (5760x2048 u16 = 5.9M floats)
  auto ffn = [&](const u16* inPair, float* out, const float* W1, const float* W2,
                 int M, float* scratch) {
    splitP(W1, SB, DFF2, DD);
    splitP(W2, SB + SL, DD, DFF2);
    for (int r0 = 0; r0 < M; r0 += CHP) {
      int mc = M - r0; if (mc > CHP) mc = CHP;
      const u16* Ap = inPair + ((size_t)(r0 >> 7) << 17);   // 128 rows = 1<<17 u16
      k_mg<4,3,1,2><<<dim3(32,(mc+127)/128,1),512,0,stream>>>(
          Ap, U(SB), nullptr, nullptr, nullptr, nullptr, U(SA2), mc, DFF2, DD, 0);
      k_mg<0,0,2,1><<<dim3(8,(mc+127)/128,2),512,0,stream>>>(
          U(SA2), U(SB+SL), nullptr, nullptr, nullptr, scratch, nullptr, mc, DD, DFF2, 0);
      k_redp<<<(int)(((size_t)mc*DD + 255)/256),256,0,stream>>>(
          scratch, 2, (size_t)mc*DD, Ap, out + (size_t)r0*DD, (size_t)mc*DD);
    }
  };

  // X += fourier_self(X); X pair must be pre-staged in R (K=512 layout).
  auto fourier_self = [&](float* X, float* T, int L, int KpL, float* DLS, float* ILS,
                          const float* Wq, const float* bq, const float* fr, const float* fi,
                          const float* Wo, const float* bo) {
    int M = BB * L;
    size_t MN8 = (size_t)8192*128;
    float* bqf   = R + 9*SL;
    float* bselp = R + 10*SL;
    splitP(Wq, SB, DD, DD);
    k_mg<1,0,1,0><<<dim3(8,(M+127)/128,1),512,0,stream>>>(
        U(R), U(SB), bq, nullptr, nullptr, T, nullptr, M, DD, DD, 0);
    splitT(T, R, L, KpL);
    k_mg<0,0,4,0><<<dim3(2,64,4),512,0,stream>>>(
        U(R), U(DLS), nullptr, nullptr, nullptr, T, nullptr, BB*DD, 128, KpL, 0);
    red(T, 4, MN8, nullptr, bqf, MN8);
    k_modemix<<<dim3(16,8,2),256,0,stream>>>(bqf, fr, fi, U(bselp), 1.0f);
    k_mg<0,2,1,0><<<dim3((L+63)/64,64,1),512,0,stream>>>(   // irfft -> pair @R
        U(bselp), U(ILS), nullptr, nullptr, nullptr, nullptr, U(R), BB*DD, L, 128, L);
    splitP(Wo, SB, DD, DD);
    k_mg<3,0,1,0><<<dim3(8,(M+127)/128,1),512,0,stream>>>(
        U(R), U(SB), bo, X, nullptr, X, nullptr, M, DD, DD, 0);
  };

  auto myln_pair = [&](const float* in, float* tmp, float* pairdst,
                       const float* g, const float* b, int L) {
    k_ln<<<BB*L,256,0,stream>>>(in, g, b, tmp);
    int chl = L / 9;
    k_colsum_part<<<dim3(BB,9),512,0,stream>>>(tmp, bpart, L, chl, 9);
    k_colsum_fin<<<32,256,0,stream>>>(bpart, bcm, 9, 1.f/(float)L);
    size_t n = (size_t)BB*L*DD;
    k_csub_pair<<<(int)((n+255)/256),256,0,stream>>>(tmp, bcm, U(pairdst), L);
  };

  // ---------------- prep ----------------
  k_extract_x<<<(BB*LEN_E*NV + 255)/256,256,0,stream>>>(history, bxe);
  k_marks_enc<<<(BB*LEN_E*4 + 255)/256,256,0,stream>>>(history, bxme);
  k_marks_dec<<<(BB*LEN_D*4 + 255)/256,256,0,stream>>>(future, bxme, bxmd);
  k_ms_part<<<dim3(BB,10),384,0,stream>>>(bxe, bmsp, 72, 10);
  k_ms_fin<<<(BB*NV + 255)/256,256,0,stream>>>(bmsp, bmean, 10);
  k_init_decomp<<<(BB*LEN_D*NV + 255)/256,256,0,stream>>>(bxe, bmean, bseas, btrend);
  k_build_wconvS<<<dim3(4,512),256,0,stream>>>(Wv_enc, U(WceS));
  k_build_wconvS<<<dim3(4,512),256,0,stream>>>(Wv_dec, U(WcdS));
  k_build_wtrcS<<<dim3(6,321),256,0,stream>>>(Wtr, U(WtrcS));
  k_build_dftS<<<dim3(3,128),256,0,stream>>>(U(D720S), LEN_E, 768);
  k_build_dftS<<<dim3(5,128),256,0,stream>>>(U(D1080S), LEN_D, 1088);
  k_build_irS<<<dim3(1,LEN_E),128,0,stream>>>(U(I720S), LEN_E);
  k_build_irS<<<dim3(1,LEN_D),128,0,stream>>>(U(I1080S), LEN_D);

  // ---------------- encoder ----------------
  int ME = BB * LEN_E;
  // conv-embed in ONE dispatch: 720 blocks, KS=1, no reduce
  splitC(bxe, R, 0, ME, LEN_E, LEN_E, 0, NV, 963, 1024);
  k_mg<0,0,1,0><<<dim3(8,90,1),512,0,stream>>>(
      U(R), U(WceS), nullptr, nullptr, nullptr, bX, nullptr, ME, DD, 1024, 0);
  k_marks_add<<<(ME*DD + 255)/256,256,0,stream>>>(bX, bxme, Wt_enc, U(R), ME);

  float *X = bX, *T = bT;
  for (int i = 0; i < 2; ++i) {
    fourier_self(X, T, LEN_E, 768, D720S, I720S,
                 eWq + (size_t)i*DD*DD, ebq + (size_t)i*DD,
                 efr + (size_t)i*HHN*64*64*64, efi + (size_t)i*HHN*64*64*64,
                 eWo + (size_t)i*DD*DD, ebo + (size_t)i*DD);
    decompP(X, U(T), LEN_E, 0);                         // T = seasonal PAIR
    ffn(U(T), X, eW1 + (size_t)i*DFF2*DD, eW2 + (size_t)i*DD*DFF2, ME, bencout);
    if (i == 0) decompD(X, T, U(R), LEN_E, 0);          // T fp32 + R pair (next fourier)
    else        decomp(X, T, LEN_E, 0);                 // T fp32 only
    { float* tmp = X; X = T; T = tmp; }
  }
  myln_pair(X, T, bencout, g_enc, b_enc, LEN_E);   // bencout = tiled pair (ME,512)

  // ---------------- decoder ----------------
  int MD = BB * LEN_D;
  for (int r0 = 0; r0 < MD; r0 += 8640) {               // 2 chunks, KS=1 (544 blocks)
    splitC(bseas, R, r0, 8640, LEN_D, LEN_D, 0, NV, 963, 1024);
    k_mg<0,0,1,0><<<dim3(8,68,1),512,0,stream>>>(
        U(R), U(WcdS), nullptr, nullptr, nullptr, X + (size_t)r0*DD, nullptr,
        8640, DD, 1024, 0);
  }
  k_marks_add<<<(MD*DD + 255)/256,256,0,stream>>>(X, bxmd, Wt_dec, U(R), MD);

  fourier_self(X, T, LEN_D, 1088, D1080S, I1080S, dWq, dbq, dfr, dfi, dWo, dbo);

  decompD(X, T, U(R), LEN_D, 2);      // T fp32 + R pair, tsum = t1

  // cross attention (q-projection first: consumes R pair before splitT clobbers R)
  {
    size_t MN8 = (size_t)8192*128;
    float* bkf = R + 9*SL;
    float* bqf = R + 10*SL;
    splitP(cWq, SB, DD, DD);
    k_mg<1,0,1,0><<<dim3(8,135,1),512,0,stream>>>(       // q proj from R pair
        U(R), U(SB), cbq, nullptr, nullptr, X, nullptr, MD, DD, DD, 0);
    splitT(X, R, LEN_D, 1088);
    k_mg<0,0,4,0><<<dim3(2,64,4),512,0,stream>>>(
        U(R), U(D1080S), nullptr, nullptr, nullptr, X, nullptr, BB*DD, 128, 1088, 0);
    red(X, 4, MN8, nullptr, bqf, MN8);
    splitP(cWk, SB, DD, DD);
    k_mg<1,0,1,0><<<dim3(8,90,1),512,0,stream>>>(        // k proj from bencout pair
        U(bencout), U(SB), cbk, nullptr, nullptr, X, nullptr, ME, DD, DD, 0);
    splitT(X, R, LEN_E, 768);
    k_mg<0,0,4,0><<<dim3(2,64,4),512,0,stream>>>(
        U(R), U(D720S), nullptr, nullptr, nullptr, X, nullptr, BB*DD, 128, 768, 0);
    red(X, 4, MN8, nullptr, bkf, MN8);
    float* ba = R;
    float* bv = R + SL;
    float* bselp = R + 2*SL;
    k_cross_qk<<<BB*HHN,256,0,stream>>>(bqf, bkf, ba);
    k_cross_v<<<BB*HHN,256,0,stream>>>(ba, bkf, bv);
    k_modemix<<<dim3(16,8,2),256,0,stream>>>(bv, cfr, cfi, U(bselp), 1.0f/262144.0f);
    k_mg<0,2,1,0><<<dim3(17,64,1),512,0,stream>>>(      // irfft -> pair @X
        U(bselp), U(I1080S), nullptr, nullptr, nullptr, nullptr, U(X), BB*DD, LEN_D, 128, LEN_D);
    splitP(cWo, SB, DD, DD);
    k_mg<3,0,1,0><<<dim3(8,135,1),512,0,stream>>>(
        U(X), U(SB), cbo, T, nullptr, T, nullptr, MD, DD, DD, 0);
  }

  decompP(T, U(X), LEN_D, 1);         // X = seasonal PAIR, tsum += t2
  ffn(U(X), T, dW1, dW2, MD, bencout);// T = x + FFN(x)
  decomp(T, X, LEN_D, 1);             // X fp32, tsum += t3

  // decoder LN + col-mean; emit REMAPPED pair (rows t>=360 only) into bencout
  {
    k_ln<<<BB*LEN_D,256,0,stream>>>(X, g_dec, b_dec, T);
    k_colsum_part<<<dim3(BB,9),512,0,stream>>>(T, bpart, LEN_D, LEN_D/9, 9);
    k_colsum_fin<<<32,256,0,stream>>>(bpart, bcm, 9, 1.f/(float)LEN_D);
    k_csub_pairR<<<(int)(((size_t)MP*DD + 255)/256),256,0,stream>>>(T, bcm, U(bencout));
  }

  // trend conv: split-K=2 (540 blocks) + reduce accumulating into btrend
  for (int r0 = 0; r0 < MP; r0 += 5760) {
    splitC(bTsum, R, r0, 5760, LEN_D, LEN_E, 360, DD, 1536, 1536);
    k_mg<0,0,2,0><<<dim3(6,45,2),512,0,stream>>>(
        U(R), U(WtrcS), nullptr, nullptr, nullptr, bX, nullptr, 5760, NV, 1536, 0);
    red(bX, 2, (size_t)5760*NV, btrend + (size_t)r0*NV, btrend + (size_t)r0*NV,
        (size_t)5760*NV);
  }

  // seasonal + trend -> d_out (fused, no k_final)
  splitP(Wp, SB, NV, DD);
  k_mg<3,0,1,0><<<dim3(6,90,1),512,0,stream>>>(
      U(bencout), U(SB), bp, btrend, nullptr, (float*)d_out, nullptr, MP, NV, DD, 0);
}

// Round 25
// 1783.874 us; speedup vs baseline: 1.2952x; 1.0883x over previous
//
#include <hip/hip_runtime.h>
#include <math.h>

#define BB 16
#define DD 512
#define HHN 8
#define LEN_E 720
#define LEN_D 1080
#define NV 321
#define DFF2 2048

typedef __attribute__((ext_vector_type(8))) short short8;
typedef __attribute__((ext_vector_type(4))) float floatx4;
typedef unsigned short u16;

__device__ __forceinline__ u16 f2bf(float v) {
  unsigned u = __builtin_bit_cast(unsigned, v);
  u += 0x7FFFu + ((u >> 16) & 1u);
  return (u16)(u >> 16);
}
__device__ __forceinline__ float bf2f(u16 h) {
  unsigned u = ((unsigned)h) << 16;
  return __builtin_bit_cast(float, u);
}

// element offset (u16) of (r,k) in tiled pair buffer; lo at +4096.
// tile = 128 rows x 32 cols, 8192 u16 (hi 4096 + lo 4096), XOR-swizzled slots.
__device__ __forceinline__ size_t toff(int r, int k, int ktn) {
  int rt = r >> 7, rr = r & 127;
  int kt = k >> 5, kk = k & 31;
  int sw = (kk >> 3) ^ (rr & 3) ^ ((rr >> 2) & 3);
  return (((size_t)(rt * ktn + kt)) << 13) + (rr << 5) + (sw << 3) + (kk & 7);
}
// single-bf16 tiled layout: tile = 128x32 = 4096 u16, same intra-tile swizzle.
__device__ __forceinline__ size_t toffS(int r, int k, int ktn) {
  int rt = r >> 7, rr = r & 127;
  int kt = k >> 5, kk = k & 31;
  int sw = (kk >> 3) ^ (rr & 3) ^ ((rr >> 2) & 3);
  return (((size_t)(rt * ktn + kt)) << 12) + (rr << 5) + (sw << 3) + (kk & 7);
}

__device__ __forceinline__ void gload_lds(const void* g, void* l) {
  __builtin_amdgcn_global_load_lds(
      (const __attribute__((address_space(1))) unsigned int*)g,
      (__attribute__((address_space(3))) unsigned int*)l, 16, 0, 0);
}

// ---------------- prep kernels ----------------
__global__ void k_extract_x(const float* __restrict__ hist, float* __restrict__ xe) {
  int idx = blockIdx.x * 256 + threadIdx.x;
  if (idx >= BB*LEN_E*NV) return;
  xe[idx] = hist[(size_t)idx * 5];
}

__global__ void k_marks_enc(const float* __restrict__ hist, float* __restrict__ xme) {
  int idx = blockIdx.x * 256 + threadIdx.x;
  if (idx >= BB*LEN_E*4) return;
  int f = idx & 3;
  int r = idx >> 2;
  xme[idx] = hist[((size_t)r * NV) * 5 + 1 + f];
}

__global__ void k_marks_dec(const float* __restrict__ fut, const float* __restrict__ xme,
                            float* __restrict__ xmd) {
  int idx = blockIdx.x * 256 + threadIdx.x;
  if (idx >= BB*LEN_D*4) return;
  int f = idx & 3;
  int r = idx >> 2;
  int t = r % LEN_D, b = r / LEN_D;
  float v;
  if (t < 360) v = xme[((b*LEN_E) + 360 + t)*4 + f];
  else v = fut[(((size_t)(b*LEN_E + (t-360))) * NV) * 5 + 1 + f];
  xmd[idx] = v;
}

__global__ void k_ms_part(const float* __restrict__ xe, float* __restrict__ part,
                          int chl, int nch) {
  int n = threadIdx.x;
  if (n >= NV) return;
  int b = blockIdx.x, c = blockIdx.y;
  int l0 = c*chl, l1 = l0 + chl; if (l1 > LEN_E) l1 = LEN_E;
  float s = 0.f;
  for (int l = l0; l < l1; ++l) s += xe[((size_t)b*LEN_E + l)*NV + n];
  part[((size_t)b*nch + c)*NV + n] = s;
}
__global__ void k_ms_fin(const float* __restrict__ part, float* __restrict__ mb, int nch) {
  int i = blockIdx.x*256 + threadIdx.x;
  if (i >= BB*NV) return;
  int b = i / NV, n = i % NV;
  float s = 0.f;
  for (int c = 0; c < nch; ++c) s += part[((size_t)b*nch + c)*NV + n];
  mb[i] = s * (1.f/(float)LEN_E);
}

// seas full (B,1080,NV); trend ONLY remapped rows (b, t>=360) -> (b*720+(t-360), n)
__global__ void k_init_decomp(const float* __restrict__ xe, const float* __restrict__ mb,
                              float* __restrict__ seas, float* __restrict__ trend) {
  int idx = blockIdx.x * 256 + threadIdx.x;
  if (idx >= BB*LEN_D*NV) return;
  int n = idx % NV; int r = idx / NV; int t = r % LEN_D; int b = r / LEN_D;
  if (t < 360) {
    int l = 360 + t;
    float s = 0.f;
    for (int j = -12; j <= 12; ++j) {
      int lc = l + j; if (lc > LEN_E-1) lc = LEN_E-1; if (lc < 0) lc = 0;
      s += xe[((size_t)b*LEN_E + lc)*NV + n];
    }
    float ma = s * (1.f/25.f);
    seas[idx]  = xe[((size_t)b*LEN_E + l)*NV + n] - ma;
  } else {
    trend[((size_t)(b*LEN_E + (t - 360)))*NV + n] = mb[b*NV + n];
    seas[idx]  = 0.f;
  }
}

// marks embedding, dual output: X += marks@Wt.T (fp32) and tiled bf16 pair
__global__ void k_marks_add(float* __restrict__ X, const float* __restrict__ xm,
                            const float* __restrict__ Wt, u16* __restrict__ pair, int M) {
  int idx = blockIdx.x*256 + threadIdx.x;
  if (idx >= M*DD) return;
  int d = idx & 511, r = idx >> 9;
  const float* m4 = xm + (size_t)r*4;
  const float* w4 = Wt + (size_t)d*4;
  float v = X[idx] + m4[0]*w4[0] + m4[1]*w4[1] + m4[2]*w4[2] + m4[3]*w4[3];
  X[idx] = v;
  u16 hh = f2bf(v);
  size_t o = toff(r, d, 16);
  pair[o] = hh; pair[o + 4096] = f2bf(v - bf2f(hh));
}

// ---------------- split builders ----------------
__global__ void k_split_plain(const float* __restrict__ src, u16* __restrict__ dst,
                              int K, int Kp) {
  int col = blockIdx.x*256 + threadIdx.x;
  if (col >= Kp) return;
  int r = blockIdx.y;
  float v = (col < K) ? src[(size_t)r*K + col] : 0.f;
  u16 hh = f2bf(v);
  size_t o = toff(r, col, Kp >> 5);
  dst[o] = hh; dst[o + 4096] = f2bf(v - bf2f(hh));
}

// plain split to SINGLE-bf16 tiled layout
__global__ void k_split_plainS(const float* __restrict__ src, u16* __restrict__ dst,
                               int K, int Kp) {
  int col = blockIdx.x*256 + threadIdx.x;
  if (col >= Kp) return;
  int r = blockIdx.y;
  float v = (col < K) ? src[(size_t)r*K + col] : 0.f;
  dst[toffS(r, col, Kp >> 5)] = f2bf(v);
}

// circular conv3 gather with row remap: out row r (r0+rr) -> b = r/Lout,
// t = (r%Lout) + tbase; sources wrap in [0,Lsrc).
__global__ void k_split_conv(const float* __restrict__ src, u16* __restrict__ dst,
                             int r0, int Lsrc, int Lout, int tbase,
                             int Din, int K, int Kp) {
  int col = blockIdx.x*256 + threadIdx.x;
  if (col >= Kp) return;
  int rr = blockIdx.y;
  int r = r0 + rr;
  int b = r / Lout, t = (r - b*Lout) + tbase;
  float v = 0.f;
  if (col < K) {
    int c = (col >= 2*Din) ? 2 : ((col >= Din) ? 1 : 0);
    int n = col - c*Din;
    int tt = t + c - 1;
    if (tt < 0) tt = Lsrc - 1; else if (tt >= Lsrc) tt -= Lsrc;
    v = src[((size_t)(b*Lsrc + tt))*Din + n];
  }
  u16 hh = f2bf(v);
  size_t o = toff(rr, col, Kp >> 5);
  dst[o] = hh; dst[o + 4096] = f2bf(v - bf2f(hh));
}

__global__ void k_split_tr(const float* __restrict__ src, u16* __restrict__ dst,
                           int Lc, int Kp) {
  __shared__ float t[32][33];
  int b = blockIdx.z;
  int l0 = blockIdx.x*32, c0 = blockIdx.y*32;
  int lx = threadIdx.x, ly = threadIdx.y;   // (32,8)
  #pragma unroll
  for (int i = 0; i < 4; ++i) {
    int ll = l0 + ly + i*8;
    t[ly + i*8][lx] = (ll < Lc) ? src[((size_t)b*Lc + ll)*DD + c0 + lx] : 0.f;
  }
  __syncthreads();
  int ktn = Kp >> 5;
  #pragma unroll
  for (int i = 0; i < 4; ++i) {
    int ch = c0 + ly + i*8;
    int ll = l0 + lx;
    float v = t[lx][ly + i*8];
    u16 hh = f2bf(v);
    size_t o = toff(b*DD + ch, ll, ktn);
    dst[o] = hh; dst[o + 4096] = f2bf(v - bf2f(hh));
  }
}

// conv-embed weight: [512][1024] (cols >=963 zero)
__global__ void k_build_wconvS(const float* __restrict__ Wv, u16* __restrict__ dst) {
  int col = blockIdx.x*256 + threadIdx.x;
  if (col >= 1024) return;
  int d = blockIdx.y;
  float v = 0.f;
  if (col < 963) {
    int c = (col >= 642) ? 2 : ((col >= 321) ? 1 : 0);
    int n = col - c*321;
    v = Wv[(size_t)d*963 + n*3 + c];
  }
  u16 hh = f2bf(v);
  size_t o = toff(d, col, 32);
  dst[o] = hh; dst[o + 4096] = f2bf(v - bf2f(hh));
}

__global__ void k_build_wtrcS(const float* __restrict__ Wtr, u16* __restrict__ dst) {
  int col = blockIdx.x*256 + threadIdx.x;
  if (col >= 1536) return;
  int n = blockIdx.y;
  int c = col >> 9, d = col & 511;
  float v = Wtr[(size_t)n*1536 + d*3 + c];
  u16 hh = f2bf(v);
  size_t o = toff(n, col, 48);
  dst[o] = hh; dst[o + 4096] = f2bf(v - bf2f(hh));
}

__global__ void k_build_dftS(u16* __restrict__ dst, int L, int Kp) {
  int col = blockIdx.x*256 + threadIdx.x;
  if (col >= Kp) return;
  int mr = blockIdx.y;
  float v = 0.f;
  if (col < L) {
    int m = mr & 63;
    int ph = (m * col) % L;
    float th = 6.2831853071795864f * ((float)ph / (float)L);
    v = (mr < 64) ? cosf(th) : -sinf(th);
  }
  u16 hh = f2bf(v);
  size_t o = toff(mr, col, Kp >> 5);
  dst[o] = hh; dst[o + 4096] = f2bf(v - bf2f(hh));
}

__global__ void k_build_irS(u16* __restrict__ dst, int L) {
  int k = threadIdx.x;   // 0..127
  int ll = blockIdx.y;
  int m = k & 63;
  int ph = (m * ll) % L;
  float th = 6.2831853071795864f * ((float)ph / (float)L);
  float v;
  if (k < 64) v = (m == 0) ? (1.f/(float)L) : (2.f/(float)L) * cosf(th);
  else        v = (m == 0) ? 0.f            : -(2.f/(float)L) * sinf(th);
  u16 hh = f2bf(v);
  size_t o = toff(ll, k, 4);
  dst[o] = hh; dst[o + 4096] = f2bf(v - bf2f(hh));
}

// ---------------- MFMA GEMM: 512-thr / 8-wave, 128x64 tile, 2 K-tiles/phase ---
// EPI bits: 1=bias, 2=res(fp32), 4=gelu, 8=res from tiled pair (Nc=512 layout)
// WOUT: 0=fp32 C, 1=pair Cout, 2=remap pair, 3=single-bf16 Cout
// AMODE: 0=pair (A hi+lo), 1=single tiled, 2=pair layout hi-only
// BMODE: 0=pair (B hi+lo), 1=single tiled
template<int EPI, int WOUT, int KS, int AMODE, int BMODE>
__global__ __launch_bounds__(512)
void k_mg(const u16* __restrict__ A, const u16* __restrict__ B,
          const float* __restrict__ bias, const float* __restrict__ res,
          const u16* __restrict__ resp,
          float* __restrict__ C, u16* __restrict__ Cout,
          int M, int Nc, int K, int Lout)
{
  __shared__ __attribute__((aligned(16))) u16 sA[AMODE ? 8192 : 16384];
  __shared__ __attribute__((aligned(16))) u16 sB[BMODE ? 4096 : 8192];

  const int tid  = threadIdx.x;
  const int lane = tid & 63;
  const int wave = tid >> 6;          // 0..7
  const int lr   = lane & 15;
  const int kg   = lane >> 4;
  const int wr   = wave >> 1;         // row group (32 rows)
  const int wc   = wave & 1;          // col group (32 cols)

  const int gx  = gridDim.x;
  const int nwg = gx * gridDim.y;
  const int lid = blockIdx.y * gx + blockIdx.x;
  const int q8  = nwg >> 3, r8 = nwg & 7;
  const int xcd = lid & 7, i8 = lid >> 3;
  const int swz = (xcd < r8 ? xcd*(q8+1) : r8*(q8+1) + (xcd - r8)*q8) + i8;
  const int row0 = (swz / gx) * 128;
  const int col0 = (swz % gx) * 64;

  const int ksteps = K >> 5;
  const int zz = (KS > 1) ? (int)blockIdx.z : 0;
  const int t0 = (KS > 1) ? (int)(((long long)ksteps * zz) / KS) : 0;
  const int t1 = (KS > 1) ? (int)(((long long)ksteps * (zz+1)) / KS) : ksteps;

  const char* gA = (const char*)(A + (((size_t)(row0 >> 7) * ksteps) << (AMODE == 1 ? 12 : 13)));
  const char* gB = (const char*)(B + (((size_t)(col0 >> 7) * ksteps) << (BMODE ? 12 : 13)));
  const int bhalf = (col0 & 64) << 6;    // pair: u16*2 byte offset within tile
  const int bhalfS = (col0 & 64) << 6;   // single: byte offset (row<<6 bytes)

  const int wlane = (wave << 10) + (lane << 4);
  const int wbase = (wave << 10);
  const int bso = (wave < 4) ? (bhalf + (wave << 10))
                             : (8192 + bhalf + ((wave - 4) << 10));

  floatx4 acc[2][2] = {};

  auto stageA = [&](int kt, int slot) {
    if (AMODE == 1) {
      const char* ta = gA + ((size_t)kt << 13);
      char* la = (char*)sA + (slot << 13);
      gload_lds(ta + wlane, la + wbase);
    } else if (AMODE == 2) {
      const char* ta = gA + ((size_t)kt << 14);   // pair tile stride, hi half only
      char* la = (char*)sA + (slot << 13);
      gload_lds(ta + wlane, la + wbase);
    } else {
      const char* ta = gA + ((size_t)kt << 14);
      char* la = (char*)sA + (slot << 14);
      gload_lds(ta + wlane, la + wbase);
      gload_lds(ta + 8192 + wlane, la + 8192 + wbase);
    }
  };
  auto stageB = [&](int kt, int slot) {
    if (BMODE) {
      if (wave < 4) {
        const char* tb = gB + ((size_t)kt << 13);   // single tile = 8192 B
        gload_lds(tb + bhalfS + (wave << 10) + (lane << 4),
                  (char*)sB + (slot << 12) + wbase);
      }
    } else {
      const char* tb = gB + ((size_t)kt << 14);
      gload_lds(tb + bso + (lane << 4), (char*)sB + (slot << 13) + wbase);
    }
  };
  auto compute = [&](int slot) {
    const u16* cA = sA + (slot << (AMODE ? 12 : 13));
    const u16* cB = sB + (slot << (BMODE ? 11 : 12));
    short8 ahf[2], alf[2], bhf[2], blf[2];
    #pragma unroll
    for (int f = 0; f < 2; ++f) {
      int row = wr*32 + f*16 + lr;
      int sw = kg ^ (row & 3) ^ ((row >> 2) & 3);
      int off = (row << 5) + (sw << 3);
      ahf[f] = *(const short8*)&cA[off];
      if (!AMODE) alf[f] = *(const short8*)&cA[4096 + off];
    }
    #pragma unroll
    for (int n = 0; n < 2; ++n) {
      int row = wc*32 + n*16 + lr;
      int sw = kg ^ (row & 3) ^ ((row >> 2) & 3);
      int off = (row << 5) + (sw << 3);
      bhf[n] = *(const short8*)&cB[off];
      if (!BMODE) blf[n] = *(const short8*)&cB[2048 + off];
    }
    #pragma unroll
    for (int f = 0; f < 2; ++f)
      #pragma unroll
      for (int n = 0; n < 2; ++n) {
        acc[f][n] = __builtin_amdgcn_mfma_f32_16x16x32_bf16(ahf[f], bhf[n], acc[f][n], 0, 0, 0);
        if (!BMODE)
          acc[f][n] = __builtin_amdgcn_mfma_f32_16x16x32_bf16(ahf[f], blf[n], acc[f][n], 0, 0, 0);
        if (!AMODE)
          acc[f][n] = __builtin_amdgcn_mfma_f32_16x16x32_bf16(alf[f], bhf[n], acc[f][n], 0, 0, 0);
      }
  };

  for (int kt = t0; kt < t1; ) {
    const bool pair = (kt + 1 < t1);
    stageA(kt, 0); stageB(kt, 0);
    if (pair) { stageA(kt + 1, 1); stageB(kt + 1, 1); }
    __syncthreads();
    compute(0);
    if (pair) compute(1);
    __syncthreads();
    kt += pair ? 2 : 1;
  }

  if (KS > 1) {
    float* Cp = C + (size_t)zz * ((size_t)M * Nc);
    #pragma unroll
    for (int n = 0; n < 2; ++n) {
      int cN = col0 + wc*32 + n*16 + lr;
      if (cN >= Nc) continue;
      #pragma unroll
      for (int f = 0; f < 2; ++f)
        #pragma unroll
        for (int i = 0; i < 4; ++i) {
          int rM = row0 + wr*32 + f*16 + kg*4 + i;
          if (rM >= M) continue;
          Cp[(size_t)rM * Nc + cN] = acc[f][n][i];
        }
    }
  } else {
    #pragma unroll
    for (int n = 0; n < 2; ++n) {
      int cN = col0 + wc*32 + n*16 + lr;
      if (cN >= Nc) continue;
      #pragma unroll
      for (int f = 0; f < 2; ++f) {
        #pragma unroll
        for (int i = 0; i < 4; ++i) {
          int rM = row0 + wr*32 + f*16 + kg*4 + i;
          if (rM >= M) continue;
          float v = acc[f][n][i];
          if (EPI & 1) v += bias[cN];
          if (EPI & 4) v = 0.5f * v * (1.f + erff(v * 0.7071067811865476f));
          if (EPI & 2) v += res[(size_t)rM * Nc + cN];
          if (EPI & 8) {
            size_t ro = toff(rM, cN, 16);
            v += bf2f(resp[ro]) + bf2f(resp[ro + 4096]);
          }
          if (WOUT == 1) {
            u16 hh = f2bf(v);
            size_t o = toff(rM, cN, Nc >> 5);
            Cout[o] = hh; Cout[o + 4096] = f2bf(v - bf2f(hh));
          } else if (WOUT == 2) {
            int b = rM >> 9, ch = rM & 511;
            int fl = ch * Lout + cN;
            int r2 = b * Lout + (fl >> 9);
            int c2 = fl & 511;
            u16 hh = f2bf(v);
            size_t o = toff(r2, c2, 16);
            Cout[o] = hh; Cout[o + 4096] = f2bf(v - bf2f(hh));
          } else if (WOUT == 3) {
            size_t o = toffS(rM, cN, Nc >> 5);
            Cout[o] = f2bf(v);
          } else {
            C[(size_t)rM * Nc + cN] = v;
          }
        }
      }
    }
  }
}

// ---------------- split-K reduce (fixed order, deterministic) ----------------
__global__ void k_red(const float* __restrict__ p, int parts, size_t stride,
                      const float* __restrict__ res, float* __restrict__ out, size_t n) {
  size_t i = (size_t)blockIdx.x*256 + threadIdx.x;
  if (i >= n) return;
  float s = res ? res[i] : 0.f;
  for (int z = 0; z < parts; ++z) s += p[(size_t)z*stride + i];
  out[i] = s;
}

// split-K reduce with residual reconstructed from tiled bf16 pair (K=512 layout)
__global__ void k_redp(const float* __restrict__ p, int parts, size_t stride,
                       const u16* __restrict__ resp, float* __restrict__ out, size_t n) {
  size_t i = (size_t)blockIdx.x*256 + threadIdx.x;
  if (i >= n) return;
  int row = (int)(i >> 9), d = (int)(i & 511);
  size_t o = toff(row, d, 16);
  float s = bf2f(resp[o]) + bf2f(resp[o + 4096]);
  for (int z = 0; z < parts; ++z) s += p[(size_t)z*stride + i];
  out[i] = s;
}

// ---------------- mode mix: m-coalesced, emits tiled bf16 pair ----------------
__global__ __launch_bounds__(256)
void k_modemix(const float* __restrict__ ftbuf, const float* __restrict__ fr,
               const float* __restrict__ fi, u16* __restrict__ sel, float scale)
{
  int tid = threadIdx.x;
  int m = tid & 63, ol = tid >> 6;
  int h = blockIdx.y, o = blockIdx.x*4 + ol;
  int b0 = blockIdx.z * 8;
  float accr[8] = {}, acci[8] = {};
  const float* fb = ftbuf + (((size_t)b0*DD + h*64)*128) + m;
  size_t wof = ((((size_t)h*64)*64 + o) << 6) + m;
  for (int e = 0; e < 64; ++e) {
    float wr = fr[wof];
    float wi = fi[wof];
    const float* fe = fb + e*128;
    #pragma unroll
    for (int b = 0; b < 8; ++b) {
      float xr = fe[(size_t)b*65536];
      float xi = fe[(size_t)b*65536 + 64];
      accr[b] += xr*wr - xi*wi;
      acci[b] += xr*wi + xi*wr;
    }
    wof += 4096;
  }
  #pragma unroll
  for (int b = 0; b < 8; ++b) {
    int row = (b0 + b)*DD + h*64 + o;
    float vr = accr[b]*scale, vi2 = acci[b]*scale;
    u16 hr = f2bf(vr);
    size_t o1 = toff(row, m, 4);
    sel[o1] = hr; sel[o1 + 4096] = f2bf(vr - bf2f(hr));
    u16 hi2 = f2bf(vi2);
    size_t o2 = toff(row, m + 64, 4);
    sel[o2] = hi2; sel[o2 + 4096] = f2bf(vi2 - bf2f(hi2));
  }
}

// ---------------- cross attention ----------------
__global__ __launch_bounds__(256)
void k_cross_qk(const float* __restrict__ qf, const float* __restrict__ kf,
                float* __restrict__ ab)
{
  int bh = blockIdx.x; int b = bh >> 3, h = bh & 7;
  __shared__ float qr[32][64], qi[32][64], kr[32][64], ki[32][64];
  int tid = threadIdx.x;
  int tx = tid & 15, ty = tid >> 4;
  float ar[4][4] = {}, ai[4][4] = {};
  for (int e0 = 0; e0 < 64; e0 += 32) {
    for (int it = 0; it < 8; ++it) {
      int idx = tid + it*256;
      int e = idx >> 6, x = idx & 63;
      size_t rof = ((size_t)b*DD + h*64 + e0 + e)*128;
      qr[e][x] = qf[rof + x]; qi[e][x] = qf[rof + 64 + x];
      kr[e][x] = kf[rof + x]; ki[e][x] = kf[rof + 64 + x];
    }
    __syncthreads();
    for (int e = 0; e < 32; ++e) {
      float xr[4], xi2[4], yr[4], yi[4];
      #pragma unroll
      for (int i = 0; i < 4; ++i) { xr[i] = qr[e][ty*4+i]; xi2[i] = qi[e][ty*4+i]; }
      #pragma unroll
      for (int j = 0; j < 4; ++j) { yr[j] = kr[e][tx*4+j]; yi[j] = ki[e][tx*4+j]; }
      #pragma unroll
      for (int i = 0; i < 4; ++i)
        #pragma unroll
        for (int j = 0; j < 4; ++j) {
          ar[i][j] += xr[i]*yr[j] - xi2[i]*yi[j];
          ai[i][j] += xr[i]*yi[j] + xi2[i]*yr[j];
        }
    }
    __syncthreads();
  }
  #pragma unroll
  for (int i = 0; i < 4; ++i)
    #pragma unroll
    for (int j = 0; j < 4; ++j) {
      float txv = tanhf(ar[i][j]);
      float tyv = tanf(ai[i][j]);
      float den = 1.f + txv*txv*tyv*tyv;
      float re = txv*(1.f + tyv*tyv) / den;
      float im = tyv*(1.f - txv*txv) / den;
      size_t of = ((size_t)bh*64 + (ty*4+i))*128 + tx*4 + j;
      ab[of] = re; ab[of + 64] = im;
    }
}

__global__ __launch_bounds__(256)
void k_cross_v(const float* __restrict__ ab, const float* __restrict__ kf,
               float* __restrict__ v)
{
  int bh = blockIdx.x; int b = bh >> 3, h = bh & 7;
  __shared__ float ar[64][32], ai[64][32], kr[64][32], ki[64][32];
  int tid = threadIdx.x;
  int tx = tid & 15, ty = tid >> 4;
  float vr[4][4] = {}, vi[4][4] = {};
  for (int y0 = 0; y0 < 64; y0 += 32) {
    for (int it = 0; it < 8; ++it) {
      int idx = tid + it*256;
      int r = idx >> 5, y = idx & 31;
      ar[r][y] = ab[((size_t)bh*64 + r)*128 + y0 + y];
      ai[r][y] = ab[((size_t)bh*64 + r)*128 + 64 + y0 + y];
      kr[r][y] = kf[((size_t)b*DD + h*64 + r)*128 + y0 + y];
      ki[r][y] = kf[((size_t)b*DD + h*64 + r)*128 + 64 + y0 + y];
    }
    __syncthreads();
    for (int y = 0; y < 32; ++y) {
      float er[4], ei[4], xr[4], xi2[4];
      #pragma unroll
      for (int i = 0; i < 4; ++i) { er[i] = kr[ty*4+i][y]; ei[i] = ki[ty*4+i][y]; }
      #pragma unroll
      for (int j = 0; j < 4; ++j) { xr[j] = ar[tx*4+j][y]; xi2[j] = ai[tx*4+j][y]; }
      #pragma unroll
      for (int i = 0; i < 4; ++i)
        #pragma unroll
        for (int j = 0; j < 4; ++j) {
          vr[i][j] += xr[j]*er[i] - xi2[j]*ei[i];
          vi[i][j] += xr[j]*ei[i] + xi2[j]*er[i];
        }
    }
    __syncthreads();
  }
  #pragma unroll
  for (int i = 0; i < 4; ++i)
    #pragma unroll
    for (int j = 0; j < 4; ++j) {
      size_t of = ((size_t)b*DD + h*64 + ty*4 + i)*128 + tx*4 + j;
      v[of] = vr[i][j]; v[of + 64] = vi[i][j];
    }
}

// ---------------- LN + column-mean subtract ----------------
__global__ __launch_bounds__(256)
void k_ln(const float* __restrict__ x, const float* __restrict__ g,
          const float* __restrict__ be, float* __restrict__ out)
{
  int r = blockIdx.x; int tid = threadIdx.x;
  float v1 = x[(size_t)r*DD + tid], v2 = x[(size_t)r*DD + 256 + tid];
  float s = v1 + v2, s2 = v1*v1 + v2*v2;
  #pragma unroll
  for (int off = 32; off; off >>= 1) { s += __shfl_down(s, off, 64); s2 += __shfl_down(s2, off, 64); }
  __shared__ float red[8];
  int wid = tid >> 6, lane = tid & 63;
  if (lane == 0) { red[wid] = s; red[4 + wid] = s2; }
  __syncthreads();
  if (tid == 0) {
    float a = red[0]+red[1]+red[2]+red[3];
    float b2 = red[4]+red[5]+red[6]+red[7];
    float mu = a / 512.f;
    float var = b2 / 512.f - mu*mu;
    red[0] = mu; red[1] = rsqrtf(var + 1e-5f);
  }
  __syncthreads();
  float mu = red[0], inv = red[1];
  out[(size_t)r*DD + tid]       = (v1 - mu)*inv*g[tid]       + be[tid];
  out[(size_t)r*DD + 256 + tid] = (v2 - mu)*inv*g[256 + tid] + be[256 + tid];
}

__global__ void k_colsum_part(const float* __restrict__ x, float* __restrict__ part,
                              int L, int chl, int nch) {
  int d = threadIdx.x;
  int b = blockIdx.x, c = blockIdx.y;
  int l0 = c*chl, l1 = l0 + chl; if (l1 > L) l1 = L;
  float s = 0.f;
  for (int l = l0; l < l1; ++l) s += x[(((size_t)b*L + l) << 9) + d];
  part[((size_t)(b*nch + c) << 9) + d] = s;
}
__global__ void k_colsum_fin(const float* __restrict__ part, float* __restrict__ cm,
                             int nch, float inv) {
  int i = blockIdx.x*256 + threadIdx.x;
  int b = i >> 9, d = i & 511;
  float s = 0.f;
  for (int c = 0; c < nch; ++c) s += part[((size_t)(b*nch + c) << 9) + d];
  cm[i] = s * inv;
}
// encoder: full rows
__global__ void k_csub_pair(const float* __restrict__ x, const float* __restrict__ cm,
                            u16* __restrict__ dst, int L) {
  size_t idx = (size_t)blockIdx.x*256 + threadIdx.x;
  if (idx >= (size_t)BB*L*DD) return;
  int d = (int)(idx & 511);
  int r = (int)(idx >> 9);
  int b = r / L;
  float v = x[idx] - cm[(b << 9) | d];
  u16 hh = f2bf(v);
  size_t o = toff(r, d, 16);
  dst[o] = hh; dst[o + 4096] = f2bf(v - bf2f(hh));
}
// decoder: remapped rows (b, 360+tt) -> r' = b*720+tt, pair of 11520 rows
__global__ void k_csub_pairR(const float* __restrict__ x, const float* __restrict__ cm,
                             u16* __restrict__ dst) {
  size_t idx = (size_t)blockIdx.x*256 + threadIdx.x;
  if (idx >= (size_t)BB*LEN_E*DD) return;
  int d = (int)(idx & 511);
  int rp = (int)(idx >> 9);
  int b = rp / LEN_E, tt = rp - b*LEN_E;
  float v = x[(((size_t)(b*LEN_D + 360 + tt)) << 9) + d] - cm[(b << 9) | d];
  u16 hh = f2bf(v);
  size_t o = toff(rp, d, 16);
  dst[o] = hh; dst[o + 4096] = f2bf(v - bf2f(hh));
}

// ---------------- series decomp: sliding-window running sum ----------------
// OUTP=0: fp32 only; OUTP=1: pair only; OUTP=2: both.
template<int ACC, int OUTP>
__global__ __launch_bounds__(512)
void k_decomp(const float* __restrict__ x, float* __restrict__ out,
              u16* __restrict__ outp, float* __restrict__ tsum, int L, int chl)
{
  int d = threadIdx.x;            // 512
  int b = blockIdx.x;
  int l0 = blockIdx.y * chl;
  int l1 = l0 + chl; if (l1 > L) l1 = L;
  const float* xb = x + (((size_t)b*L) << 9) + d;
  float s = 0.f;
  #pragma unroll
  for (int j = -12; j <= 12; ++j) {
    int lc = l0 + j; lc = lc < 0 ? 0 : (lc >= L ? L-1 : lc);
    s += xb[(size_t)lc << 9];
  }
  for (int l = l0; l < l1; ++l) {
    int r = b*L + l;
    size_t o = ((size_t)r << 9) + d;
    float ma = s * (1.f/25.f);
    float v = xb[(size_t)l << 9] - ma;
    if (OUTP == 0 || OUTP == 2) out[o] = v;
    if (OUTP == 1 || OUTP == 2) {
      size_t op = toff(r, d, 16);
      u16 hh = f2bf(v);
      outp[op] = hh; outp[op + 4096] = f2bf(v - bf2f(hh));
    }
    if (ACC == 1) tsum[o] += ma;
    if (ACC == 2) tsum[o] = ma;
    int la = l + 13; if (la >= L) la = L - 1;
    int lr = l - 12; if (lr < 0) lr = 0;
    s += xb[(size_t)la << 9] - xb[(size_t)lr << 9];
  }
}

// =====================================================================
extern "C" void kernel_launch(void* const* d_in, const int* in_sizes, int n_in,
                              void* d_out, int out_size, void* d_ws, size_t ws_size,
                              hipStream_t stream)
{
  (void)in_sizes; (void)n_in; (void)out_size; (void)ws_size;
  const float* history = (const float*)d_in[0];
  const float* future  = (const float*)d_in[1];
  const float* Wv_enc  = (const float*)d_in[2];
  const float* Wt_enc  = (const float*)d_in[3];
  const float* Wv_dec  = (const float*)d_in[4];
  const float* Wt_dec  = (const float*)d_in[5];
  const float* eWq = (const float*)d_in[6];
  const float* ebq = (const float*)d_in[7];
  const float* efr = (const float*)d_in[8];
  const float* efi = (const float*)d_in[9];
  const float* eWo = (const float*)d_in[10];
  const float* ebo = (const float*)d_in[11];
  const float* eW1 = (const float*)d_in[12];
  const float* eW2 = (const float*)d_in[13];
  const float* g_enc = (const float*)d_in[14];
  const float* b_enc = (const float*)d_in[15];
  const float* dWq = (const float*)d_in[16];
  const float* dbq = (const float*)d_in[17];
  const float* dfr = (const float*)d_in[18];
  const float* dfi = (const float*)d_in[19];
  const float* dWo = (const float*)d_in[20];
  const float* dbo = (const float*)d_in[21];
  const float* cWq = (const float*)d_in[22];
  const float* cbq = (const float*)d_in[23];
  const float* cWk = (const float*)d_in[24];
  const float* cbk = (const float*)d_in[25];
  const float* cfr = (const float*)d_in[26];
  const float* cfi = (const float*)d_in[27];
  const float* cWo = (const float*)d_in[28];
  const float* cbo = (const float*)d_in[29];
  const float* dW1 = (const float*)d_in[30];
  const float* dW2 = (const float*)d_in[31];
  const float* Wtr = (const float*)d_in[32];
  const float* g_dec = (const float*)d_in[33];
  const float* b_dec = (const float*)d_in[34];
  const float* Wp  = (const float*)d_in[35];
  const float* bp  = (const float*)d_in[36];

  float* ws = (float*)d_ws;
  size_t off = 0;
  auto alloc = [&](size_t n) { float* p = ws + off; off += (n + 63) & ~(size_t)63; return p; };

  const size_t SL = 1048576;
  const int MP = BB * LEN_E;   // remapped output rows = 11520

  float* btrend = alloc((size_t)BB*LEN_D*NV);   // uses first MP*NV
  float* bTsum  = alloc((size_t)BB*LEN_D*DD);
  float* bX     = alloc((size_t)BB*LEN_D*DD);
  float* bT     = alloc((size_t)BB*LEN_D*DD);
  float* bencout= alloc((size_t)BB*LEN_E*DD);
  float* bseas  = alloc((size_t)BB*LEN_D*NV);
  float* R      = alloc((size_t)11900000);
  float* SB     = alloc((size_t)2*SL + 128);
  float* WceS   = alloc((size_t)512*1024);
  float* WcdS   = alloc((size_t)512*1024);
  float* WtrcS  = alloc((size_t)384*1536);
  float* D720S  = alloc((size_t)128*768);
  float* D1080S = alloc((size_t)128*1088);
  float* I720S  = alloc((size_t)768*128);
  float* I1080S = alloc((size_t)1152*128);
  float* bxme   = alloc((size_t)BB*LEN_E*4);
  float* bxmd   = alloc((size_t)BB*LEN_D*4);
  float* bmean  = alloc((size_t)BB*NV);
  float* bpart  = alloc((size_t)BB*9*DD);
  float* bcm    = alloc((size_t)BB*DD);
  float* bmsp   = alloc((size_t)BB*10*NV);

  float* bxe = bT;   // prep alias (dead before T written)

  auto U = [](float* p) { return (u16*)p; };

  auto splitP = [&](const float* src, float* dst, int M, int K) {
    dim3 g((K + 255)/256, M);
    k_split_plain<<<g,256,0,stream>>>(src, U(dst), K, K);
  };
  auto splitPS = [&](const float* src, float* dst, int M, int K) {
    dim3 g((K + 255)/256, M);
    k_split_plainS<<<g,256,0,stream>>>(src, U(dst), K, K);
  };
  auto splitC = [&](const float* src, float* dst, int r0, int Mc, int Lsrc, int Lout,
                    int tbase, int Din, int K, int Kp) {
    dim3 g((Kp + 255)/256, Mc);
    k_split_conv<<<g,256,0,stream>>>(src, U(dst), r0, Lsrc, Lout, tbase, Din, K, Kp);
  };
  auto splitT = [&](const float* src, float* dst, int Lc, int Kp) {
    dim3 g(Kp/32, 16, BB), b(32, 8);
    k_split_tr<<<g,b,0,stream>>>(src, U(dst), Lc, Kp);
  };
  auto red = [&](const float* p, int parts, size_t stride, const float* res,
                 float* out, size_t n) {
    k_red<<<(int)((n + 255)/256),256,0,stream>>>(p, parts, stride, res, out, n);
  };

  auto decomp = [&](const float* in, float* out, int L, int acc) {
    int chl = 45;
    int nch = (L + chl - 1) / chl;
    dim3 g(BB, nch);
    if (acc == 1)      k_decomp<1,0><<<g,512,0,stream>>>(in, out, nullptr, bTsum, L, chl);
    else if (acc == 2) k_decomp<2,0><<<g,512,0,stream>>>(in, out, nullptr, bTsum, L, chl);
    else               k_decomp<0,0><<<g,512,0,stream>>>(in, out, nullptr, nullptr, L, chl);
  };
  auto decompP = [&](const float* in, u16* outp, int L, int acc) {
    int chl = 45;
    int nch = (L + chl - 1) / chl;
    dim3 g(BB, nch);
    if (acc == 1) k_decomp<1,1><<<g,512,0,stream>>>(in, nullptr, outp, bTsum, L, chl);
    else          k_decomp<0,1><<<g,512,0,stream>>>(in, nullptr, outp, nullptr, L, chl);
  };
  auto decompD = [&](const float* in, float* out, u16* outp, int L, int acc) {
    int chl = 45;
    int nch = (L + chl - 1) / chl;
    dim3 g(BB, nch);
    if (acc == 2)      k_decomp<2,2><<<g,512,0,stream>>>(in, out, outp, bTsum, L, chl);
    else               k_decomp<0,2><<<g,512,0,stream>>>(in, out, outp, nullptr, L, chl);
  };

  // FFN: out = reconstruct(inPair) + gelu(hi(inPair)@W1.T)@W2.T
  // W1/W2 SINGLE bf16; GEMM1 A hi-only + B single (1 MFMA) -> hidden single;
  // GEMM2 A single + B single (1 MFMA) split-K=2 + k_redp (residual from full pair).
  const int CHP = 5760;   // ME = 2 chunks, MD = 3 chunks exactly
  float* SA2 = R;         // hidden single tiled (5760x2048 u16 = 5.9M floats)
  auto ffn = [&](const u16* inPair, float* out, const float* W1, const float* W2,
                 int M, float* scratch) {
    splitPS(W1, SB, DFF2, DD);
    splitPS(W2, SB + SL, DD, DFF2);
    for (int r0 = 0; r0 < M; r0 += CHP) {
      int mc = M - r0; if (mc > CHP) mc = CHP;
      const u16* Ap = inPair + ((size_t)(r0 >> 7) << 17);   // 128 rows = 1<<17 u16
      k_mg<4,3,1,2,1><<<dim3(32,(mc+127)/128,1),512,0,stream>>>(
          Ap, U(SB), nullptr, nullptr, nullptr, nullptr, U(SA2), mc, DFF2, DD, 0);
      k_mg<0,0,2,1,1><<<dim3(8,(mc+127)/128,2),512,0,stream>>>(
          U(SA2), U(SB+SL), nullptr, nullptr, nullptr, scratch, nullptr, mc, DD, DFF2, 0);
      k_redp<<<(int)(((size_t)mc*DD + 255)/256),256,0,stream>>>(
          scratch, 2, (size_t)mc*DD, Ap, out + (size_t)r0*DD, (size_t)mc*DD);
    }
  };

  // X += fourier_self(X); X pair must be pre-staged in R (K=512 layout).
  auto fourier_self = [&](float* X, float* T, int L, int KpL, float* DLS, float* ILS,
                          const float* Wq, const float* bq, const float* fr, const float* fi,
                          const float* Wo, const float* bo) {
    int M = BB * L;
    size_t MN8 = (size_t)8192*128;
    float* bqf   = R + 9*SL;
    float* bselp = R + 10*SL;
    splitP(Wq, SB, DD, DD);
    k_mg<1,0,1,2,0><<<dim3(8,(M+127)/128,1),512,0,stream>>>(
        U(R), U(SB), bq, nullptr, nullptr, T, nullptr, M, DD, DD, 0);
    splitT(T, R, L, KpL);
    k_mg<0,0,4,0,0><<<dim3(2,64,4),512,0,stream>>>(
        U(R), U(DLS), nullptr, nullptr, nullptr, T, nullptr, BB*DD, 128, KpL, 0);
    red(T, 4, MN8, nullptr, bqf, MN8);
    k_modemix<<<dim3(16,8,2),256,0,stream>>>(bqf, fr, fi, U(bselp), 1.0f);
    k_mg<0,2,1,0,0><<<dim3((L+63)/64,64,1),512,0,stream>>>(   // irfft -> pair @R
        U(bselp), U(ILS), nullptr, nullptr, nullptr, nullptr, U(R), BB*DD, L, 128, L);
    splitP(Wo, SB, DD, DD);
    k_mg<3,0,1,2,0><<<dim3(8,(M+127)/128,1),512,0,stream>>>(
        U(R), U(SB), bo, X, nullptr, X, nullptr, M, DD, DD, 0);
  };

  auto myln_pair = [&](const float* in, float* tmp, float* pairdst,
                       const float* g, const float* b, int L) {
    k_ln<<<BB*L,256,0,stream>>>(in, g, b, tmp);
    int chl = L / 9;
    k_colsum_part<<<dim3(BB,9),512,0,stream>>>(tmp, bpart, L, chl, 9);
    k_colsum_fin<<<32,256,0,stream>>>(bpart, bcm, 9, 1.f/(float)L);
    size_t n = (size_t)BB*L*DD;
    k_csub_pair<<<(int)((n+255)/256),256,0,stream>>>(tmp, bcm, U(pairdst), L);
  };

  // ---------------- prep ----------------
  k_extract_x<<<(BB*LEN_E*NV + 255)/256,256,0,stream>>>(history, bxe);
  k_marks_enc<<<(BB*LEN_E*4 + 255)/256,256,0,stream>>>(history, bxme);
  k_marks_dec<<<(BB*LEN_D*4 + 255)/256,256,0,stream>>>(future, bxme, bxmd);
  k_ms_part<<<dim3(BB,10),384,0,stream>>>(bxe, bmsp, 72, 10);
  k_ms_fin<<<(BB*NV + 255)/256,256,0,stream>>>(bmsp, bmean, 10);
  k_init_decomp<<<(BB*LEN_D*NV + 255)/256,256,0,stream>>>(bxe, bmean, bseas, btrend);
  k_build_wconvS<<<dim3(4,512),256,0,stream>>>(Wv_enc, U(WceS));
  k_build_wconvS<<<dim3(4,512),256,0,stream>>>(Wv_dec, U(WcdS));
  k_build_wtrcS<<<dim3(6,321),256,0,stream>>>(Wtr, U(WtrcS));
  k_build_dftS<<<dim3(3,128),256,0,stream>>>(U(D720S), LEN_E, 768);
  k_build_dftS<<<dim3(5,128),256,0,stream>>>(U(D1080S), LEN_D, 1088);
  k_build_irS<<<dim3(1,LEN_E),128,0,stream>>>(U(I720S), LEN_E);
  k_build_irS<<<dim3(1,LEN_D),128,0,stream>>>(U(I1080S), LEN_D);

  // ---------------- encoder ----------------
  int ME = BB * LEN_E;
  // conv-embed in ONE dispatch: 720 blocks, KS=1, no reduce
  splitC(bxe, R, 0, ME, LEN_E, LEN_E, 0, NV, 963, 1024);
  k_mg<0,0,1,0,0><<<dim3(8,90,1),512,0,stream>>>(
      U(R), U(WceS), nullptr, nullptr, nullptr, bX, nullptr, ME, DD, 1024, 0);
  k_marks_add<<<(ME*DD + 255)/256,256,0,stream>>>(bX, bxme, Wt_enc, U(R), ME);

  float *X = bX, *T = bT;
  for (int i = 0; i < 2; ++i) {
    fourier_self(X, T, LEN_E, 768, D720S, I720S,
                 eWq + (size_t)i*DD*DD, ebq + (size_t)i*DD,
                 efr + (size_t)i*HHN*64*64*64, efi + (size_t)i*HHN*64*64*64,
                 eWo + (size_t)i*DD*DD, ebo + (size_t)i*DD);
    decompP(X, U(T), LEN_E, 0);                         // T = seasonal PAIR
    ffn(U(T), X, eW1 + (size_t)i*DFF2*DD, eW2 + (size_t)i*DD*DFF2, ME, bencout);
    if (i == 0) decompD(X, T, U(R), LEN_E, 0);          // T fp32 + R pair (next fourier)
    else        decomp(X, T, LEN_E, 0);                 // T fp32 only
    { float* tmp = X; X = T; T = tmp; }
  }
  myln_pair(X, T, bencout, g_enc, b_enc, LEN_E);   // bencout = tiled pair (ME,512)

  // ---------------- decoder ----------------
  int MD = BB * LEN_D;
  for (int r0 = 0; r0 < MD; r0 += 8640) {               // 2 chunks, KS=1 (544 blocks)
    splitC(bseas, R, r0, 8640, LEN_D, LEN_D, 0, NV, 963, 1024);
    k_mg<0,0,1,0,0><<<dim3(8,68,1),512,0,stream>>>(
        U(R), U(WcdS), nullptr, nullptr, nullptr, X + (size_t)r0*DD, nullptr,
        8640, DD, 1024, 0);
  }
  k_marks_add<<<(MD*DD + 255)/256,256,0,stream>>>(X, bxmd, Wt_dec, U(R), MD);

  fourier_self(X, T, LEN_D, 1088, D1080S, I1080S, dWq, dbq, dfr, dfi, dWo, dbo);

  decompD(X, T, U(R), LEN_D, 2);      // T fp32 + R pair, tsum = t1

  // cross attention (q-projection first: consumes R pair before splitT clobbers R)
  {
    size_t MN8 = (size_t)8192*128;
    float* bkf = R + 9*SL;
    float* bqf = R + 10*SL;
    splitP(cWq, SB, DD, DD);
    k_mg<1,0,1,2,0><<<dim3(8,135,1),512,0,stream>>>(     // q proj from R pair (hi)
        U(R), U(SB), cbq, nullptr, nullptr, X, nullptr, MD, DD, DD, 0);
    splitT(X, R, LEN_D, 1088);
    k_mg<0,0,4,0,0><<<dim3(2,64,4),512,0,stream>>>(
        U(R), U(D1080S), nullptr, nullptr, nullptr, X, nullptr, BB*DD, 128, 1088, 0);
    red(X, 4, MN8, nullptr, bqf, MN8);
    splitP(cWk, SB, DD, DD);
    k_mg<1,0,1,2,0><<<dim3(8,90,1),512,0,stream>>>(      // k proj from bencout (hi)
        U(bencout), U(SB), cbk, nullptr, nullptr, X, nullptr, ME, DD, DD, 0);
    splitT(X, R, LEN_E, 768);
    k_mg<0,0,4,0,0><<<dim3(2,64,4),512,0,stream>>>(
        U(R), U(D720S), nullptr, nullptr, nullptr, X, nullptr, BB*DD, 128, 768, 0);
    red(X, 4, MN8, nullptr, bkf, MN8);
    float* ba = R;
    float* bv = R + SL;
    float* bselp = R + 2*SL;
    k_cross_qk<<<BB*HHN,256,0,stream>>>(bqf, bkf, ba);
    k_cross_v<<<BB*HHN,256,0,stream>>>(ba, bkf, bv);
    k_modemix<<<dim3(16,8,2),256,0,stream>>>(bv, cfr, cfi, U(bselp), 1.0f/262144.0f);
    k_mg<0,2,1,0,0><<<dim3(17,64,1),512,0,stream>>>(    // irfft -> pair @X
        U(bselp), U(I1080S), nullptr, nullptr, nullptr, nullptr, U(X), BB*DD, LEN_D, 128, LEN_D);
    splitP(cWo, SB, DD, DD);
    k_mg<3,0,1,2,0><<<dim3(8,135,1),512,0,stream>>>(
        U(X), U(SB), cbo, T, nullptr, T, nullptr, MD, DD, DD, 0);
  }

  decompP(T, U(X), LEN_D, 1);         // X = seasonal PAIR, tsum += t2
  ffn(U(X), T, dW1, dW2, MD, bencout);// T = x + FFN(x)
  decomp(T, X, LEN_D, 1);             // X fp32, tsum += t3

  // decoder LN + col-mean; emit REMAPPED pair (rows t>=360 only) into bencout
  {
    k_ln<<<BB*LEN_D,256,0,stream>>>(X, g_dec, b_dec, T);
    k_colsum_part<<<dim3(BB,9),512,0,stream>>>(T, bpart, LEN_D, LEN_D/9, 9);
    k_colsum_fin<<<32,256,0,stream>>>(bpart, bcm, 9, 1.f/(float)LEN_D);
    k_csub_pairR<<<(int)(((size_t)MP*DD + 255)/256),256,0,stream>>>(T, bcm, U(bencout));
  }

  // trend conv: split-K=2 (540 blocks) + reduce accumulating into btrend
  for (int r0 = 0; r0 < MP; r0 += 5760) {
    splitC(bTsum, R, r0, 5760, LEN_D, LEN_E, 360, DD, 1536, 1536);
    k_mg<0,0,2,0,0><<<dim3(6,45,2),512,0,stream>>>(
        U(R), U(WtrcS), nullptr, nullptr, nullptr, bX, nullptr, 5760, NV, 1536, 0);
    red(bX, 2, (size_t)5760*NV, btrend + (size_t)r0*NV, btrend + (size_t)r0*NV,
        (size_t)5760*NV);
  }

  // seasonal + trend -> d_out (fused, no k_final; A hi-only)
  splitP(Wp, SB, NV, DD);
  k_mg<3,0,1,2,0><<<dim3(6,90,1),512,0,stream>>>(
      U(bencout), U(SB), bp, btrend, nullptr, (float*)d_out, nullptr, MP, NV, DD, 0);
}